// Round 20
// baseline (412.053 us; speedup 1.0000x reference)
//
#include <hip/hip_runtime.h>
#include <cstdint>
#include <cstddef>

typedef unsigned short u16;
typedef __attribute__((ext_vector_type(4))) short short4v;
typedef __attribute__((ext_vector_type(8))) short short8;
typedef __attribute__((ext_vector_type(4))) float f32x4;

__device__ __forceinline__ float bf2f(u16 h) { return __uint_as_float(((unsigned)h) << 16); }
__device__ __forceinline__ u16 f2bf(float f) {
    unsigned u = __float_as_uint(f);
    unsigned r = (u + 0x7fffu + ((u >> 16) & 1u)) >> 16;
    return (u16)r;
}
// round-half-up: <=0.5 ULP, 2 VALU ops (flash inner loop)
__device__ __forceinline__ u16 f2bf_fast(float f) {
    return (u16)((__float_as_uint(f) + 0x8000u) >> 16);
}

__device__ __forceinline__ void gl_lds16(const void* g, void* l) {
    __builtin_amdgcn_global_load_lds((const __attribute__((address_space(1))) void*)g,
                                     (__attribute__((address_space(3))) void*)l, 16, 0, 0);
}

// ---------------- merged prologue: detect + param-cvt + weight transpose ----
struct Prologue {
    const void* tsrc[8];
    u16* tdst[8];
    int tR[8], tC[8], toff[8];
    const void* psrc[12];
    int poff[12], pn[12];
    int ntrans;
};
__global__ __launch_bounds__(256) void prologue_kernel(Prologue P,
                                                       const unsigned* __restrict__ x,
                                                       int* __restrict__ flag,
                                                       float* __restrict__ pf) {
    // self-detect dtype (1024 samples of x's low u16: bf16 exponent-field test)
    __shared__ int cnt[256];
    int c = 0;
    for (int i = threadIdx.x; i < 1024; i += 256) {
        unsigned lo = x[i] & 0xFFFFu;
        unsigned e = (lo >> 7) & 0xFFu;
        c += (e >= 100u && e <= 150u) ? 1 : 0;
    }
    cnt[threadIdx.x] = c;
    __syncthreads();
    for (int s = 128; s > 0; s >>= 1) {
        if (threadIdx.x < s) cnt[threadIdx.x] += cnt[threadIdx.x + s];
        __syncthreads();
    }
    const int bf = (cnt[0] > 512) ? 1 : 0;
    if (blockIdx.x == 0 && threadIdx.x == 0) *flag = bf;

    const int bid = blockIdx.x;
    if (bid >= P.ntrans) {
        const int s = bid - P.ntrans;
        const void* sp = P.psrc[s];
        float* dp = pf + P.poff[s];
        const int n = P.pn[s];
        for (int i = threadIdx.x; i < n; i += 256)
            dp[i] = bf ? bf2f(((const u16*)sp)[i]) : ((const float*)sp)[i];
        return;
    }
    __shared__ u16 tile[32][33];
    int m = 0;
#pragma unroll
    for (int i = 1; i < 8; i++) m = (bid >= P.toff[i]) ? i : m;
    const int local = bid - P.toff[m];
    const int R = P.tR[m], C = P.tC[m];
    const int tilesx = C >> 5;
    const int bx = local % tilesx, by = local / tilesx;
    const void* src = P.tsrc[m];
    u16* dst = P.tdst[m];
    const int tx = threadIdx.x & 31, ty = threadIdx.x >> 5;   // ty 0..7
#pragma unroll
    for (int i = 0; i < 32; i += 8) {
        size_t idx = (size_t)(by * 32 + ty + i) * C + bx * 32 + tx;
        tile[ty + i][tx] = bf ? ((const u16*)src)[idx] : f2bf(((const float*)src)[idx]);
    }
    __syncthreads();
#pragma unroll
    for (int i = 0; i < 32; i += 8)
        dst[(size_t)(bx * 32 + ty + i) * R + by * 32 + tx] = tile[tx][ty + i];
}

// ---------------- fused x-convert + LayerNorm (first LN) --------------------
__global__ __launch_bounds__(256) void ln_x_kernel(const void* __restrict__ X,
                                                   const float* __restrict__ G,
                                                   const float* __restrict__ Be,
                                                   u16* __restrict__ Xb,
                                                   u16* __restrict__ Y,
                                                   const int* __restrict__ flag) {
    const int row = blockIdx.x;
    const int tid = threadIdx.x;
    const int lane = tid & 63, wave = tid >> 6;
    u16 vbuf[4];
    if (*flag) {
        *(uint2*)vbuf = *(const uint2*)((const u16*)X + (size_t)row * 1024 + tid * 4);
    } else {
        float4 v = *(const float4*)((const float*)X + (size_t)row * 1024 + tid * 4);
        vbuf[0] = f2bf(v.x); vbuf[1] = f2bf(v.y); vbuf[2] = f2bf(v.z); vbuf[3] = f2bf(v.w);
    }
    *(uint2*)&Xb[(size_t)row * 1024 + tid * 4] = *(uint2*)vbuf;
    float f[4];
    float s = 0.f, sq = 0.f;
#pragma unroll
    for (int j = 0; j < 4; j++) { f[j] = bf2f(vbuf[j]); s += f[j]; sq += f[j] * f[j]; }
#pragma unroll
    for (int m = 1; m < 64; m <<= 1) { s += __shfl_xor(s, m, 64); sq += __shfl_xor(sq, m, 64); }
    __shared__ float rs_[4], rq_[4];
    if (lane == 0) { rs_[wave] = s; rq_[wave] = sq; }
    __syncthreads();
    float S = rs_[0] + rs_[1] + rs_[2] + rs_[3];
    float Q2 = rq_[0] + rq_[1] + rq_[2] + rq_[3];
    float mean = S * (1.f / 1024.f);
    float var = Q2 * (1.f / 1024.f) - mean * mean;
    float rstd = rsqrtf(var + 1e-5f);
    u16 o[4];
#pragma unroll
    for (int j = 0; j < 4; j++) {
        int c2 = tid * 4 + j;
        float y = (f[j] - mean) * rstd * G[c2] + Be[c2];
        o[j] = f2bf(y);
    }
    *(uint2*)&Y[(size_t)row * 1024 + tid * 4] = *(uint2*)o;
}

// ---------------- LayerNorm over C=1024 (bf16 in, f32 params, bf16 out) -----
__global__ __launch_bounds__(256) void ln_kernel(const u16* __restrict__ X,
                                                 const float* __restrict__ G,
                                                 const float* __restrict__ Be,
                                                 u16* __restrict__ Y) {
    const int row = blockIdx.x;
    const int tid = threadIdx.x;
    const int lane = tid & 63, wave = tid >> 6;
    const u16* xr = X + (size_t)row * 1024;
    u16 vbuf[4];
    *(uint2*)vbuf = *(const uint2*)&xr[tid * 4];
    float f[4];
    float s = 0.f, sq = 0.f;
#pragma unroll
    for (int j = 0; j < 4; j++) { f[j] = bf2f(vbuf[j]); s += f[j]; sq += f[j] * f[j]; }
#pragma unroll
    for (int m = 1; m < 64; m <<= 1) { s += __shfl_xor(s, m, 64); sq += __shfl_xor(sq, m, 64); }
    __shared__ float rs_[4], rq_[4];
    if (lane == 0) { rs_[wave] = s; rq_[wave] = sq; }
    __syncthreads();
    float S = rs_[0] + rs_[1] + rs_[2] + rs_[3];
    float Q2 = rq_[0] + rq_[1] + rq_[2] + rq_[3];
    float mean = S * (1.f / 1024.f);
    float var = Q2 * (1.f / 1024.f) - mean * mean;
    float rstd = rsqrtf(var + 1e-5f);
    u16 o[4];
#pragma unroll
    for (int j = 0; j < 4; j++) {
        int c2 = tid * 4 + j;
        float y = (f[j] - mean) * rstd * G[c2] + Be[c2];
        o[j] = f2bf(y);
    }
    *(uint2*)&Y[(size_t)row * 1024 + tid * 4] = *(uint2*)o;
}

// ---------------- GEMM 128x128 / 8 waves, K-region pipeline, 1 barrier ------
// Round-8 verified kernel. BK=64, 8 waves (32x64/wave), 64KB LDS -> 2 blk/CU
// where the grid supplies them. One barrier per phase. Calendar: t.ph0 stages
// (t+1,k1), waits vmcnt(4) [tail 0]; t.ph1 stages (t+2,k0), waits vmcnt(4)
// [tail 2]. Swizzle involution phys_chunk = logical ^ ((rsub>>1)&3) on BOTH
// global source and ds_read (rule #21).
template <int TAG>
__global__ __launch_bounds__(512, 4) void gemm128_kernel(const u16* __restrict__ A,
                                                         const u16* __restrict__ Bt,
                                                         const float* __restrict__ bias,
                                                         const u16* __restrict__ res1,
                                                         const u16* __restrict__ res2,
                                                         void* __restrict__ out,
                                                         void* __restrict__ out_k,
                                                         void* __restrict__ out_v,
                                                         int M, int N, int K, int relu, int mode,
                                                         int swz,
                                                         const int* __restrict__ flag) {
    (void)flag; (void)M;
    __shared__ __align__(16) u16 As[2][2][128 * 32];   // [buf][kh][row*32+chunk*8] = 8KB each
    __shared__ __align__(16) u16 Bs[2][2][128 * 32];
    const int tid = threadIdx.x;
    const int wave = tid >> 6, lane = tid & 63;
    const int l15 = lane & 15, quad = lane >> 4;
    const int wr = wave & 3, wc = wave >> 2;           // 4x2 wave grid: 32x64 per wave
    int bx = blockIdx.x, by = blockIdx.y;
    if (swz) {
        const int gx = gridDim.x;
        const int nwg = gx * gridDim.y;
        const int bid = by * gx + bx;
        const int sbid = (bid & 7) * (nwg >> 3) + (bid >> 3);  // XCD-chunked, bijective
        bx = sbid % gx;
        by = sbid / gx;
    }
    const int m0 = by * 128, n0 = bx * 128;
    const int nt = K >> 6;

    const int rsub = lane >> 2;                        // 0..15
    const int logc = (lane & 3) ^ ((rsub >> 1) & 3);

    auto stage_pair = [&](int t, int kh) {
        const int buf = t & 1;
        const int kk = (t << 6) + (kh << 5) + logc * 8;
        const int roff = wave * 16 + rsub;
        gl_lds16(A + (size_t)(m0 + roff) * K + kk, &As[buf][kh][wave * 512 + lane * 8]);
        gl_lds16(Bt + (size_t)(n0 + roff) * K + kk, &Bs[buf][kh][wave * 512 + lane * 8]);
    };

    f32x4 acc[2][4];
#pragma unroll
    for (int i = 0; i < 2; i++)
#pragma unroll
        for (int j = 0; j < 4; j++) acc[i][j] = (f32x4){0.f, 0.f, 0.f, 0.f};

    stage_pair(0, 0);
    stage_pair(0, 1);
    stage_pair(1, 0);
    asm volatile("s_waitcnt vmcnt(4)" ::: "memory");
    __builtin_amdgcn_s_barrier();

    const int rx = (l15 >> 1) & 3;                     // read-side involution
    for (int t = 0; t < nt; t++) {
        const int b = t & 1;
#pragma unroll
        for (int ph = 0; ph < 2; ph++) {
            const int kh = ph;
            short8 af[2], bfr[4];
#pragma unroll
            for (int i = 0; i < 2; i++)
                af[i] = *(const short8*)&As[b][kh][(wr * 32 + i * 16 + l15) * 32 +
                                                   ((quad ^ rx) << 3)];
#pragma unroll
            for (int j = 0; j < 4; j++)
                bfr[j] = *(const short8*)&Bs[b][kh][(wc * 64 + j * 16 + l15) * 32 +
                                                    ((quad ^ rx) << 3)];
            if (ph == 0) { if (t + 1 < nt) stage_pair(t + 1, 1); }
            else         { if (t + 2 < nt) stage_pair(t + 2, 0); }
            __builtin_amdgcn_s_setprio(1);
#pragma unroll
            for (int i = 0; i < 2; i++)
#pragma unroll
                for (int j = 0; j < 4; j++)
                    acc[i][j] = __builtin_amdgcn_mfma_f32_16x16x32_bf16(
                        af[i], bfr[j], acc[i][j], 0, 0, 0);
            __builtin_amdgcn_s_setprio(0);
            if (ph == 0) {
                if (t + 1 < nt) { asm volatile("s_waitcnt vmcnt(4)" ::: "memory"); }
                else            { asm volatile("s_waitcnt vmcnt(0)" ::: "memory"); }
            } else {
                if (t + 2 < nt)      { asm volatile("s_waitcnt vmcnt(4)" ::: "memory"); }
                else if (t + 1 < nt) { asm volatile("s_waitcnt vmcnt(2)" ::: "memory"); }
            }
            __builtin_amdgcn_s_barrier();
        }
    }

    // epilogue: C/D layout col=lane&15, row=quad*4+r (m89-verified)
    if (mode == 2) {
        const int region = n0 >> 10;
        if (region < 2) {
            u16* o = (u16*)(region == 0 ? out : out_k);
#pragma unroll
            for (int j = 0; j < 4; j++) {
                const int col = n0 + wc * 64 + j * 16 + l15;
                const float bv = bias[col];
                const int cl = col & 1023;
#pragma unroll
                for (int i = 0; i < 2; i++) {
                    const int row0 = m0 + wr * 32 + i * 16 + quad * 4;
#pragma unroll
                    for (int r = 0; r < 4; r++)
                        o[(size_t)(row0 + r) * 1024 + cl] = f2bf(acc[i][j][r] + bv);
                }
            }
        } else {
            u16* o = (u16*)out_v;
#pragma unroll
            for (int j = 0; j < 4; j++) {
                const int col = n0 + wc * 64 + j * 16 + l15;
                const float bv = bias[col];
                const int cl = col & 1023;
                const int h = cl >> 6, d = cl & 63;
#pragma unroll
                for (int i = 0; i < 2; i++) {
                    const int row_base = m0 + wr * 32 + i * 16 + quad * 4;
                    const int bb = row_base >> 11, tt = row_base & 2047;
                    u16 pk[4];
#pragma unroll
                    for (int r = 0; r < 4; r++) pk[r] = f2bf(acc[i][j][r] + bv);
                    *(uint2*)&o[(((size_t)bb * 16 + h) * 64 + d) * 2048 + tt] = *(uint2*)pk;
                }
            }
        }
        return;
    }
    // mode 0: bias [+relu] [+res] -> bf16
#pragma unroll
    for (int j = 0; j < 4; j++) {
        const int col = n0 + wc * 64 + j * 16 + l15;
        const float bv = bias ? bias[col] : 0.f;
#pragma unroll
        for (int i = 0; i < 2; i++) {
            const int row0 = m0 + wr * 32 + i * 16 + quad * 4;
#pragma unroll
            for (int r = 0; r < 4; r++) {
                float v = acc[i][j][r] + bv;
                if (relu) v = fmaxf(v, 0.f);
                const size_t idx = (size_t)(row0 + r) * N + col;
                if (res1) v += bf2f(res1[idx]);
                if (res2) v += bf2f(res2[idx]);
                ((u16*)out)[idx] = f2bf(v);
            }
        }
    }
}

// ---------------- GEMM 128x128 SPLIT-K: BK=64 pipeline, f32 partials --------
// FFN2 fix (r19 counters: 1 blk/CU, MfmaUtil 27 / VALU 15 / HBM 15 -- nothing
// busy = latency-bound lockstep). Byte-copy of the verified gemm128 K-loop
// with kbeg = z*Ksub added to staging (pattern proven in old split-K gemm_bt)
// and the proven mode-3 f32-partial epilogue (bias deferred to reduce).
// 64KB LDS + (512,4) bounds -> 2 resident blocks/CU = 16 waves/CU: one
// block's waves issue while the other drains its barrier (m114 overlap).
template <int TAG>
__global__ __launch_bounds__(512, 4) void gemm128s_kernel(const u16* __restrict__ A,
                                                          const u16* __restrict__ Bt,
                                                          float* __restrict__ out,
                                                          int M, int N, int K, int Ksub) {
    __shared__ __align__(16) u16 As[2][2][128 * 32];
    __shared__ __align__(16) u16 Bs[2][2][128 * 32];
    const int tid = threadIdx.x;
    const int wave = tid >> 6, lane = tid & 63;
    const int l15 = lane & 15, quad = lane >> 4;
    const int wr = wave & 3, wc = wave >> 2;           // 4x2 wave grid: 32x64 per wave
    const int m0 = blockIdx.y * 128, n0 = blockIdx.x * 128;
    const int kbeg = blockIdx.z * Ksub;
    const int nt = Ksub >> 6;

    const int rsub = lane >> 2;                        // 0..15
    const int logc = (lane & 3) ^ ((rsub >> 1) & 3);

    auto stage_pair = [&](int t, int kh) {
        const int buf = t & 1;
        const int kk = kbeg + (t << 6) + (kh << 5) + logc * 8;
        const int roff = wave * 16 + rsub;
        gl_lds16(A + (size_t)(m0 + roff) * K + kk, &As[buf][kh][wave * 512 + lane * 8]);
        gl_lds16(Bt + (size_t)(n0 + roff) * K + kk, &Bs[buf][kh][wave * 512 + lane * 8]);
    };

    f32x4 acc[2][4];
#pragma unroll
    for (int i = 0; i < 2; i++)
#pragma unroll
        for (int j = 0; j < 4; j++) acc[i][j] = (f32x4){0.f, 0.f, 0.f, 0.f};

    stage_pair(0, 0);
    stage_pair(0, 1);
    stage_pair(1, 0);
    asm volatile("s_waitcnt vmcnt(4)" ::: "memory");
    __builtin_amdgcn_s_barrier();

    const int rx = (l15 >> 1) & 3;                     // read-side involution
    for (int t = 0; t < nt; t++) {
        const int b = t & 1;
#pragma unroll
        for (int ph = 0; ph < 2; ph++) {
            const int kh = ph;
            short8 af[2], bfr[4];
#pragma unroll
            for (int i = 0; i < 2; i++)
                af[i] = *(const short8*)&As[b][kh][(wr * 32 + i * 16 + l15) * 32 +
                                                   ((quad ^ rx) << 3)];
#pragma unroll
            for (int j = 0; j < 4; j++)
                bfr[j] = *(const short8*)&Bs[b][kh][(wc * 64 + j * 16 + l15) * 32 +
                                                    ((quad ^ rx) << 3)];
            if (ph == 0) { if (t + 1 < nt) stage_pair(t + 1, 1); }
            else         { if (t + 2 < nt) stage_pair(t + 2, 0); }
            __builtin_amdgcn_s_setprio(1);
#pragma unroll
            for (int i = 0; i < 2; i++)
#pragma unroll
                for (int j = 0; j < 4; j++)
                    acc[i][j] = __builtin_amdgcn_mfma_f32_16x16x32_bf16(
                        af[i], bfr[j], acc[i][j], 0, 0, 0);
            __builtin_amdgcn_s_setprio(0);
            if (ph == 0) {
                if (t + 1 < nt) { asm volatile("s_waitcnt vmcnt(4)" ::: "memory"); }
                else            { asm volatile("s_waitcnt vmcnt(0)" ::: "memory"); }
            } else {
                if (t + 2 < nt)      { asm volatile("s_waitcnt vmcnt(4)" ::: "memory"); }
                else if (t + 1 < nt) { asm volatile("s_waitcnt vmcnt(2)" ::: "memory"); }
            }
            __builtin_amdgcn_s_barrier();
        }
    }

    // epilogue: f32 partials, no bias (m89-verified C/D layout)
    float* po = out + (size_t)blockIdx.z * M * N;
#pragma unroll
    for (int j = 0; j < 4; j++) {
        const int col = n0 + wc * 64 + j * 16 + l15;
#pragma unroll
        for (int i = 0; i < 2; i++) {
            const int row0 = m0 + wr * 32 + i * 16 + quad * 4;
#pragma unroll
            for (int r = 0; r < 4; r++)
                po[(size_t)(row0 + r) * N + col] = acc[i][j][r];
        }
    }
}

// ---------------- split-K reduce: out = f(sum_z part[z]) (r14-verified) -----
template <int TAG>
__global__ __launch_bounds__(256) void reduce_kernel(const float* __restrict__ part,
                                                     int nsplit, size_t MN,
                                                     const float* __restrict__ bias, int N,
                                                     const u16* __restrict__ res1,
                                                     const u16* __restrict__ res2,
                                                     void* __restrict__ out,
                                                     int relu, int final_store,
                                                     const int* __restrict__ flag) {
    const size_t i0 = ((size_t)blockIdx.x * 256 + threadIdx.x) * 4;
    float4 s = *(const float4*)&part[i0];
    for (int z = 1; z < nsplit; z++) {
        float4 p = *(const float4*)&part[(size_t)z * MN + i0];
        s.x += p.x; s.y += p.y; s.z += p.z; s.w += p.w;
    }
    const int col = (int)(i0 & (size_t)(N - 1));
    float v[4] = {s.x, s.y, s.z, s.w};
#pragma unroll
    for (int j = 0; j < 4; j++) {
        v[j] += bias[col + j];
        if (relu) v[j] = fmaxf(v[j], 0.f);
    }
    if (res1) {
        u16 r[4]; *(uint2*)r = *(const uint2*)&res1[i0];
#pragma unroll
        for (int j = 0; j < 4; j++) v[j] += bf2f(r[j]);
    }
    if (res2) {
        u16 r[4]; *(uint2*)r = *(const uint2*)&res2[i0];
#pragma unroll
        for (int j = 0; j < 4; j++) v[j] += bf2f(r[j]);
    }
    if (final_store && (*flag == 0)) {
        *(float4*)&((float*)out)[i0] = (float4){v[0], v[1], v[2], v[3]};
    } else {
        u16 o[4];
#pragma unroll
        for (int j = 0; j < 4; j++) o[j] = f2bf(v[j]);
        *(uint2*)&((u16*)out)[i0] = *(uint2*)o;
    }
}

// ---------------- GEMM 256x256 / 8 waves of 128x64, K-region pipeline -------
// FFN1 kernel (r18). K-MAJOR regions As/Bs[buf][kh][256*32] (16KB). Calendar
// at 4 loads/stage: prologue vmcnt(8); ph0-end vmcnt(8) [tail 0]; ph1-end
// vmcnt(8) [tail 4]. Both-sides involution ((row&15)>>1)&3 (rule #21).
template <int TAG>
__global__ __launch_bounds__(512, 2) void gemm256w_kernel(const u16* __restrict__ A,
                                                          const u16* __restrict__ Bt,
                                                          const float* __restrict__ bias,
                                                          void* __restrict__ out,
                                                          int N, int K, int relu) {
    __shared__ __align__(16) u16 As[2][2][256 * 32];   // [buf][kh] 16KB regions
    __shared__ __align__(16) u16 Bs[2][2][256 * 32];
    const int tid = threadIdx.x;
    const int wave = tid >> 6, lane = tid & 63;
    const int l15 = lane & 15, quad = lane >> 4;
    const int wr = wave >> 2, wc = wave & 3;           // 2x4 wave grid: 128x64 per wave
    const int m0 = blockIdx.y * 256, n0 = blockIdx.x * 256;
    const int nt = K >> 6;

    const int rsub = lane >> 2;                        // 0..15
    const int logc = (lane & 3) ^ ((rsub >> 1) & 3);   // involution, +16-row invariant

    auto stage_pair = [&](int t, int kh) {
        const int buf = t & 1;
        const int kk = (t << 6) + (kh << 5) + logc * 8;
        const int r0 = wave * 32 + rsub;
        u16* da = &As[buf][kh][wave * 1024 + lane * 8];
        u16* db = &Bs[buf][kh][wave * 1024 + lane * 8];
        gl_lds16(A + (size_t)(m0 + r0) * K + kk, da);
        gl_lds16(A + (size_t)(m0 + r0 + 16) * K + kk, da + 512);
        gl_lds16(Bt + (size_t)(n0 + r0) * K + kk, db);
        gl_lds16(Bt + (size_t)(n0 + r0 + 16) * K + kk, db + 512);
    };

    f32x4 acc[8][4];
#pragma unroll
    for (int i = 0; i < 8; i++)
#pragma unroll
        for (int j = 0; j < 4; j++) acc[i][j] = (f32x4){0.f, 0.f, 0.f, 0.f};

    stage_pair(0, 0);
    stage_pair(0, 1);
    stage_pair(1, 0);
    asm volatile("s_waitcnt vmcnt(8)" ::: "memory");
    __builtin_amdgcn_s_barrier();

    const int rx = (l15 >> 1) & 3;                     // read-side involution
    for (int t = 0; t < nt; t++) {
        const int b = t & 1;
#pragma unroll
        for (int ph = 0; ph < 2; ph++) {
            const int kh = ph;
            short8 af[8], bfr[4];
#pragma unroll
            for (int i = 0; i < 8; i++)
                af[i] = *(const short8*)&As[b][kh][(wr * 128 + i * 16 + l15) * 32 +
                                                   ((quad ^ rx) << 3)];
#pragma unroll
            for (int j = 0; j < 4; j++)
                bfr[j] = *(const short8*)&Bs[b][kh][(wc * 64 + j * 16 + l15) * 32 +
                                                    ((quad ^ rx) << 3)];
            if (ph == 0) { if (t + 1 < nt) stage_pair(t + 1, 1); }
            else         { if (t + 2 < nt) stage_pair(t + 2, 0); }
            __builtin_amdgcn_s_setprio(1);
#pragma unroll
            for (int i = 0; i < 8; i++)
#pragma unroll
                for (int j = 0; j < 4; j++)
                    acc[i][j] = __builtin_amdgcn_mfma_f32_16x16x32_bf16(
                        af[i], bfr[j], acc[i][j], 0, 0, 0);
            __builtin_amdgcn_s_setprio(0);
            if (ph == 0) {
                if (t + 1 < nt) { asm volatile("s_waitcnt vmcnt(8)" ::: "memory"); }
                else            { asm volatile("s_waitcnt vmcnt(0)" ::: "memory"); }
            } else {
                if (t + 2 < nt)      { asm volatile("s_waitcnt vmcnt(8)" ::: "memory"); }
                else if (t + 1 < nt) { asm volatile("s_waitcnt vmcnt(4)" ::: "memory"); }
            }
            __builtin_amdgcn_s_barrier();
        }
    }

    // epilogue: bias [+relu] -> bf16 (m89-verified C/D layout)
#pragma unroll
    for (int j = 0; j < 4; j++) {
        const int col = n0 + wc * 64 + j * 16 + l15;
        const float bv = bias ? bias[col] : 0.f;
#pragma unroll
        for (int i = 0; i < 8; i++) {
            const int row0 = m0 + wr * 128 + i * 16 + quad * 4;
#pragma unroll
            for (int r = 0; r < 4; r++) {
                float v = acc[i][j][r] + bv;
                if (relu) v = fmaxf(v, 0.f);
                ((u16*)out)[(size_t)(row0 + r) * N + col] = f2bf(v);
            }
        }
    }
}

// ---------------- GEMM 128x128 DEEP: BK=128, for 1-block/CU grids -----------
// For grid-256 shapes (Wo; FFN2 fallback). Calendar at 4 loads/stage:
// prologue vmcnt(8); ph0-end vmcnt(8) [tail 0]; ph1-end vmcnt(8) [tail 4].
template <int TAG>
__global__ __launch_bounds__(512, 2) void gemm128d_kernel(const u16* __restrict__ A,
                                                          const u16* __restrict__ Bt,
                                                          const float* __restrict__ bias,
                                                          const u16* __restrict__ res1,
                                                          void* __restrict__ out,
                                                          int N, int K, int relu, int swz) {
    __shared__ __align__(16) u16 As[2][2][128 * 64];   // [buf][kh] 16KB regions
    __shared__ __align__(16) u16 Bs[2][2][128 * 64];
    const int tid = threadIdx.x;
    const int wave = tid >> 6, lane = tid & 63;
    const int l15 = lane & 15, quad = lane >> 4;
    const int wr = wave & 3, wc = wave >> 2;           // 4x2 wave grid: 32x64 per wave
    int bx = blockIdx.x, by = blockIdx.y;
    if (swz) {
        const int gx = gridDim.x;
        const int nwg = gx * gridDim.y;
        const int bid = by * gx + bx;
        const int sbid = (bid & 7) * (nwg >> 3) + (bid >> 3);  // XCD-chunked, bijective
        bx = sbid % gx;
        by = sbid / gx;
    }
    const int m0 = by * 128, n0 = bx * 128;
    const int nt = K >> 7;                             // BK=128 tiles

    const int srow = lane >> 3;                        // 0..7
    const int logc = (lane & 7) ^ ((lane >> 4) & 3);   // involution, +8-row invariant

    auto stage_pair = [&](int t, int kh) {
        const int buf = t & 1;
        const int kk = (t << 7) + (kh << 6) + logc * 8;
        const int r0 = wave * 16 + srow;
        u16* da = &As[buf][kh][wave * 1024 + lane * 8];
        u16* db = &Bs[buf][kh][wave * 1024 + lane * 8];
        gl_lds16(A + (size_t)(m0 + r0) * K + kk, da);
        gl_lds16(A + (size_t)(m0 + r0 + 8) * K + kk, da + 512);
        gl_lds16(Bt + (size_t)(n0 + r0) * K + kk, db);
        gl_lds16(Bt + (size_t)(n0 + r0 + 8) * K + kk, db + 512);
    };

    f32x4 acc[2][4];
#pragma unroll
    for (int i = 0; i < 2; i++)
#pragma unroll
        for (int j = 0; j < 4; j++) acc[i][j] = (f32x4){0.f, 0.f, 0.f, 0.f};

    stage_pair(0, 0);
    stage_pair(0, 1);
    stage_pair(1, 0);
    asm volatile("s_waitcnt vmcnt(8)" ::: "memory");
    __builtin_amdgcn_s_barrier();

    const int rx = (l15 >> 1) & 3;                     // read-side involution
    for (int t = 0; t < nt; t++) {
        const int b = t & 1;
#pragma unroll
        for (int ph = 0; ph < 2; ph++) {
            const int kh = ph;
            short8 af[2][2], bfr[4][2];
#pragma unroll
            for (int ks = 0; ks < 2; ks++) {
                const int ck = ((ks << 2) | (quad ^ rx)) << 3;
#pragma unroll
                for (int i = 0; i < 2; i++)
                    af[i][ks] = *(const short8*)&As[b][kh][(wr * 32 + i * 16 + l15) * 64 + ck];
#pragma unroll
                for (int j = 0; j < 4; j++)
                    bfr[j][ks] = *(const short8*)&Bs[b][kh][(wc * 64 + j * 16 + l15) * 64 + ck];
            }
            if (ph == 0) { if (t + 1 < nt) stage_pair(t + 1, 1); }
            else         { if (t + 2 < nt) stage_pair(t + 2, 0); }
            __builtin_amdgcn_s_setprio(1);
#pragma unroll
            for (int ks = 0; ks < 2; ks++)
#pragma unroll
                for (int i = 0; i < 2; i++)
#pragma unroll
                    for (int j = 0; j < 4; j++)
                        acc[i][j] = __builtin_amdgcn_mfma_f32_16x16x32_bf16(
                            af[i][ks], bfr[j][ks], acc[i][j], 0, 0, 0);
            __builtin_amdgcn_s_setprio(0);
            if (ph == 0) {
                if (t + 1 < nt) { asm volatile("s_waitcnt vmcnt(8)" ::: "memory"); }
                else            { asm volatile("s_waitcnt vmcnt(0)" ::: "memory"); }
            } else {
                if (t + 2 < nt)      { asm volatile("s_waitcnt vmcnt(8)" ::: "memory"); }
                else if (t + 1 < nt) { asm volatile("s_waitcnt vmcnt(4)" ::: "memory"); }
            }
            __builtin_amdgcn_s_barrier();
        }
    }

    // epilogue: bias [+relu] [+res1] -> bf16 (m89-verified C/D layout)
#pragma unroll
    for (int j = 0; j < 4; j++) {
        const int col = n0 + wc * 64 + j * 16 + l15;
        const float bv = bias ? bias[col] : 0.f;
#pragma unroll
        for (int i = 0; i < 2; i++) {
            const int row0 = m0 + wr * 32 + i * 16 + quad * 4;
#pragma unroll
            for (int r = 0; r < 4; r++) {
                float v = acc[i][j][r] + bv;
                if (relu) v = fmaxf(v, 0.f);
                const size_t idx = (size_t)(row0 + r) * N + col;
                if (res1) v += bf2f(res1[idx]);
                ((u16*)out)[idx] = f2bf(v);
            }
        }
    }
}

// ---------------- fused adapter: out = x1 + hh + relu(hh@Wd+bd)@Wu + bu -----
__global__ __launch_bounds__(512) void adapter_kernel(const u16* __restrict__ hh,
                                                      const u16* __restrict__ x1,
                                                      const u16* __restrict__ WdT,
                                                      const u16* __restrict__ WuT,
                                                      const float* __restrict__ bd,
                                                      const float* __restrict__ bu,
                                                      void* __restrict__ out,
                                                      const int* __restrict__ flag) {
    const int tid = threadIdx.x;
    const int wave = tid >> 6, lane = tid & 63;
    const int l15 = lane & 15, quad = lane >> 4;
    const int r0 = blockIdx.x * 16;

    __shared__ float part[8][16 * 64];
    __shared__ __align__(16) u16 bot_s[16 * 72];       // 72-pad: conflict-free A-frag reads

    // phase 1: down-GEMM partial over this wave's K-slice
    f32x4 dacc[4];
#pragma unroll
    for (int j = 0; j < 4; j++) dacc[j] = (f32x4){0.f, 0.f, 0.f, 0.f};
    const int kw = wave * 128;
#pragma unroll
    for (int ks = 0; ks < 4; ks++) {
        const int k0 = kw + ks * 32 + quad * 8;
        short8 af = *(const short8*)&hh[(size_t)(r0 + l15) * 1024 + k0];
#pragma unroll
        for (int j = 0; j < 4; j++) {
            short8 bf = *(const short8*)&WdT[(size_t)(j * 16 + l15) * 1024 + k0];
            dacc[j] = __builtin_amdgcn_mfma_f32_16x16x32_bf16(af, bf, dacc[j], 0, 0, 0);
        }
    }
#pragma unroll
    for (int j = 0; j < 4; j++)
#pragma unroll
        for (int r = 0; r < 4; r++)
            part[wave][(quad * 4 + r) * 64 + j * 16 + l15] = dacc[j][r];
    __syncthreads();

    // reduce 8 partials, +bd, relu, bf16
    for (int e = tid; e < 1024; e += 512) {
        float s = part[0][e];
#pragma unroll
        for (int w = 1; w < 8; w++) s += part[w][e];
        s += bd[e & 63];
        s = fmaxf(s, 0.f);
        bot_s[(e >> 6) * 72 + (e & 63)] = f2bf(s);
    }
    __syncthreads();

    // phase 2: up-GEMM, wave owns cols [wave*128, +128), K=64
    short8 auf[2];
    auf[0] = *(const short8*)&bot_s[l15 * 72 + quad * 8];
    auf[1] = *(const short8*)&bot_s[l15 * 72 + 32 + quad * 8];
    f32x4 uacc[8];
#pragma unroll
    for (int j = 0; j < 8; j++) uacc[j] = (f32x4){0.f, 0.f, 0.f, 0.f};
#pragma unroll
    for (int j = 0; j < 8; j++) {
        const size_t nb = (size_t)(wave * 128 + j * 16 + l15) * 64;
        short8 b0 = *(const short8*)&WuT[nb + quad * 8];
        short8 b1 = *(const short8*)&WuT[nb + 32 + quad * 8];
        uacc[j] = __builtin_amdgcn_mfma_f32_16x16x32_bf16(auf[0], b0, uacc[j], 0, 0, 0);
        uacc[j] = __builtin_amdgcn_mfma_f32_16x16x32_bf16(auf[1], b1, uacc[j], 0, 0, 0);
    }
    const int f32out = (*flag == 0);
#pragma unroll
    for (int j = 0; j < 8; j++) {
        const int col = wave * 128 + j * 16 + l15;
        const float bv = bu[col];
#pragma unroll
        for (int r = 0; r < 4; r++) {
            const int row = r0 + quad * 4 + r;
            const size_t idx = (size_t)row * 1024 + col;
            float v = uacc[j][r] + bv;
            v += bf2f(hh[idx]);
            v += bf2f(x1[idx]);
            if (f32out) ((float*)out)[idx] = v;
            else ((u16*)out)[idx] = f2bf(v);
        }
    }
}

// ---------------- flash attention v11: paired q-blocks, shared K/V staging --
// r19 WIN (52 -> off top-5). v8b's exact per-wave math; waves 0-3 own qbA,
// waves 4-7 own qbB, shared K/V tile feeds 128 q-rows; zero per-wave VGPR
// change -> VGPR-capped 24 waves/CU (vs LDS-capped 20).
__global__ __launch_bounds__(512) void flash_pair_kernel(const u16* __restrict__ Q,
                                                         const u16* __restrict__ Kg,
                                                         const u16* __restrict__ VtG,
                                                         u16* __restrict__ O,
                                                         u16* __restrict__ pO,
                                                         float* __restrict__ pL) {
    const int tid = threadIdx.x;
    const int wave = tid >> 6, lane = tid & 63;
    const int half = wave >> 2, w4 = wave & 3;
    int i = blockIdx.x, c, p;
    if (i < 16)      { c = 0; p = i; }
    else if (i < 28) { c = 1; p = i - 16; }
    else if (i < 36) { c = 2; p = i - 28; }
    else             { c = 3; p = i - 36; }
    const int qb = 31 - 2 * p - half;          // A: 31-2p (waves 0-3), B: 30-2p
    const int bh = blockIdx.y;
    const int t0 = qb * 64;
    const int steps = qb + 1;
    const int ktbeg = c * 8;
    int ktend = ktbeg + 8; if (steps < ktend) ktend = steps;        // this half
    const int qbA = 31 - 2 * p;
    int ktend_blk = ktbeg + 8; if (qbA + 1 < ktend_blk) ktend_blk = qbA + 1;
    const size_t base = ((size_t)(bh >> 4) * 2048) * 1024 + (size_t)(bh & 15) * 64;
    const size_t basev = (size_t)bh * 64 * 2048;

    __shared__ __align__(16) u16 Ks[2][64 * 64];
    __shared__ __align__(16) u16 Vt[2][64 * 64];
#if !__has_builtin(__builtin_amdgcn_mfma_f32_16x16x16bf16_1k)
    __shared__ __align__(16) u16 Ps[8][16 * 72];
#endif

    const int l15 = lane & 15, quad = lane >> 4;
    const int rmin = t0 + w4 * 16;             // this wave's 16 q-rows

    // Q fragments (B-operand): lane holds Q[qrow=l15][d = st*32 + quad*8 ..+7]
    short8 qf[2];
    {
        const u16* qp = Q + base + (size_t)(rmin + l15) * 1024 + quad * 8;
        qf[0] = *(const short8*)qp;
        qf[1] = *(const short8*)(qp + 32);
    }

    const int slr = lane >> 3;                 // 0..7
    const int sc8 = (lane & 7) ^ slr;          // swizzled source col-chunk
    const int rb = wave * 8;                   // 8 waves x 8 rows = 64-row tile

    auto stage = [&](int kt, int bufi) {
        gl_lds16(Kg + base + (size_t)(kt * 64 + rb + slr) * 1024 + sc8 * 8,
                 &Ks[bufi][rb * 64 + lane * 8]);
        gl_lds16(VtG + basev + (size_t)(rb + slr) * 2048 + kt * 64 + sc8 * 8,
                 &Vt[bufi][rb * 64 + lane * 8]);
    };

    float l_part = 0.f;
    f32x4 oacc[4];
#pragma unroll
    for (int jt = 0; jt < 4; jt++) oacc[jt] = (f32x4){0.f, 0.f, 0.f, 0.f};

    const float Cs = 0.125f * 1.44269504f;     // scale * log2(e)

    stage(ktbeg, 0);
    __syncthreads();

    for (int kt = ktbeg; kt < ktend_blk; kt++) {
        const int cur = kt & 1;
        if (kt + 1 < ktend_blk) stage(kt + 1, cur ^ 1);   // prefetch overlaps compute

        if (kt < ktend) {
            // K fragments (A-operand): lane holds K[key=j*16+l15][d chunk st*4+quad]
            short8 kf[2][4];
#pragma unroll
            for (int st = 0; st < 2; st++)
#pragma unroll
                for (int j = 0; j < 4; j++)
                    kf[st][j] = *(const short8*)&Ks[cur][(j * 16 + l15) * 64 +
                                                         (((st * 4 + quad) ^ (l15 & 7)) * 8)];
#if __has_builtin(__builtin_amdgcn_mfma_f32_16x16x16bf16_1k)
            // V b64 fragments for 16x16x16 PV
            short4v vf[4][4];
#pragma unroll
            for (int j = 0; j < 4; j++) {
                int k8 = j * 2 + (quad >> 1);      // data key-chunk
#pragma unroll
                for (int jt = 0; jt < 4; jt++) {
                    int d = jt * 16 + l15;
                    vf[j][jt] = *(const short4v*)&Vt[cur][d * 64 + ((k8 ^ (d & 7)) * 8) +
                                                          (quad & 1) * 4];
                }
            }
#else
            short8 vf[2][4];
#pragma unroll
            for (int st = 0; st < 2; st++)
#pragma unroll
                for (int jt = 0; jt < 4; jt++) {
                    int d = jt * 16 + l15;
                    vf[st][jt] = *(const short8*)&Vt[cur][d * 64 + (((st * 4 + quad) ^ (d & 7)) * 8)];
                }
#endif

            // S^T = K Q^T : lane gets qrow=l15, keys j*16+quad*4+r
            f32x4 s[4];
#pragma unroll
            for (int j = 0; j < 4; j++) s[j] = (f32x4){0.f, 0.f, 0.f, 0.f};
#pragma unroll
            for (int st = 0; st < 2; st++)
#pragma unroll
                for (int j = 0; j < 4; j++)
                    s[j] = __builtin_amdgcn_mfma_f32_16x16x32_bf16(kf[st][j], qf[st], s[j], 0, 0, 0);

            // softmax: mask fires only on this half's diagonal step (kt==qb)
            float lpv[4] = {0.f, 0.f, 0.f, 0.f};
            short4v pj[4];
            if (kt != qb) {
#pragma unroll
                for (int j = 0; j < 4; j++) {
                    union { short4v v; u16 u[4]; } pk;
#pragma unroll
                    for (int r = 0; r < 4; r++) {
                        float pv = __builtin_amdgcn_exp2f(s[j][r] * Cs);
                        lpv[r] += pv;
                        pk.u[r] = f2bf_fast(pv);
                    }
                    pj[j] = pk.v;
                }
            } else {
                const int qrow = rmin + l15;
#pragma unroll
                for (int j = 0; j < 4; j++) {
                    union { short4v v; u16 u[4]; } pk;
#pragma unroll
                    for (int r = 0; r < 4; r++) {
                        float pv = __builtin_amdgcn_exp2f(s[j][r] * Cs);
                        int key = kt * 64 + j * 16 + quad * 4 + r;
                        if (key > qrow) pv = 0.f;
                        lpv[r] += pv;
                        pk.u[r] = f2bf_fast(pv);
                    }
                    pj[j] = pk.v;
                }
            }
            l_part += (lpv[0] + lpv[1]) + (lpv[2] + lpv[3]);

#if __has_builtin(__builtin_amdgcn_mfma_f32_16x16x16bf16_1k)
            // O += P V, P straight from registers (A-frag match)
#pragma unroll
            for (int jt = 0; jt < 4; jt++)
#pragma unroll
                for (int j = 0; j < 4; j++)
                    oacc[jt] = __builtin_amdgcn_mfma_f32_16x16x16bf16_1k(pj[j], vf[j][jt],
                                                                         oacc[jt], 0, 0, 0);
#else
            u16* Pw = Ps[wave];
#pragma unroll
            for (int j = 0; j < 4; j++)
                *(short4v*)&Pw[l15 * 72 + j * 16 + quad * 4] = pj[j];
#pragma unroll
            for (int st = 0; st < 2; st++) {
                short8 pf2 = *(const short8*)&Pw[l15 * 72 + st * 32 + quad * 8];
#pragma unroll
                for (int jt = 0; jt < 4; jt++)
                    oacc[jt] = __builtin_amdgcn_mfma_f32_16x16x32_bf16(pf2, vf[st][jt],
                                                                      oacc[jt], 0, 0, 0);
            }
#endif
        }
        __syncthreads();
    }

    // l reduction: l lives per qrow=l15; reduce across quads
    float lf = l_part;
    lf += __shfl_xor(lf, 16, 64);
    lf += __shfl_xor(lf, 32, 64);

    if (steps > 8) {
        // multi-chunk q-block: write un-normalized bf16 partials (v8b layout)
        const size_t ib = ((size_t)bh * 24 + (qb - 8)) * 4 + c;
        u16* po = pO + ib * 4096;
#pragma unroll
        for (int jt = 0; jt < 4; jt++)
#pragma unroll
            for (int r = 0; r < 4; r++)
                po[(w4 * 16 + quad * 4 + r) * 64 + jt * 16 + l15] = f2bf(oacc[jt][r]);
        if (quad == 0) pL[ib * 64 + w4 * 16 + l15] = lf;
        return;
    }

    // single-chunk (qb<=7, c==0): normalize and store bf16
    {
        float inv[4];
#pragma unroll
        for (int r = 0; r < 4; r++) inv[r] = 1.f / __shfl(lf, quad * 4 + r, 64);
#pragma unroll
        for (int jt = 0; jt < 4; jt++) {
            int d = jt * 16 + l15;
#pragma unroll
            for (int r = 0; r < 4; r++) {
                int t = rmin + quad * 4 + r;
                O[base + (size_t)t * 1024 + d] = f2bf(oacc[jt][r] * inv[r]);
            }
        }
    }
}

// ---------------- flash attention v8b (non-split fallback, 256 threads) -----
__global__ __launch_bounds__(256) void flash_kernel(const u16* __restrict__ Q,
                                                    const u16* __restrict__ Kg,
                                                    const u16* __restrict__ VtG,
                                                    u16* __restrict__ O) {
    const int tid = threadIdx.x;
    const int wave = tid >> 6, lane = tid & 63;
    const int qb = 31 - blockIdx.x;
    const int bh = blockIdx.y;
    const int t0 = qb * 64;
    const int steps = qb + 1;
    const size_t base = ((size_t)(bh >> 4) * 2048) * 1024 + (size_t)(bh & 15) * 64;
    const size_t basev = (size_t)bh * 64 * 2048;

    __shared__ __align__(16) u16 Ks[2][64 * 64];
    __shared__ __align__(16) u16 Vt[2][64 * 64];
#if !__has_builtin(__builtin_amdgcn_mfma_f32_16x16x16bf16_1k)
    __shared__ __align__(16) u16 Ps[4][16 * 72];
#endif

    const int l15 = lane & 15, quad = lane >> 4;
    const int rmin = t0 + wave * 16;

    short8 qf[2];
    {
        const u16* qp = Q + base + (size_t)(rmin + l15) * 1024 + quad * 8;
        qf[0] = *(const short8*)qp;
        qf[1] = *(const short8*)(qp + 32);
    }

    const int slr = lane >> 3;
    const int sc8 = (lane & 7) ^ slr;
    const int rb = wave * 16;

    auto stage = [&](int kt, int bufi) {
        gl_lds16(Kg + base + (size_t)(kt * 64 + rb + slr) * 1024 + sc8 * 8,
                 &Ks[bufi][rb * 64 + lane * 8]);
        gl_lds16(Kg + base + (size_t)(kt * 64 + rb + 8 + slr) * 1024 + sc8 * 8,
                 &Ks[bufi][(rb + 8) * 64 + lane * 8]);
        gl_lds16(VtG + basev + (size_t)(rb + slr) * 2048 + kt * 64 + sc8 * 8,
                 &Vt[bufi][rb * 64 + lane * 8]);
        gl_lds16(VtG + basev + (size_t)(rb + 8 + slr) * 2048 + kt * 64 + sc8 * 8,
                 &Vt[bufi][(rb + 8) * 64 + lane * 8]);
    };

    float l_part = 0.f;
    f32x4 oacc[4];
#pragma unroll
    for (int jt = 0; jt < 4; jt++) oacc[jt] = (f32x4){0.f, 0.f, 0.f, 0.f};

    const float Cs = 0.125f * 1.44269504f;

    stage(0, 0);
    __syncthreads();

    for (int kt = 0; kt < steps; kt++) {
        const int cur = kt & 1;
        if (kt + 1 < steps) stage(kt + 1, cur ^ 1);

        short8 kf[2][4];
#pragma unroll
        for (int st = 0; st < 2; st++)
#pragma unroll
            for (int j = 0; j < 4; j++)
                kf[st][j] = *(const short8*)&Ks[cur][(j * 16 + l15) * 64 +
                                                     (((st * 4 + quad) ^ (l15 & 7)) * 8)];
#if __has_builtin(__builtin_amdgcn_mfma_f32_16x16x16bf16_1k)
        short4v vf[4][4];
#pragma unroll
        for (int j = 0; j < 4; j++) {
            int k8 = j * 2 + (quad >> 1);
#pragma unroll
            for (int jt = 0; jt < 4; jt++) {
                int d = jt * 16 + l15;
                vf[j][jt] = *(const short4v*)&Vt[cur][d * 64 + ((k8 ^ (d & 7)) * 8) +
                                                      (quad & 1) * 4];
            }
        }
#else
        short8 vf[2][4];
#pragma unroll
        for (int st = 0; st < 2; st++)
#pragma unroll
            for (int jt = 0; jt < 4; jt++) {
                int d = jt * 16 + l15;
                vf[st][jt] = *(const short8*)&Vt[cur][d * 64 + (((st * 4 + quad) ^ (d & 7)) * 8)];
            }
#endif

        f32x4 s[4];
#pragma unroll
        for (int j = 0; j < 4; j++) s[j] = (f32x4){0.f, 0.f, 0.f, 0.f};
#pragma unroll
        for (int st = 0; st < 2; st++)
#pragma unroll
            for (int j = 0; j < 4; j++)
                s[j] = __builtin_amdgcn_mfma_f32_16x16x32_bf16(kf[st][j], qf[st], s[j], 0, 0, 0);

        float lpv[4] = {0.f, 0.f, 0.f, 0.f};
        short4v pj[4];
        if (kt != qb) {
#pragma unroll
            for (int j = 0; j < 4; j++) {
                union { short4v v; u16 u[4]; } pk;
#pragma unroll
                for (int r = 0; r < 4; r++) {
                    float pv = __builtin_amdgcn_exp2f(s[j][r] * Cs);
                    lpv[r] += pv;
                    pk.u[r] = f2bf_fast(pv);
                }
                pj[j] = pk.v;
            }
        } else {
            const int qrow = rmin + l15;
#pragma unroll
            for (int j = 0; j < 4; j++) {
                union { short4v v; u16 u[4]; } pk;
#pragma unroll
                for (int r = 0; r < 4; r++) {
                    float pv = __builtin_amdgcn_exp2f(s[j][r] * Cs);
                    int key = kt * 64 + j * 16 + quad * 4 + r;
                    if (key > qrow) pv = 0.f;
                    lpv[r] += pv;
                    pk.u[r] = f2bf_fast(pv);
                }
                pj[j] = pk.v;
            }
        }
        l_part += (lpv[0] + lpv[1]) + (lpv[2] + lpv[3]);

#if __has_builtin(__builtin_amdgcn_mfma_f32_16x16x16bf16_1k)
#pragma unroll
        for (int jt = 0; jt < 4; jt++)
#pragma unroll
            for (int j = 0; j < 4; j++)
                oacc[jt] = __builtin_amdgcn_mfma_f32_16x16x16bf16_1k(pj[j], vf[j][jt],
                                                                     oacc[jt], 0, 0, 0);
#else
        u16* Pw = Ps[wave];
#pragma unroll
        for (int j = 0; j < 4; j++)
            *(short4v*)&Pw[l15 * 72 + j * 16 + quad * 4] = pj[j];
#pragma unroll
        for (int st = 0; st < 2; st++) {
            short8 pf2 = *(const short8*)&Pw[l15 * 72 + st * 32 + quad * 8];
#pragma unroll
            for (int jt = 0; jt < 4; jt++)
                oacc[jt] = __builtin_amdgcn_mfma_f32_16x16x32_bf16(pf2, vf[st][jt],
                                                                  oacc[jt], 0, 0, 0);
        }
#endif
        __syncthreads();
    }

    float lf = l_part;
    lf += __shfl_xor(lf, 16, 64);
    lf += __shfl_xor(lf, 32, 64);
    float inv[4];
#pragma unroll
    for (int r = 0; r < 4; r++) inv[r] = 1.f / __shfl(lf, quad * 4 + r, 64);
#pragma unroll
    for (int jt = 0; jt < 4; jt++) {
        int d = jt * 16 + l15;
#pragma unroll
        for (int r = 0; r < 4; r++) {
            int t = rmin + quad * 4 + r;
            O[base + (size_t)t * 1024 + d] = f2bf(oacc[jt][r] * inv[r]);
        }
    }
}

// ---------------- flash combine: O = (sum_c O_c) / (sum_c l_c) --------------
__global__ __launch_bounds__(256) void flash_combine_kernel(const u16* __restrict__ pO,
                                                            const float* __restrict__ pL,
                                                            u16* __restrict__ O) {
    const int qj = blockIdx.x;                 // 0..23 -> qb = qj + 8
    const int bh = blockIdx.y;
    const int qb = qj + 8;
    const int nch = (qb >> 3) + 1;             // 2, 3 or 4 chunks
    const int tid = threadIdx.x;
    const int row = tid >> 2;                  // 0..63
    const int d0 = (tid & 3) * 16;
    const size_t ib = ((size_t)bh * 24 + qj) * 4;

    float acc[16];
#pragma unroll
    for (int k = 0; k < 16; k++) acc[k] = 0.f;
    float lsum = 0.f;
    for (int c = 0; c < nch; c++) {
        const u16* po = pO + (ib + c) * 4096 + row * 64 + d0;
        u16 pb[16];
        *(uint4*)pb = *(const uint4*)po;
        *(uint4*)(pb + 8) = *(const uint4*)(po + 8);
#pragma unroll
        for (int k = 0; k < 16; k++) acc[k] += bf2f(pb[k]);
        lsum += pL[(ib + c) * 64 + row];
    }
    const float inv = 1.f / lsum;
    u16 o[16];
#pragma unroll
    for (int k = 0; k < 16; k++) o[k] = f2bf(acc[k] * inv);
    const size_t base = ((size_t)(bh >> 4) * 2048) * 1024 + (size_t)(bh & 15) * 64;
    const int t = qb * 64 + row;
    u16* op = &O[base + (size_t)t * 1024 + d0];
    *(uint4*)op = ((uint4*)o)[0];
    *(uint4*)(op + 8) = ((uint4*)o)[1];
}

extern "C" void kernel_launch(void* const* d_in, const int* in_sizes, int n_in,
                              void* d_out, int out_size, void* d_ws, size_t ws_size,
                              hipStream_t stream) {
    (void)in_sizes; (void)n_in; (void)out_size;
    const void* x   = d_in[0];
    // d_in[1] = attn_mask (int32, pure causal) -- implemented directly
    const void* Wq  = d_in[2];  const void* bq  = d_in[3];
    const void* Wk  = d_in[4];  const void* bk  = d_in[5];
    const void* Wv  = d_in[6];  const void* bv  = d_in[7];
    const void* Wo  = d_in[8];  const void* bo  = d_in[9];
    const void* g1  = d_in[10]; const void* be1 = d_in[11];
    const void* g2  = d_in[12]; const void* be2 = d_in[13];
    const void* W1  = d_in[14]; const void* bf1 = d_in[15];
    const void* W2  = d_in[16]; const void* bf2 = d_in[17];
    const void* Wd  = d_in[18]; const void* bd  = d_in[19];
    const void* Wu  = d_in[20]; const void* bu  = d_in[21];

    uint8_t* w8 = (uint8_t*)d_ws;
    int* flag = (int*)w8;                    // 64 B header
    float* pf = (float*)(w8 + 64);           // f32 param pool
    u16* wsb = (u16*)(w8 + 64 + 65536);      // bf16 arena

    const size_t M1 = 1024ull * 1024ull;
    u16* WqT = wsb;                          // Wq/Wk/Wv transposed, contiguous 3072xK
    u16* WkT = wsb + 1 * M1;
    u16* WvT = wsb + 2 * M1;
    u16* WoT = wsb + 3 * M1;
    u16* W1T = wsb + 4 * M1;                 // 4M
    u16* W2T = wsb + 8 * M1;                 // 4M
    u16* WdT = wsb + 12 * M1;                // 64K
    u16* WuT = wsb + 12 * M1 + 65536;        // 64K
    u16* S0  = wsb + 12 * M1 + 131072;
    u16* Areg = S0;                          // xb
    u16* Breg = S0 + 4 * M1;                 // xn -> attn
    u16* ff1  = S0;                          // 16M spans Areg+Breg+8M fresh
    u16* Creg = S0 + 16 * M1;                // q -> xn2
    u16* Dreg = S0 + 20 * M1;                // k -> x1
    u16* Ereg = S0 + 24 * M1;                // VtG -> hh
    u16* xb = Areg;
    u16* xn = Breg; u16* attn = Breg;
    u16* q = Creg;  u16* xn2 = Creg;
    u16* kk_ = Dreg; u16* x1 = Dreg;
    u16* VtG = Ereg; u16* hh = Ereg;

    // f32 partial buffer after the bf16 arena
    // (time-shared: flash partials [24MB bf16 O + 1MB f32 l] -> FFN2 split-K)
    const size_t arena_bytes = (size_t)(64 + 65536) + (40 * M1 + 131072) * 2;
    float* partf = (float*)(w8 + ((arena_bytes + 255) & ~(size_t)255));
    const size_t need = ((arena_bytes + 255) & ~(size_t)255) + 4ull * 4 * M1 * 4;
    const bool sk = ws_size >= need;
    float* flL = partf + 14 * M1;            // flash l partials at +56MB

    float* bqkv_f = pf + 0;    // bq,bk,bv contiguous (3072)
    float* bo_f  = pf + 3072;
    float* bf1_f = pf + 4096;  float* bf2_f = pf + 8192;
    float* bd_f  = pf + 9216;  float* bu_f  = pf + 9280;
    float* g1_f  = pf + 10304; float* be1_f = pf + 11328;
    float* g2_f  = pf + 12352; float* be2_f = pf + 13376;

    // merged prologue: detect + param convert + weight transpose (1 launch)
    Prologue P;
    const void* tsrc[8] = {Wq, Wk, Wv, Wo, W1, W2, Wd, Wu};
    u16* tdst[8] = {WqT, WkT, WvT, WoT, W1T, W2T, WdT, WuT};
    int tR[8] = {1024, 1024, 1024, 1024, 1024, 4096, 1024, 64};
    int tC[8] = {1024, 1024, 1024, 1024, 4096, 1024, 64, 1024};
    int acc_off = 0;
    for (int i = 0; i < 8; i++) {
        P.tsrc[i] = tsrc[i]; P.tdst[i] = tdst[i];
        P.tR[i] = tR[i]; P.tC[i] = tC[i];
        P.toff[i] = acc_off;
        acc_off += (tR[i] >> 5) * (tC[i] >> 5);
    }
    P.ntrans = acc_off;
    const void* psrc[12] = {bq, bk, bv, bo, bf1, bf2, bd, bu, g1, be1, g2, be2};
    int poff[12] = {0, 1024, 2048, 3072, 4096, 8192, 9216, 9280, 10304, 11328, 12352, 13376};
    int pn[12]   = {1024, 1024, 1024, 1024, 4096, 1024, 64, 1024, 1024, 1024, 1024, 1024};
    for (int i = 0; i < 12; i++) { P.psrc[i] = psrc[i]; P.poff[i] = poff[i]; P.pn[i] = pn[i]; }
    prologue_kernel<<<acc_off + 12, 256, 0, stream>>>(P, (const unsigned*)x, flag, pf);

    // fused x-convert + LN1: writes xb (bf16 x) and xn in one pass
    ln_x_kernel<<<4096, 256, 0, stream>>>(x, g1_f, be1_f, xb, xn, flag);
    // TAG 0: fused QKV (N=3072, V transposed per-head into VtG), 768 blocks
    gemm128_kernel<0><<<dim3(24, 32), 512, 0, stream>>>(xn, WqT, bqkv_f, nullptr, nullptr,
                                                        q, kk_, VtG, 4096, 3072, 1024, 0, 2, 0, flag);
    if (sk) {
        flash_pair_kernel<<<dim3(40, 32), 512, 0, stream>>>(q, kk_, VtG, attn, (u16*)partf, flL);
        flash_combine_kernel<<<dim3(24, 32), 256, 0, stream>>>((const u16*)partf, flL, attn);
    } else {
        flash_kernel<<<dim3(32, 32), 256, 0, stream>>>(q, kk_, VtG, attn);
    }
    // TAG 1: Wo projection + bias + residual, BK=128 deep kernel + XCD swizzle
    gemm128d_kernel<1><<<dim3(8, 32), 512, 0, stream>>>(attn, WoT, bo_f, xb,
                                                        x1, 1024, 1024, 0, 1);
    ln_kernel<<<4096, 256, 0, stream>>>(x1, g2_f, be2_f, xn2);
    // TAG 2: FFN1 (relu), 256x256 tile / 128x64 waves
    gemm256w_kernel<2><<<dim3(16, 16), 512, 0, stream>>>(xn2, W1T, bf1_f,
                                                         ff1, 4096, 1024, 1);
    // TAG 3: FFN2, split-K 2 on the BK=64 pipeline (2 blk/CU resident) +
    // r14-verified reduce (+bias). Partials in partf (free after combine).
    if (sk) {
        gemm128s_kernel<3><<<dim3(8, 32, 2), 512, 0, stream>>>(ff1, W2T, partf,
                                                               4096, 1024, 4096, 2048);
        reduce_kernel<3><<<4096, 256, 0, stream>>>(partf, 2, (size_t)4096 * 1024, bf2_f, 1024,
                                                   nullptr, nullptr, hh, 0, 0, flag);
    } else {
        gemm128d_kernel<3><<<dim3(8, 32), 512, 0, stream>>>(ff1, W2T, bf2_f, nullptr,
                                                            hh, 1024, 4096, 0, 1);
    }
    // fused adapter: replaces TAG4 + reduce + TAG5 (3 launches -> 1)
    adapter_kernel<<<256, 512, 0, stream>>>(hh, x1, WdT, WuT, bd_f, bu_f, d_out, flag);
}

// Round 21
// 401.178 us; speedup vs baseline: 1.0271x; 1.0271x over previous
//
#include <hip/hip_runtime.h>
#include <cstdint>
#include <cstddef>

typedef unsigned short u16;
typedef __attribute__((ext_vector_type(4))) short short4v;
typedef __attribute__((ext_vector_type(8))) short short8;
typedef __attribute__((ext_vector_type(4))) float f32x4;

__device__ __forceinline__ float bf2f(u16 h) { return __uint_as_float(((unsigned)h) << 16); }
__device__ __forceinline__ u16 f2bf(float f) {
    unsigned u = __float_as_uint(f);
    unsigned r = (u + 0x7fffu + ((u >> 16) & 1u)) >> 16;
    return (u16)r;
}
// round-half-up: <=0.5 ULP, 2 VALU ops (flash inner loop)
__device__ __forceinline__ u16 f2bf_fast(float f) {
    return (u16)((__float_as_uint(f) + 0x8000u) >> 16);
}

__device__ __forceinline__ void gl_lds16(const void* g, void* l) {
    __builtin_amdgcn_global_load_lds((const __attribute__((address_space(1))) void*)g,
                                     (__attribute__((address_space(3))) void*)l, 16, 0, 0);
}

// ---------------- merged prologue: detect + param-cvt + weight transpose ----
struct Prologue {
    const void* tsrc[8];
    u16* tdst[8];
    int tR[8], tC[8], toff[8];
    const void* psrc[12];
    int poff[12], pn[12];
    int ntrans;
};
__global__ __launch_bounds__(256) void prologue_kernel(Prologue P,
                                                       const unsigned* __restrict__ x,
                                                       int* __restrict__ flag,
                                                       float* __restrict__ pf) {
    // self-detect dtype (1024 samples of x's low u16: bf16 exponent-field test)
    __shared__ int cnt[256];
    int c = 0;
    for (int i = threadIdx.x; i < 1024; i += 256) {
        unsigned lo = x[i] & 0xFFFFu;
        unsigned e = (lo >> 7) & 0xFFu;
        c += (e >= 100u && e <= 150u) ? 1 : 0;
    }
    cnt[threadIdx.x] = c;
    __syncthreads();
    for (int s = 128; s > 0; s >>= 1) {
        if (threadIdx.x < s) cnt[threadIdx.x] += cnt[threadIdx.x + s];
        __syncthreads();
    }
    const int bf = (cnt[0] > 512) ? 1 : 0;
    if (blockIdx.x == 0 && threadIdx.x == 0) *flag = bf;

    const int bid = blockIdx.x;
    if (bid >= P.ntrans) {
        const int s = bid - P.ntrans;
        const void* sp = P.psrc[s];
        float* dp = pf + P.poff[s];
        const int n = P.pn[s];
        for (int i = threadIdx.x; i < n; i += 256)
            dp[i] = bf ? bf2f(((const u16*)sp)[i]) : ((const float*)sp)[i];
        return;
    }
    __shared__ u16 tile[32][33];
    int m = 0;
#pragma unroll
    for (int i = 1; i < 8; i++) m = (bid >= P.toff[i]) ? i : m;
    const int local = bid - P.toff[m];
    const int R = P.tR[m], C = P.tC[m];
    const int tilesx = C >> 5;
    const int bx = local % tilesx, by = local / tilesx;
    const void* src = P.tsrc[m];
    u16* dst = P.tdst[m];
    const int tx = threadIdx.x & 31, ty = threadIdx.x >> 5;   // ty 0..7
#pragma unroll
    for (int i = 0; i < 32; i += 8) {
        size_t idx = (size_t)(by * 32 + ty + i) * C + bx * 32 + tx;
        tile[ty + i][tx] = bf ? ((const u16*)src)[idx] : f2bf(((const float*)src)[idx]);
    }
    __syncthreads();
#pragma unroll
    for (int i = 0; i < 32; i += 8)
        dst[(size_t)(bx * 32 + ty + i) * R + by * 32 + tx] = tile[tx][ty + i];
}

// ---------------- fused x-convert + LayerNorm (first LN) --------------------
__global__ __launch_bounds__(256) void ln_x_kernel(const void* __restrict__ X,
                                                   const float* __restrict__ G,
                                                   const float* __restrict__ Be,
                                                   u16* __restrict__ Xb,
                                                   u16* __restrict__ Y,
                                                   const int* __restrict__ flag) {
    const int row = blockIdx.x;
    const int tid = threadIdx.x;
    const int lane = tid & 63, wave = tid >> 6;
    u16 vbuf[4];
    if (*flag) {
        *(uint2*)vbuf = *(const uint2*)((const u16*)X + (size_t)row * 1024 + tid * 4);
    } else {
        float4 v = *(const float4*)((const float*)X + (size_t)row * 1024 + tid * 4);
        vbuf[0] = f2bf(v.x); vbuf[1] = f2bf(v.y); vbuf[2] = f2bf(v.z); vbuf[3] = f2bf(v.w);
    }
    *(uint2*)&Xb[(size_t)row * 1024 + tid * 4] = *(uint2*)vbuf;
    float f[4];
    float s = 0.f, sq = 0.f;
#pragma unroll
    for (int j = 0; j < 4; j++) { f[j] = bf2f(vbuf[j]); s += f[j]; sq += f[j] * f[j]; }
#pragma unroll
    for (int m = 1; m < 64; m <<= 1) { s += __shfl_xor(s, m, 64); sq += __shfl_xor(sq, m, 64); }
    __shared__ float rs_[4], rq_[4];
    if (lane == 0) { rs_[wave] = s; rq_[wave] = sq; }
    __syncthreads();
    float S = rs_[0] + rs_[1] + rs_[2] + rs_[3];
    float Q2 = rq_[0] + rq_[1] + rq_[2] + rq_[3];
    float mean = S * (1.f / 1024.f);
    float var = Q2 * (1.f / 1024.f) - mean * mean;
    float rstd = rsqrtf(var + 1e-5f);
    u16 o[4];
#pragma unroll
    for (int j = 0; j < 4; j++) {
        int c2 = tid * 4 + j;
        float y = (f[j] - mean) * rstd * G[c2] + Be[c2];
        o[j] = f2bf(y);
    }
    *(uint2*)&Y[(size_t)row * 1024 + tid * 4] = *(uint2*)o;
}

// ---------------- LayerNorm over C=1024 (bf16 in, f32 params, bf16 out) -----
__global__ __launch_bounds__(256) void ln_kernel(const u16* __restrict__ X,
                                                 const float* __restrict__ G,
                                                 const float* __restrict__ Be,
                                                 u16* __restrict__ Y) {
    const int row = blockIdx.x;
    const int tid = threadIdx.x;
    const int lane = tid & 63, wave = tid >> 6;
    const u16* xr = X + (size_t)row * 1024;
    u16 vbuf[4];
    *(uint2*)vbuf = *(const uint2*)&xr[tid * 4];
    float f[4];
    float s = 0.f, sq = 0.f;
#pragma unroll
    for (int j = 0; j < 4; j++) { f[j] = bf2f(vbuf[j]); s += f[j]; sq += f[j] * f[j]; }
#pragma unroll
    for (int m = 1; m < 64; m <<= 1) { s += __shfl_xor(s, m, 64); sq += __shfl_xor(sq, m, 64); }
    __shared__ float rs_[4], rq_[4];
    if (lane == 0) { rs_[wave] = s; rq_[wave] = sq; }
    __syncthreads();
    float S = rs_[0] + rs_[1] + rs_[2] + rs_[3];
    float Q2 = rq_[0] + rq_[1] + rq_[2] + rq_[3];
    float mean = S * (1.f / 1024.f);
    float var = Q2 * (1.f / 1024.f) - mean * mean;
    float rstd = rsqrtf(var + 1e-5f);
    u16 o[4];
#pragma unroll
    for (int j = 0; j < 4; j++) {
        int c2 = tid * 4 + j;
        float y = (f[j] - mean) * rstd * G[c2] + Be[c2];
        o[j] = f2bf(y);
    }
    *(uint2*)&Y[(size_t)row * 1024 + tid * 4] = *(uint2*)o;
}

// ---------------- GEMM 128x128 / 8 waves, K-region pipeline, 1 barrier ------
// Round-8 verified kernel. BK=64, 8 waves (32x64/wave), 64KB LDS -> 2 blk/CU
// where the grid supplies them. One barrier per phase. Calendar: t.ph0 stages
// (t+1,k1), waits vmcnt(4) [tail 0]; t.ph1 stages (t+2,k0), waits vmcnt(4)
// [tail 2]. Swizzle involution phys_chunk = logical ^ ((rsub>>1)&3) on BOTH
// global source and ds_read (rule #21).
template <int TAG>
__global__ __launch_bounds__(512, 4) void gemm128_kernel(const u16* __restrict__ A,
                                                         const u16* __restrict__ Bt,
                                                         const float* __restrict__ bias,
                                                         const u16* __restrict__ res1,
                                                         const u16* __restrict__ res2,
                                                         void* __restrict__ out,
                                                         void* __restrict__ out_k,
                                                         void* __restrict__ out_v,
                                                         int M, int N, int K, int relu, int mode,
                                                         int swz,
                                                         const int* __restrict__ flag) {
    (void)flag; (void)M;
    __shared__ __align__(16) u16 As[2][2][128 * 32];   // [buf][kh][row*32+chunk*8] = 8KB each
    __shared__ __align__(16) u16 Bs[2][2][128 * 32];
    const int tid = threadIdx.x;
    const int wave = tid >> 6, lane = tid & 63;
    const int l15 = lane & 15, quad = lane >> 4;
    const int wr = wave & 3, wc = wave >> 2;           // 4x2 wave grid: 32x64 per wave
    int bx = blockIdx.x, by = blockIdx.y;
    if (swz) {
        const int gx = gridDim.x;
        const int nwg = gx * gridDim.y;
        const int bid = by * gx + bx;
        const int sbid = (bid & 7) * (nwg >> 3) + (bid >> 3);  // XCD-chunked, bijective
        bx = sbid % gx;
        by = sbid / gx;
    }
    const int m0 = by * 128, n0 = bx * 128;
    const int nt = K >> 6;

    const int rsub = lane >> 2;                        // 0..15
    const int logc = (lane & 3) ^ ((rsub >> 1) & 3);

    auto stage_pair = [&](int t, int kh) {
        const int buf = t & 1;
        const int kk = (t << 6) + (kh << 5) + logc * 8;
        const int roff = wave * 16 + rsub;
        gl_lds16(A + (size_t)(m0 + roff) * K + kk, &As[buf][kh][wave * 512 + lane * 8]);
        gl_lds16(Bt + (size_t)(n0 + roff) * K + kk, &Bs[buf][kh][wave * 512 + lane * 8]);
    };

    f32x4 acc[2][4];
#pragma unroll
    for (int i = 0; i < 2; i++)
#pragma unroll
        for (int j = 0; j < 4; j++) acc[i][j] = (f32x4){0.f, 0.f, 0.f, 0.f};

    stage_pair(0, 0);
    stage_pair(0, 1);
    stage_pair(1, 0);
    asm volatile("s_waitcnt vmcnt(4)" ::: "memory");
    __builtin_amdgcn_s_barrier();

    const int rx = (l15 >> 1) & 3;                     // read-side involution
    for (int t = 0; t < nt; t++) {
        const int b = t & 1;
#pragma unroll
        for (int ph = 0; ph < 2; ph++) {
            const int kh = ph;
            short8 af[2], bfr[4];
#pragma unroll
            for (int i = 0; i < 2; i++)
                af[i] = *(const short8*)&As[b][kh][(wr * 32 + i * 16 + l15) * 32 +
                                                   ((quad ^ rx) << 3)];
#pragma unroll
            for (int j = 0; j < 4; j++)
                bfr[j] = *(const short8*)&Bs[b][kh][(wc * 64 + j * 16 + l15) * 32 +
                                                    ((quad ^ rx) << 3)];
            if (ph == 0) { if (t + 1 < nt) stage_pair(t + 1, 1); }
            else         { if (t + 2 < nt) stage_pair(t + 2, 0); }
            __builtin_amdgcn_s_setprio(1);
#pragma unroll
            for (int i = 0; i < 2; i++)
#pragma unroll
                for (int j = 0; j < 4; j++)
                    acc[i][j] = __builtin_amdgcn_mfma_f32_16x16x32_bf16(
                        af[i], bfr[j], acc[i][j], 0, 0, 0);
            __builtin_amdgcn_s_setprio(0);
            if (ph == 0) {
                if (t + 1 < nt) { asm volatile("s_waitcnt vmcnt(4)" ::: "memory"); }
                else            { asm volatile("s_waitcnt vmcnt(0)" ::: "memory"); }
            } else {
                if (t + 2 < nt)      { asm volatile("s_waitcnt vmcnt(4)" ::: "memory"); }
                else if (t + 1 < nt) { asm volatile("s_waitcnt vmcnt(2)" ::: "memory"); }
            }
            __builtin_amdgcn_s_barrier();
        }
    }

    // epilogue: C/D layout col=lane&15, row=quad*4+r (m89-verified)
    if (mode == 2) {
        const int region = n0 >> 10;
        if (region < 2) {
            u16* o = (u16*)(region == 0 ? out : out_k);
#pragma unroll
            for (int j = 0; j < 4; j++) {
                const int col = n0 + wc * 64 + j * 16 + l15;
                const float bv = bias[col];
                const int cl = col & 1023;
#pragma unroll
                for (int i = 0; i < 2; i++) {
                    const int row0 = m0 + wr * 32 + i * 16 + quad * 4;
#pragma unroll
                    for (int r = 0; r < 4; r++)
                        o[(size_t)(row0 + r) * 1024 + cl] = f2bf(acc[i][j][r] + bv);
                }
            }
        } else {
            u16* o = (u16*)out_v;
#pragma unroll
            for (int j = 0; j < 4; j++) {
                const int col = n0 + wc * 64 + j * 16 + l15;
                const float bv = bias[col];
                const int cl = col & 1023;
                const int h = cl >> 6, d = cl & 63;
#pragma unroll
                for (int i = 0; i < 2; i++) {
                    const int row_base = m0 + wr * 32 + i * 16 + quad * 4;
                    const int bb = row_base >> 11, tt = row_base & 2047;
                    u16 pk[4];
#pragma unroll
                    for (int r = 0; r < 4; r++) pk[r] = f2bf(acc[i][j][r] + bv);
                    *(uint2*)&o[(((size_t)bb * 16 + h) * 64 + d) * 2048 + tt] = *(uint2*)pk;
                }
            }
        }
        return;
    }
    // mode 0: bias [+relu] [+res] -> bf16
#pragma unroll
    for (int j = 0; j < 4; j++) {
        const int col = n0 + wc * 64 + j * 16 + l15;
        const float bv = bias ? bias[col] : 0.f;
#pragma unroll
        for (int i = 0; i < 2; i++) {
            const int row0 = m0 + wr * 32 + i * 16 + quad * 4;
#pragma unroll
            for (int r = 0; r < 4; r++) {
                float v = acc[i][j][r] + bv;
                if (relu) v = fmaxf(v, 0.f);
                const size_t idx = (size_t)(row0 + r) * N + col;
                if (res1) v += bf2f(res1[idx]);
                if (res2) v += bf2f(res2[idx]);
                ((u16*)out)[idx] = f2bf(v);
            }
        }
    }
}

// ---------------- GEMM 128x128 SPLIT-K: BK=64 pipeline, f32 partials --------
// FFN2 path. r20 regression diagnosis: split-K delivered the occupancy
// (19->34%) but FETCH exploded 50->139MB -- the exact un-swizzled-FFN2
// signature r7 measured (137MB) and fixed with the XCD-chunked remap.
// gemm128s was the only GEMM without it. Swizzle over (bx,by) only
// (nwg=256, %8==0); z-layers read disjoint K-halves so z stays direct.
template <int TAG>
__global__ __launch_bounds__(512, 4) void gemm128s_kernel(const u16* __restrict__ A,
                                                          const u16* __restrict__ Bt,
                                                          float* __restrict__ out,
                                                          int M, int N, int K, int Ksub) {
    __shared__ __align__(16) u16 As[2][2][128 * 32];
    __shared__ __align__(16) u16 Bs[2][2][128 * 32];
    const int tid = threadIdx.x;
    const int wave = tid >> 6, lane = tid & 63;
    const int l15 = lane & 15, quad = lane >> 4;
    const int wr = wave & 3, wc = wave >> 2;           // 4x2 wave grid: 32x64 per wave
    int bx = blockIdx.x, by = blockIdx.y;
    {
        const int gx = gridDim.x;
        const int nwg = gx * gridDim.y;
        const int bid = by * gx + bx;
        const int sbid = (bid & 7) * (nwg >> 3) + (bid >> 3);  // XCD-chunked, bijective
        bx = sbid % gx;
        by = sbid / gx;
    }
    const int m0 = by * 128, n0 = bx * 128;
    const int kbeg = blockIdx.z * Ksub;
    const int nt = Ksub >> 6;

    const int rsub = lane >> 2;                        // 0..15
    const int logc = (lane & 3) ^ ((rsub >> 1) & 3);

    auto stage_pair = [&](int t, int kh) {
        const int buf = t & 1;
        const int kk = kbeg + (t << 6) + (kh << 5) + logc * 8;
        const int roff = wave * 16 + rsub;
        gl_lds16(A + (size_t)(m0 + roff) * K + kk, &As[buf][kh][wave * 512 + lane * 8]);
        gl_lds16(Bt + (size_t)(n0 + roff) * K + kk, &Bs[buf][kh][wave * 512 + lane * 8]);
    };

    f32x4 acc[2][4];
#pragma unroll
    for (int i = 0; i < 2; i++)
#pragma unroll
        for (int j = 0; j < 4; j++) acc[i][j] = (f32x4){0.f, 0.f, 0.f, 0.f};

    stage_pair(0, 0);
    stage_pair(0, 1);
    stage_pair(1, 0);
    asm volatile("s_waitcnt vmcnt(4)" ::: "memory");
    __builtin_amdgcn_s_barrier();

    const int rx = (l15 >> 1) & 3;                     // read-side involution
    for (int t = 0; t < nt; t++) {
        const int b = t & 1;
#pragma unroll
        for (int ph = 0; ph < 2; ph++) {
            const int kh = ph;
            short8 af[2], bfr[4];
#pragma unroll
            for (int i = 0; i < 2; i++)
                af[i] = *(const short8*)&As[b][kh][(wr * 32 + i * 16 + l15) * 32 +
                                                   ((quad ^ rx) << 3)];
#pragma unroll
            for (int j = 0; j < 4; j++)
                bfr[j] = *(const short8*)&Bs[b][kh][(wc * 64 + j * 16 + l15) * 32 +
                                                    ((quad ^ rx) << 3)];
            if (ph == 0) { if (t + 1 < nt) stage_pair(t + 1, 1); }
            else         { if (t + 2 < nt) stage_pair(t + 2, 0); }
            __builtin_amdgcn_s_setprio(1);
#pragma unroll
            for (int i = 0; i < 2; i++)
#pragma unroll
                for (int j = 0; j < 4; j++)
                    acc[i][j] = __builtin_amdgcn_mfma_f32_16x16x32_bf16(
                        af[i], bfr[j], acc[i][j], 0, 0, 0);
            __builtin_amdgcn_s_setprio(0);
            if (ph == 0) {
                if (t + 1 < nt) { asm volatile("s_waitcnt vmcnt(4)" ::: "memory"); }
                else            { asm volatile("s_waitcnt vmcnt(0)" ::: "memory"); }
            } else {
                if (t + 2 < nt)      { asm volatile("s_waitcnt vmcnt(4)" ::: "memory"); }
                else if (t + 1 < nt) { asm volatile("s_waitcnt vmcnt(2)" ::: "memory"); }
            }
            __builtin_amdgcn_s_barrier();
        }
    }

    // epilogue: f32 partials, no bias (m89-verified C/D layout)
    float* po = out + (size_t)blockIdx.z * M * N;
#pragma unroll
    for (int j = 0; j < 4; j++) {
        const int col = n0 + wc * 64 + j * 16 + l15;
#pragma unroll
        for (int i = 0; i < 2; i++) {
            const int row0 = m0 + wr * 32 + i * 16 + quad * 4;
#pragma unroll
            for (int r = 0; r < 4; r++)
                po[(size_t)(row0 + r) * N + col] = acc[i][j][r];
        }
    }
}

// ---------------- split-K reduce: out = f(sum_z part[z]) (r14-verified) -----
template <int TAG>
__global__ __launch_bounds__(256) void reduce_kernel(const float* __restrict__ part,
                                                     int nsplit, size_t MN,
                                                     const float* __restrict__ bias, int N,
                                                     const u16* __restrict__ res1,
                                                     const u16* __restrict__ res2,
                                                     void* __restrict__ out,
                                                     int relu, int final_store,
                                                     const int* __restrict__ flag) {
    const size_t i0 = ((size_t)blockIdx.x * 256 + threadIdx.x) * 4;
    float4 s = *(const float4*)&part[i0];
    for (int z = 1; z < nsplit; z++) {
        float4 p = *(const float4*)&part[(size_t)z * MN + i0];
        s.x += p.x; s.y += p.y; s.z += p.z; s.w += p.w;
    }
    const int col = (int)(i0 & (size_t)(N - 1));
    float v[4] = {s.x, s.y, s.z, s.w};
#pragma unroll
    for (int j = 0; j < 4; j++) {
        v[j] += bias[col + j];
        if (relu) v[j] = fmaxf(v[j], 0.f);
    }
    if (res1) {
        u16 r[4]; *(uint2*)r = *(const uint2*)&res1[i0];
#pragma unroll
        for (int j = 0; j < 4; j++) v[j] += bf2f(r[j]);
    }
    if (res2) {
        u16 r[4]; *(uint2*)r = *(const uint2*)&res2[i0];
#pragma unroll
        for (int j = 0; j < 4; j++) v[j] += bf2f(r[j]);
    }
    if (final_store && (*flag == 0)) {
        *(float4*)&((float*)out)[i0] = (float4){v[0], v[1], v[2], v[3]};
    } else {
        u16 o[4];
#pragma unroll
        for (int j = 0; j < 4; j++) o[j] = f2bf(v[j]);
        *(uint2*)&((u16*)out)[i0] = *(uint2*)o;
    }
}

// ---------------- GEMM 256x256 / 8 waves of 128x64, K-region pipeline -------
// FFN1 kernel (r18). K-MAJOR regions As/Bs[buf][kh][256*32] (16KB). Calendar
// at 4 loads/stage: prologue vmcnt(8); ph0-end vmcnt(8) [tail 0]; ph1-end
// vmcnt(8) [tail 4]. Both-sides involution ((row&15)>>1)&3 (rule #21).
template <int TAG>
__global__ __launch_bounds__(512, 2) void gemm256w_kernel(const u16* __restrict__ A,
                                                          const u16* __restrict__ Bt,
                                                          const float* __restrict__ bias,
                                                          void* __restrict__ out,
                                                          int N, int K, int relu) {
    __shared__ __align__(16) u16 As[2][2][256 * 32];   // [buf][kh] 16KB regions
    __shared__ __align__(16) u16 Bs[2][2][256 * 32];
    const int tid = threadIdx.x;
    const int wave = tid >> 6, lane = tid & 63;
    const int l15 = lane & 15, quad = lane >> 4;
    const int wr = wave >> 2, wc = wave & 3;           // 2x4 wave grid: 128x64 per wave
    const int m0 = blockIdx.y * 256, n0 = blockIdx.x * 256;
    const int nt = K >> 6;

    const int rsub = lane >> 2;                        // 0..15
    const int logc = (lane & 3) ^ ((rsub >> 1) & 3);   // involution, +16-row invariant

    auto stage_pair = [&](int t, int kh) {
        const int buf = t & 1;
        const int kk = (t << 6) + (kh << 5) + logc * 8;
        const int r0 = wave * 32 + rsub;
        u16* da = &As[buf][kh][wave * 1024 + lane * 8];
        u16* db = &Bs[buf][kh][wave * 1024 + lane * 8];
        gl_lds16(A + (size_t)(m0 + r0) * K + kk, da);
        gl_lds16(A + (size_t)(m0 + r0 + 16) * K + kk, da + 512);
        gl_lds16(Bt + (size_t)(n0 + r0) * K + kk, db);
        gl_lds16(Bt + (size_t)(n0 + r0 + 16) * K + kk, db + 512);
    };

    f32x4 acc[8][4];
#pragma unroll
    for (int i = 0; i < 8; i++)
#pragma unroll
        for (int j = 0; j < 4; j++) acc[i][j] = (f32x4){0.f, 0.f, 0.f, 0.f};

    stage_pair(0, 0);
    stage_pair(0, 1);
    stage_pair(1, 0);
    asm volatile("s_waitcnt vmcnt(8)" ::: "memory");
    __builtin_amdgcn_s_barrier();

    const int rx = (l15 >> 1) & 3;                     // read-side involution
    for (int t = 0; t < nt; t++) {
        const int b = t & 1;
#pragma unroll
        for (int ph = 0; ph < 2; ph++) {
            const int kh = ph;
            short8 af[8], bfr[4];
#pragma unroll
            for (int i = 0; i < 8; i++)
                af[i] = *(const short8*)&As[b][kh][(wr * 128 + i * 16 + l15) * 32 +
                                                   ((quad ^ rx) << 3)];
#pragma unroll
            for (int j = 0; j < 4; j++)
                bfr[j] = *(const short8*)&Bs[b][kh][(wc * 64 + j * 16 + l15) * 32 +
                                                    ((quad ^ rx) << 3)];
            if (ph == 0) { if (t + 1 < nt) stage_pair(t + 1, 1); }
            else         { if (t + 2 < nt) stage_pair(t + 2, 0); }
            __builtin_amdgcn_s_setprio(1);
#pragma unroll
            for (int i = 0; i < 8; i++)
#pragma unroll
                for (int j = 0; j < 4; j++)
                    acc[i][j] = __builtin_amdgcn_mfma_f32_16x16x32_bf16(
                        af[i], bfr[j], acc[i][j], 0, 0, 0);
            __builtin_amdgcn_s_setprio(0);
            if (ph == 0) {
                if (t + 1 < nt) { asm volatile("s_waitcnt vmcnt(8)" ::: "memory"); }
                else            { asm volatile("s_waitcnt vmcnt(0)" ::: "memory"); }
            } else {
                if (t + 2 < nt)      { asm volatile("s_waitcnt vmcnt(8)" ::: "memory"); }
                else if (t + 1 < nt) { asm volatile("s_waitcnt vmcnt(4)" ::: "memory"); }
            }
            __builtin_amdgcn_s_barrier();
        }
    }

    // epilogue: bias [+relu] -> bf16 (m89-verified C/D layout)
#pragma unroll
    for (int j = 0; j < 4; j++) {
        const int col = n0 + wc * 64 + j * 16 + l15;
        const float bv = bias ? bias[col] : 0.f;
#pragma unroll
        for (int i = 0; i < 8; i++) {
            const int row0 = m0 + wr * 128 + i * 16 + quad * 4;
#pragma unroll
            for (int r = 0; r < 4; r++) {
                float v = acc[i][j][r] + bv;
                if (relu) v = fmaxf(v, 0.f);
                ((u16*)out)[(size_t)(row0 + r) * N + col] = f2bf(v);
            }
        }
    }
}

// ---------------- GEMM 128x128 DEEP: BK=128, for 1-block/CU grids -----------
// For grid-256 shapes (Wo; FFN2 fallback). Calendar at 4 loads/stage:
// prologue vmcnt(8); ph0-end vmcnt(8) [tail 0]; ph1-end vmcnt(8) [tail 4].
template <int TAG>
__global__ __launch_bounds__(512, 2) void gemm128d_kernel(const u16* __restrict__ A,
                                                          const u16* __restrict__ Bt,
                                                          const float* __restrict__ bias,
                                                          const u16* __restrict__ res1,
                                                          void* __restrict__ out,
                                                          int N, int K, int relu, int swz) {
    __shared__ __align__(16) u16 As[2][2][128 * 64];   // [buf][kh] 16KB regions
    __shared__ __align__(16) u16 Bs[2][2][128 * 64];
    const int tid = threadIdx.x;
    const int wave = tid >> 6, lane = tid & 63;
    const int l15 = lane & 15, quad = lane >> 4;
    const int wr = wave & 3, wc = wave >> 2;           // 4x2 wave grid: 32x64 per wave
    int bx = blockIdx.x, by = blockIdx.y;
    if (swz) {
        const int gx = gridDim.x;
        const int nwg = gx * gridDim.y;
        const int bid = by * gx + bx;
        const int sbid = (bid & 7) * (nwg >> 3) + (bid >> 3);  // XCD-chunked, bijective
        bx = sbid % gx;
        by = sbid / gx;
    }
    const int m0 = by * 128, n0 = bx * 128;
    const int nt = K >> 7;                             // BK=128 tiles

    const int srow = lane >> 3;                        // 0..7
    const int logc = (lane & 7) ^ ((lane >> 4) & 3);   // involution, +8-row invariant

    auto stage_pair = [&](int t, int kh) {
        const int buf = t & 1;
        const int kk = (t << 7) + (kh << 6) + logc * 8;
        const int r0 = wave * 16 + srow;
        u16* da = &As[buf][kh][wave * 1024 + lane * 8];
        u16* db = &Bs[buf][kh][wave * 1024 + lane * 8];
        gl_lds16(A + (size_t)(m0 + r0) * K + kk, da);
        gl_lds16(A + (size_t)(m0 + r0 + 8) * K + kk, da + 512);
        gl_lds16(Bt + (size_t)(n0 + r0) * K + kk, db);
        gl_lds16(Bt + (size_t)(n0 + r0 + 8) * K + kk, db + 512);
    };

    f32x4 acc[2][4];
#pragma unroll
    for (int i = 0; i < 2; i++)
#pragma unroll
        for (int j = 0; j < 4; j++) acc[i][j] = (f32x4){0.f, 0.f, 0.f, 0.f};

    stage_pair(0, 0);
    stage_pair(0, 1);
    stage_pair(1, 0);
    asm volatile("s_waitcnt vmcnt(8)" ::: "memory");
    __builtin_amdgcn_s_barrier();

    const int rx = (l15 >> 1) & 3;                     // read-side involution
    for (int t = 0; t < nt; t++) {
        const int b = t & 1;
#pragma unroll
        for (int ph = 0; ph < 2; ph++) {
            const int kh = ph;
            short8 af[2][2], bfr[4][2];
#pragma unroll
            for (int ks = 0; ks < 2; ks++) {
                const int ck = ((ks << 2) | (quad ^ rx)) << 3;
#pragma unroll
                for (int i = 0; i < 2; i++)
                    af[i][ks] = *(const short8*)&As[b][kh][(wr * 32 + i * 16 + l15) * 64 + ck];
#pragma unroll
                for (int j = 0; j < 4; j++)
                    bfr[j][ks] = *(const short8*)&Bs[b][kh][(wc * 64 + j * 16 + l15) * 64 + ck];
            }
            if (ph == 0) { if (t + 1 < nt) stage_pair(t + 1, 1); }
            else         { if (t + 2 < nt) stage_pair(t + 2, 0); }
            __builtin_amdgcn_s_setprio(1);
#pragma unroll
            for (int ks = 0; ks < 2; ks++)
#pragma unroll
                for (int i = 0; i < 2; i++)
#pragma unroll
                    for (int j = 0; j < 4; j++)
                        acc[i][j] = __builtin_amdgcn_mfma_f32_16x16x32_bf16(
                            af[i][ks], bfr[j][ks], acc[i][j], 0, 0, 0);
            __builtin_amdgcn_s_setprio(0);
            if (ph == 0) {
                if (t + 1 < nt) { asm volatile("s_waitcnt vmcnt(8)" ::: "memory"); }
                else            { asm volatile("s_waitcnt vmcnt(0)" ::: "memory"); }
            } else {
                if (t + 2 < nt)      { asm volatile("s_waitcnt vmcnt(8)" ::: "memory"); }
                else if (t + 1 < nt) { asm volatile("s_waitcnt vmcnt(4)" ::: "memory"); }
            }
            __builtin_amdgcn_s_barrier();
        }
    }

    // epilogue: bias [+relu] [+res1] -> bf16 (m89-verified C/D layout)
#pragma unroll
    for (int j = 0; j < 4; j++) {
        const int col = n0 + wc * 64 + j * 16 + l15;
        const float bv = bias ? bias[col] : 0.f;
#pragma unroll
        for (int i = 0; i < 2; i++) {
            const int row0 = m0 + wr * 32 + i * 16 + quad * 4;
#pragma unroll
            for (int r = 0; r < 4; r++) {
                float v = acc[i][j][r] + bv;
                if (relu) v = fmaxf(v, 0.f);
                const size_t idx = (size_t)(row0 + r) * N + col;
                if (res1) v += bf2f(res1[idx]);
                ((u16*)out)[idx] = f2bf(v);
            }
        }
    }
}

// ---------------- fused adapter: out = x1 + hh + relu(hh@Wd+bd)@Wu + bu -----
__global__ __launch_bounds__(512) void adapter_kernel(const u16* __restrict__ hh,
                                                      const u16* __restrict__ x1,
                                                      const u16* __restrict__ WdT,
                                                      const u16* __restrict__ WuT,
                                                      const float* __restrict__ bd,
                                                      const float* __restrict__ bu,
                                                      void* __restrict__ out,
                                                      const int* __restrict__ flag) {
    const int tid = threadIdx.x;
    const int wave = tid >> 6, lane = tid & 63;
    const int l15 = lane & 15, quad = lane >> 4;
    const int r0 = blockIdx.x * 16;

    __shared__ float part[8][16 * 64];
    __shared__ __align__(16) u16 bot_s[16 * 72];       // 72-pad: conflict-free A-frag reads

    // phase 1: down-GEMM partial over this wave's K-slice
    f32x4 dacc[4];
#pragma unroll
    for (int j = 0; j < 4; j++) dacc[j] = (f32x4){0.f, 0.f, 0.f, 0.f};
    const int kw = wave * 128;
#pragma unroll
    for (int ks = 0; ks < 4; ks++) {
        const int k0 = kw + ks * 32 + quad * 8;
        short8 af = *(const short8*)&hh[(size_t)(r0 + l15) * 1024 + k0];
#pragma unroll
        for (int j = 0; j < 4; j++) {
            short8 bf = *(const short8*)&WdT[(size_t)(j * 16 + l15) * 1024 + k0];
            dacc[j] = __builtin_amdgcn_mfma_f32_16x16x32_bf16(af, bf, dacc[j], 0, 0, 0);
        }
    }
#pragma unroll
    for (int j = 0; j < 4; j++)
#pragma unroll
        for (int r = 0; r < 4; r++)
            part[wave][(quad * 4 + r) * 64 + j * 16 + l15] = dacc[j][r];
    __syncthreads();

    // reduce 8 partials, +bd, relu, bf16
    for (int e = tid; e < 1024; e += 512) {
        float s = part[0][e];
#pragma unroll
        for (int w = 1; w < 8; w++) s += part[w][e];
        s += bd[e & 63];
        s = fmaxf(s, 0.f);
        bot_s[(e >> 6) * 72 + (e & 63)] = f2bf(s);
    }
    __syncthreads();

    // phase 2: up-GEMM, wave owns cols [wave*128, +128), K=64
    short8 auf[2];
    auf[0] = *(const short8*)&bot_s[l15 * 72 + quad * 8];
    auf[1] = *(const short8*)&bot_s[l15 * 72 + 32 + quad * 8];
    f32x4 uacc[8];
#pragma unroll
    for (int j = 0; j < 8; j++) uacc[j] = (f32x4){0.f, 0.f, 0.f, 0.f};
#pragma unroll
    for (int j = 0; j < 8; j++) {
        const size_t nb = (size_t)(wave * 128 + j * 16 + l15) * 64;
        short8 b0 = *(const short8*)&WuT[nb + quad * 8];
        short8 b1 = *(const short8*)&WuT[nb + 32 + quad * 8];
        uacc[j] = __builtin_amdgcn_mfma_f32_16x16x32_bf16(auf[0], b0, uacc[j], 0, 0, 0);
        uacc[j] = __builtin_amdgcn_mfma_f32_16x16x32_bf16(auf[1], b1, uacc[j], 0, 0, 0);
    }
    const int f32out = (*flag == 0);
#pragma unroll
    for (int j = 0; j < 8; j++) {
        const int col = wave * 128 + j * 16 + l15;
        const float bv = bu[col];
#pragma unroll
        for (int r = 0; r < 4; r++) {
            const int row = r0 + quad * 4 + r;
            const size_t idx = (size_t)row * 1024 + col;
            float v = uacc[j][r] + bv;
            v += bf2f(hh[idx]);
            v += bf2f(x1[idx]);
            if (f32out) ((float*)out)[idx] = v;
            else ((u16*)out)[idx] = f2bf(v);
        }
    }
}

// ---------------- flash attention v11: paired q-blocks, shared K/V staging --
// r19 WIN (52 -> off top-5). v8b's exact per-wave math; waves 0-3 own qbA,
// waves 4-7 own qbB, shared K/V tile feeds 128 q-rows; zero per-wave VGPR
// change -> VGPR-capped 24 waves/CU (vs LDS-capped 20).
__global__ __launch_bounds__(512) void flash_pair_kernel(const u16* __restrict__ Q,
                                                         const u16* __restrict__ Kg,
                                                         const u16* __restrict__ VtG,
                                                         u16* __restrict__ O,
                                                         u16* __restrict__ pO,
                                                         float* __restrict__ pL) {
    const int tid = threadIdx.x;
    const int wave = tid >> 6, lane = tid & 63;
    const int half = wave >> 2, w4 = wave & 3;
    int i = blockIdx.x, c, p;
    if (i < 16)      { c = 0; p = i; }
    else if (i < 28) { c = 1; p = i - 16; }
    else if (i < 36) { c = 2; p = i - 28; }
    else             { c = 3; p = i - 36; }
    const int qb = 31 - 2 * p - half;          // A: 31-2p (waves 0-3), B: 30-2p
    const int bh = blockIdx.y;
    const int t0 = qb * 64;
    const int steps = qb + 1;
    const int ktbeg = c * 8;
    int ktend = ktbeg + 8; if (steps < ktend) ktend = steps;        // this half
    const int qbA = 31 - 2 * p;
    int ktend_blk = ktbeg + 8; if (qbA + 1 < ktend_blk) ktend_blk = qbA + 1;
    const size_t base = ((size_t)(bh >> 4) * 2048) * 1024 + (size_t)(bh & 15) * 64;
    const size_t basev = (size_t)bh * 64 * 2048;

    __shared__ __align__(16) u16 Ks[2][64 * 64];
    __shared__ __align__(16) u16 Vt[2][64 * 64];
#if !__has_builtin(__builtin_amdgcn_mfma_f32_16x16x16bf16_1k)
    __shared__ __align__(16) u16 Ps[8][16 * 72];
#endif

    const int l15 = lane & 15, quad = lane >> 4;
    const int rmin = t0 + w4 * 16;             // this wave's 16 q-rows

    // Q fragments (B-operand): lane holds Q[qrow=l15][d = st*32 + quad*8 ..+7]
    short8 qf[2];
    {
        const u16* qp = Q + base + (size_t)(rmin + l15) * 1024 + quad * 8;
        qf[0] = *(const short8*)qp;
        qf[1] = *(const short8*)(qp + 32);
    }

    const int slr = lane >> 3;                 // 0..7
    const int sc8 = (lane & 7) ^ slr;          // swizzled source col-chunk
    const int rb = wave * 8;                   // 8 waves x 8 rows = 64-row tile

    auto stage = [&](int kt, int bufi) {
        gl_lds16(Kg + base + (size_t)(kt * 64 + rb + slr) * 1024 + sc8 * 8,
                 &Ks[bufi][rb * 64 + lane * 8]);
        gl_lds16(VtG + basev + (size_t)(rb + slr) * 2048 + kt * 64 + sc8 * 8,
                 &Vt[bufi][rb * 64 + lane * 8]);
    };

    float l_part = 0.f;
    f32x4 oacc[4];
#pragma unroll
    for (int jt = 0; jt < 4; jt++) oacc[jt] = (f32x4){0.f, 0.f, 0.f, 0.f};

    const float Cs = 0.125f * 1.44269504f;     // scale * log2(e)

    stage(ktbeg, 0);
    __syncthreads();

    for (int kt = ktbeg; kt < ktend_blk; kt++) {
        const int cur = kt & 1;
        if (kt + 1 < ktend_blk) stage(kt + 1, cur ^ 1);   // prefetch overlaps compute

        if (kt < ktend) {
            // K fragments (A-operand): lane holds K[key=j*16+l15][d chunk st*4+quad]
            short8 kf[2][4];
#pragma unroll
            for (int st = 0; st < 2; st++)
#pragma unroll
                for (int j = 0; j < 4; j++)
                    kf[st][j] = *(const short8*)&Ks[cur][(j * 16 + l15) * 64 +
                                                         (((st * 4 + quad) ^ (l15 & 7)) * 8)];
#if __has_builtin(__builtin_amdgcn_mfma_f32_16x16x16bf16_1k)
            // V b64 fragments for 16x16x16 PV
            short4v vf[4][4];
#pragma unroll
            for (int j = 0; j < 4; j++) {
                int k8 = j * 2 + (quad >> 1);      // data key-chunk
#pragma unroll
                for (int jt = 0; jt < 4; jt++) {
                    int d = jt * 16 + l15;
                    vf[j][jt] = *(const short4v*)&Vt[cur][d * 64 + ((k8 ^ (d & 7)) * 8) +
                                                          (quad & 1) * 4];
                }
            }
#else
            short8 vf[2][4];
#pragma unroll
            for (int st = 0; st < 2; st++)
#pragma unroll
                for (int jt = 0; jt < 4; jt++) {
                    int d = jt * 16 + l15;
                    vf[st][jt] = *(const short8*)&Vt[cur][d * 64 + (((st * 4 + quad) ^ (d & 7)) * 8)];
                }
#endif

            // S^T = K Q^T : lane gets qrow=l15, keys j*16+quad*4+r
            f32x4 s[4];
#pragma unroll
            for (int j = 0; j < 4; j++) s[j] = (f32x4){0.f, 0.f, 0.f, 0.f};
#pragma unroll
            for (int st = 0; st < 2; st++)
#pragma unroll
                for (int j = 0; j < 4; j++)
                    s[j] = __builtin_amdgcn_mfma_f32_16x16x32_bf16(kf[st][j], qf[st], s[j], 0, 0, 0);

            // softmax: mask fires only on this half's diagonal step (kt==qb)
            float lpv[4] = {0.f, 0.f, 0.f, 0.f};
            short4v pj[4];
            if (kt != qb) {
#pragma unroll
                for (int j = 0; j < 4; j++) {
                    union { short4v v; u16 u[4]; } pk;
#pragma unroll
                    for (int r = 0; r < 4; r++) {
                        float pv = __builtin_amdgcn_exp2f(s[j][r] * Cs);
                        lpv[r] += pv;
                        pk.u[r] = f2bf_fast(pv);
                    }
                    pj[j] = pk.v;
                }
            } else {
                const int qrow = rmin + l15;
#pragma unroll
                for (int j = 0; j < 4; j++) {
                    union { short4v v; u16 u[4]; } pk;
#pragma unroll
                    for (int r = 0; r < 4; r++) {
                        float pv = __builtin_amdgcn_exp2f(s[j][r] * Cs);
                        int key = kt * 64 + j * 16 + quad * 4 + r;
                        if (key > qrow) pv = 0.f;
                        lpv[r] += pv;
                        pk.u[r] = f2bf_fast(pv);
                    }
                    pj[j] = pk.v;
                }
            }
            l_part += (lpv[0] + lpv[1]) + (lpv[2] + lpv[3]);

#if __has_builtin(__builtin_amdgcn_mfma_f32_16x16x16bf16_1k)
            // O += P V, P straight from registers (A-frag match)
#pragma unroll
            for (int jt = 0; jt < 4; jt++)
#pragma unroll
                for (int j = 0; j < 4; j++)
                    oacc[jt] = __builtin_amdgcn_mfma_f32_16x16x16bf16_1k(pj[j], vf[j][jt],
                                                                         oacc[jt], 0, 0, 0);
#else
            u16* Pw = Ps[wave];
#pragma unroll
            for (int j = 0; j < 4; j++)
                *(short4v*)&Pw[l15 * 72 + j * 16 + quad * 4] = pj[j];
#pragma unroll
            for (int st = 0; st < 2; st++) {
                short8 pf2 = *(const short8*)&Pw[l15 * 72 + st * 32 + quad * 8];
#pragma unroll
                for (int jt = 0; jt < 4; jt++)
                    oacc[jt] = __builtin_amdgcn_mfma_f32_16x16x32_bf16(pf2, vf[st][jt],
                                                                      oacc[jt], 0, 0, 0);
            }
#endif
        }
        __syncthreads();
    }

    // l reduction: l lives per qrow=l15; reduce across quads
    float lf = l_part;
    lf += __shfl_xor(lf, 16, 64);
    lf += __shfl_xor(lf, 32, 64);

    if (steps > 8) {
        // multi-chunk q-block: write un-normalized bf16 partials (v8b layout)
        const size_t ib = ((size_t)bh * 24 + (qb - 8)) * 4 + c;
        u16* po = pO + ib * 4096;
#pragma unroll
        for (int jt = 0; jt < 4; jt++)
#pragma unroll
            for (int r = 0; r < 4; r++)
                po[(w4 * 16 + quad * 4 + r) * 64 + jt * 16 + l15] = f2bf(oacc[jt][r]);
        if (quad == 0) pL[ib * 64 + w4 * 16 + l15] = lf;
        return;
    }

    // single-chunk (qb<=7, c==0): normalize and store bf16
    {
        float inv[4];
#pragma unroll
        for (int r = 0; r < 4; r++) inv[r] = 1.f / __shfl(lf, quad * 4 + r, 64);
#pragma unroll
        for (int jt = 0; jt < 4; jt++) {
            int d = jt * 16 + l15;
#pragma unroll
            for (int r = 0; r < 4; r++) {
                int t = rmin + quad * 4 + r;
                O[base + (size_t)t * 1024 + d] = f2bf(oacc[jt][r] * inv[r]);
            }
        }
    }
}

// ---------------- flash attention v8b (non-split fallback, 256 threads) -----
__global__ __launch_bounds__(256) void flash_kernel(const u16* __restrict__ Q,
                                                    const u16* __restrict__ Kg,
                                                    const u16* __restrict__ VtG,
                                                    u16* __restrict__ O) {
    const int tid = threadIdx.x;
    const int wave = tid >> 6, lane = tid & 63;
    const int qb = 31 - blockIdx.x;
    const int bh = blockIdx.y;
    const int t0 = qb * 64;
    const int steps = qb + 1;
    const size_t base = ((size_t)(bh >> 4) * 2048) * 1024 + (size_t)(bh & 15) * 64;
    const size_t basev = (size_t)bh * 64 * 2048;

    __shared__ __align__(16) u16 Ks[2][64 * 64];
    __shared__ __align__(16) u16 Vt[2][64 * 64];
#if !__has_builtin(__builtin_amdgcn_mfma_f32_16x16x16bf16_1k)
    __shared__ __align__(16) u16 Ps[4][16 * 72];
#endif

    const int l15 = lane & 15, quad = lane >> 4;
    const int rmin = t0 + wave * 16;

    short8 qf[2];
    {
        const u16* qp = Q + base + (size_t)(rmin + l15) * 1024 + quad * 8;
        qf[0] = *(const short8*)qp;
        qf[1] = *(const short8*)(qp + 32);
    }

    const int slr = lane >> 3;
    const int sc8 = (lane & 7) ^ slr;
    const int rb = wave * 16;

    auto stage = [&](int kt, int bufi) {
        gl_lds16(Kg + base + (size_t)(kt * 64 + rb + slr) * 1024 + sc8 * 8,
                 &Ks[bufi][rb * 64 + lane * 8]);
        gl_lds16(Kg + base + (size_t)(kt * 64 + rb + 8 + slr) * 1024 + sc8 * 8,
                 &Ks[bufi][(rb + 8) * 64 + lane * 8]);
        gl_lds16(VtG + basev + (size_t)(rb + slr) * 2048 + kt * 64 + sc8 * 8,
                 &Vt[bufi][rb * 64 + lane * 8]);
        gl_lds16(VtG + basev + (size_t)(rb + 8 + slr) * 2048 + kt * 64 + sc8 * 8,
                 &Vt[bufi][(rb + 8) * 64 + lane * 8]);
    };

    float l_part = 0.f;
    f32x4 oacc[4];
#pragma unroll
    for (int jt = 0; jt < 4; jt++) oacc[jt] = (f32x4){0.f, 0.f, 0.f, 0.f};

    const float Cs = 0.125f * 1.44269504f;

    stage(0, 0);
    __syncthreads();

    for (int kt = 0; kt < steps; kt++) {
        const int cur = kt & 1;
        if (kt + 1 < steps) stage(kt + 1, cur ^ 1);

        short8 kf[2][4];
#pragma unroll
        for (int st = 0; st < 2; st++)
#pragma unroll
            for (int j = 0; j < 4; j++)
                kf[st][j] = *(const short8*)&Ks[cur][(j * 16 + l15) * 64 +
                                                     (((st * 4 + quad) ^ (l15 & 7)) * 8)];
#if __has_builtin(__builtin_amdgcn_mfma_f32_16x16x16bf16_1k)
        short4v vf[4][4];
#pragma unroll
        for (int j = 0; j < 4; j++) {
            int k8 = j * 2 + (quad >> 1);
#pragma unroll
            for (int jt = 0; jt < 4; jt++) {
                int d = jt * 16 + l15;
                vf[j][jt] = *(const short4v*)&Vt[cur][d * 64 + ((k8 ^ (d & 7)) * 8) +
                                                      (quad & 1) * 4];
            }
        }
#else
        short8 vf[2][4];
#pragma unroll
        for (int st = 0; st < 2; st++)
#pragma unroll
            for (int jt = 0; jt < 4; jt++) {
                int d = jt * 16 + l15;
                vf[st][jt] = *(const short8*)&Vt[cur][d * 64 + (((st * 4 + quad) ^ (d & 7)) * 8)];
            }
#endif

        f32x4 s[4];
#pragma unroll
        for (int j = 0; j < 4; j++) s[j] = (f32x4){0.f, 0.f, 0.f, 0.f};
#pragma unroll
        for (int st = 0; st < 2; st++)
#pragma unroll
            for (int j = 0; j < 4; j++)
                s[j] = __builtin_amdgcn_mfma_f32_16x16x32_bf16(kf[st][j], qf[st], s[j], 0, 0, 0);

        float lpv[4] = {0.f, 0.f, 0.f, 0.f};
        short4v pj[4];
        if (kt != qb) {
#pragma unroll
            for (int j = 0; j < 4; j++) {
                union { short4v v; u16 u[4]; } pk;
#pragma unroll
                for (int r = 0; r < 4; r++) {
                    float pv = __builtin_amdgcn_exp2f(s[j][r] * Cs);
                    lpv[r] += pv;
                    pk.u[r] = f2bf_fast(pv);
                }
                pj[j] = pk.v;
            }
        } else {
            const int qrow = rmin + l15;
#pragma unroll
            for (int j = 0; j < 4; j++) {
                union { short4v v; u16 u[4]; } pk;
#pragma unroll
                for (int r = 0; r < 4; r++) {
                    float pv = __builtin_amdgcn_exp2f(s[j][r] * Cs);
                    int key = kt * 64 + j * 16 + quad * 4 + r;
                    if (key > qrow) pv = 0.f;
                    lpv[r] += pv;
                    pk.u[r] = f2bf_fast(pv);
                }
                pj[j] = pk.v;
            }
        }
        l_part += (lpv[0] + lpv[1]) + (lpv[2] + lpv[3]);

#if __has_builtin(__builtin_amdgcn_mfma_f32_16x16x16bf16_1k)
#pragma unroll
        for (int jt = 0; jt < 4; jt++)
#pragma unroll
            for (int j = 0; j < 4; j++)
                oacc[jt] = __builtin_amdgcn_mfma_f32_16x16x16bf16_1k(pj[j], vf[j][jt],
                                                                     oacc[jt], 0, 0, 0);
#else
        u16* Pw = Ps[wave];
#pragma unroll
        for (int j = 0; j < 4; j++)
            *(short4v*)&Pw[l15 * 72 + j * 16 + quad * 4] = pj[j];
#pragma unroll
        for (int st = 0; st < 2; st++) {
            short8 pf2 = *(const short8*)&Pw[l15 * 72 + st * 32 + quad * 8];
#pragma unroll
            for (int jt = 0; jt < 4; jt++)
                oacc[jt] = __builtin_amdgcn_mfma_f32_16x16x32_bf16(pf2, vf[st][jt],
                                                                  oacc[jt], 0, 0, 0);
        }
#endif
        __syncthreads();
    }

    float lf = l_part;
    lf += __shfl_xor(lf, 16, 64);
    lf += __shfl_xor(lf, 32, 64);
    float inv[4];
#pragma unroll
    for (int r = 0; r < 4; r++) inv[r] = 1.f / __shfl(lf, quad * 4 + r, 64);
#pragma unroll
    for (int jt = 0; jt < 4; jt++) {
        int d = jt * 16 + l15;
#pragma unroll
        for (int r = 0; r < 4; r++) {
            int t = rmin + quad * 4 + r;
            O[base + (size_t)t * 1024 + d] = f2bf(oacc[jt][r] * inv[r]);
        }
    }
}

// ---------------- flash combine: O = (sum_c O_c) / (sum_c l_c) --------------
__global__ __launch_bounds__(256) void flash_combine_kernel(const u16* __restrict__ pO,
                                                            const float* __restrict__ pL,
                                                            u16* __restrict__ O) {
    const int qj = blockIdx.x;                 // 0..23 -> qb = qj + 8
    const int bh = blockIdx.y;
    const int qb = qj + 8;
    const int nch = (qb >> 3) + 1;             // 2, 3 or 4 chunks
    const int tid = threadIdx.x;
    const int row = tid >> 2;                  // 0..63
    const int d0 = (tid & 3) * 16;
    const size_t ib = ((size_t)bh * 24 + qj) * 4;

    float acc[16];
#pragma unroll
    for (int k = 0; k < 16; k++) acc[k] = 0.f;
    float lsum = 0.f;
    for (int c = 0; c < nch; c++) {
        const u16* po = pO + (ib + c) * 4096 + row * 64 + d0;
        u16 pb[16];
        *(uint4*)pb = *(const uint4*)po;
        *(uint4*)(pb + 8) = *(const uint4*)(po + 8);
#pragma unroll
        for (int k = 0; k < 16; k++) acc[k] += bf2f(pb[k]);
        lsum += pL[(ib + c) * 64 + row];
    }
    const float inv = 1.f / lsum;
    u16 o[16];
#pragma unroll
    for (int k = 0; k < 16; k++) o[k] = f2bf(acc[k] * inv);
    const size_t base = ((size_t)(bh >> 4) * 2048) * 1024 + (size_t)(bh & 15) * 64;
    const int t = qb * 64 + row;
    u16* op = &O[base + (size_t)t * 1024 + d0];
    *(uint4*)op = ((uint4*)o)[0];
    *(uint4*)(op + 8) = ((uint4*)o)[1];
}

extern "C" void kernel_launch(void* const* d_in, const int* in_sizes, int n_in,
                              void* d_out, int out_size, void* d_ws, size_t ws_size,
                              hipStream_t stream) {
    (void)in_sizes; (void)n_in; (void)out_size;
    const void* x   = d_in[0];
    // d_in[1] = attn_mask (int32, pure causal) -- implemented directly
    const void* Wq  = d_in[2];  const void* bq  = d_in[3];
    const void* Wk  = d_in[4];  const void* bk  = d_in[5];
    const void* Wv  = d_in[6];  const void* bv  = d_in[7];
    const void* Wo  = d_in[8];  const void* bo  = d_in[9];
    const void* g1  = d_in[10]; const void* be1 = d_in[11];
    const void* g2  = d_in[12]; const void* be2 = d_in[13];
    const void* W1  = d_in[14]; const void* bf1 = d_in[15];
    const void* W2  = d_in[16]; const void* bf2 = d_in[17];
    const void* Wd  = d_in[18]; const void* bd  = d_in[19];
    const void* Wu  = d_in[20]; const void* bu  = d_in[21];

    uint8_t* w8 = (uint8_t*)d_ws;
    int* flag = (int*)w8;                    // 64 B header
    float* pf = (float*)(w8 + 64);           // f32 param pool
    u16* wsb = (u16*)(w8 + 64 + 65536);      // bf16 arena

    const size_t M1 = 1024ull * 1024ull;
    u16* WqT = wsb;                          // Wq/Wk/Wv transposed, contiguous 3072xK
    u16* WkT = wsb + 1 * M1;
    u16* WvT = wsb + 2 * M1;
    u16* WoT = wsb + 3 * M1;
    u16* W1T = wsb + 4 * M1;                 // 4M
    u16* W2T = wsb + 8 * M1;                 // 4M
    u16* WdT = wsb + 12 * M1;                // 64K
    u16* WuT = wsb + 12 * M1 + 65536;        // 64K
    u16* S0  = wsb + 12 * M1 + 131072;
    u16* Areg = S0;                          // xb
    u16* Breg = S0 + 4 * M1;                 // xn -> attn
    u16* ff1  = S0;                          // 16M spans Areg+Breg+8M fresh
    u16* Creg = S0 + 16 * M1;                // q -> xn2
    u16* Dreg = S0 + 20 * M1;                // k -> x1
    u16* Ereg = S0 + 24 * M1;                // VtG -> hh
    u16* xb = Areg;
    u16* xn = Breg; u16* attn = Breg;
    u16* q = Creg;  u16* xn2 = Creg;
    u16* kk_ = Dreg; u16* x1 = Dreg;
    u16* VtG = Ereg; u16* hh = Ereg;

    // f32 partial buffer after the bf16 arena
    // (time-shared: flash partials [24MB bf16 O + 1MB f32 l] -> FFN2 split-K)
    const size_t arena_bytes = (size_t)(64 + 65536) + (40 * M1 + 131072) * 2;
    float* partf = (float*)(w8 + ((arena_bytes + 255) & ~(size_t)255));
    const size_t need = ((arena_bytes + 255) & ~(size_t)255) + 4ull * 4 * M1 * 4;
    const bool sk = ws_size >= need;
    float* flL = partf + 14 * M1;            // flash l partials at +56MB

    float* bqkv_f = pf + 0;    // bq,bk,bv contiguous (3072)
    float* bo_f  = pf + 3072;
    float* bf1_f = pf + 4096;  float* bf2_f = pf + 8192;
    float* bd_f  = pf + 9216;  float* bu_f  = pf + 9280;
    float* g1_f  = pf + 10304; float* be1_f = pf + 11328;
    float* g2_f  = pf + 12352; float* be2_f = pf + 13376;

    // merged prologue: detect + param convert + weight transpose (1 launch)
    Prologue P;
    const void* tsrc[8] = {Wq, Wk, Wv, Wo, W1, W2, Wd, Wu};
    u16* tdst[8] = {WqT, WkT, WvT, WoT, W1T, W2T, WdT, WuT};
    int tR[8] = {1024, 1024, 1024, 1024, 1024, 4096, 1024, 64};
    int tC[8] = {1024, 1024, 1024, 1024, 4096, 1024, 64, 1024};
    int acc_off = 0;
    for (int i = 0; i < 8; i++) {
        P.tsrc[i] = tsrc[i]; P.tdst[i] = tdst[i];
        P.tR[i] = tR[i]; P.tC[i] = tC[i];
        P.toff[i] = acc_off;
        acc_off += (tR[i] >> 5) * (tC[i] >> 5);
    }
    P.ntrans = acc_off;
    const void* psrc[12] = {bq, bk, bv, bo, bf1, bf2, bd, bu, g1, be1, g2, be2};
    int poff[12] = {0, 1024, 2048, 3072, 4096, 8192, 9216, 9280, 10304, 11328, 12352, 13376};
    int pn[12]   = {1024, 1024, 1024, 1024, 4096, 1024, 64, 1024, 1024, 1024, 1024, 1024};
    for (int i = 0; i < 12; i++) { P.psrc[i] = psrc[i]; P.poff[i] = poff[i]; P.pn[i] = pn[i]; }
    prologue_kernel<<<acc_off + 12, 256, 0, stream>>>(P, (const unsigned*)x, flag, pf);

    // fused x-convert + LN1: writes xb (bf16 x) and xn in one pass
    ln_x_kernel<<<4096, 256, 0, stream>>>(x, g1_f, be1_f, xb, xn, flag);
    // TAG 0: fused QKV (N=3072, V transposed per-head into VtG), 768 blocks
    gemm128_kernel<0><<<dim3(24, 32), 512, 0, stream>>>(xn, WqT, bqkv_f, nullptr, nullptr,
                                                        q, kk_, VtG, 4096, 3072, 1024, 0, 2, 0, flag);
    if (sk) {
        flash_pair_kernel<<<dim3(40, 32), 512, 0, stream>>>(q, kk_, VtG, attn, (u16*)partf, flL);
        flash_combine_kernel<<<dim3(24, 32), 256, 0, stream>>>((const u16*)partf, flL, attn);
    } else {
        flash_kernel<<<dim3(32, 32), 256, 0, stream>>>(q, kk_, VtG, attn);
    }
    // TAG 1: Wo projection + bias + residual, BK=128 deep kernel + XCD swizzle
    gemm128d_kernel<1><<<dim3(8, 32), 512, 0, stream>>>(attn, WoT, bo_f, xb,
                                                        x1, 1024, 1024, 0, 1);
    ln_kernel<<<4096, 256, 0, stream>>>(x1, g2_f, be2_f, xn2);
    // TAG 2: FFN1 (relu), 256x256 tile / 128x64 waves
    gemm256w_kernel<2><<<dim3(16, 16), 512, 0, stream>>>(xn2, W1T, bf1_f,
                                                         ff1, 4096, 1024, 1);
    // TAG 3: FFN2, split-K 2 (2 blk/CU resident) + XCD swizzle (r7 FETCH fix)
    // + r14-verified reduce (+bias). Partials in partf (free after combine).
    if (sk) {
        gemm128s_kernel<3><<<dim3(8, 32, 2), 512, 0, stream>>>(ff1, W2T, partf,
                                                               4096, 1024, 4096, 2048);
        reduce_kernel<3><<<4096, 256, 0, stream>>>(partf, 2, (size_t)4096 * 1024, bf2_f, 1024,
                                                   nullptr, nullptr, hh, 0, 0, flag);
    } else {
        gemm128d_kernel<3><<<dim3(8, 32), 512, 0, stream>>>(ff1, W2T, bf2_f, nullptr,
                                                            hh, 1024, 4096, 0, 1);
    }
    // fused adapter: replaces TAG4 + reduce + TAG5 (3 launches -> 1)
    adapter_kernel<<<256, 512, 0, stream>>>(hh, x1, WdT, WuT, bd_f, bu_f, d_out, flag);
}

// Round 22
// 396.759 us; speedup vs baseline: 1.0385x; 1.0111x over previous
//
#include <hip/hip_runtime.h>
#include <cstdint>
#include <cstddef>

typedef unsigned short u16;
typedef __attribute__((ext_vector_type(4))) short short4v;
typedef __attribute__((ext_vector_type(8))) short short8;
typedef __attribute__((ext_vector_type(4))) float f32x4;

__device__ __forceinline__ float bf2f(u16 h) { return __uint_as_float(((unsigned)h) << 16); }
__device__ __forceinline__ u16 f2bf(float f) {
    unsigned u = __float_as_uint(f);
    unsigned r = (u + 0x7fffu + ((u >> 16) & 1u)) >> 16;
    return (u16)r;
}
// round-half-up: <=0.5 ULP, 2 VALU ops (flash inner loop)
__device__ __forceinline__ u16 f2bf_fast(float f) {
    return (u16)((__float_as_uint(f) + 0x8000u) >> 16);
}

__device__ __forceinline__ void gl_lds16(const void* g, void* l) {
    __builtin_amdgcn_global_load_lds((const __attribute__((address_space(1))) void*)g,
                                     (__attribute__((address_space(3))) void*)l, 16, 0, 0);
}

// ---------------- merged prologue: detect + param-cvt + weight transpose ----
struct Prologue {
    const void* tsrc[8];
    u16* tdst[8];
    int tR[8], tC[8], toff[8];
    const void* psrc[12];
    int poff[12], pn[12];
    int ntrans;
};
__global__ __launch_bounds__(256) void prologue_kernel(Prologue P,
                                                       const unsigned* __restrict__ x,
                                                       int* __restrict__ flag,
                                                       float* __restrict__ pf) {
    // self-detect dtype (1024 samples of x's low u16: bf16 exponent-field test)
    __shared__ int cnt[256];
    int c = 0;
    for (int i = threadIdx.x; i < 1024; i += 256) {
        unsigned lo = x[i] & 0xFFFFu;
        unsigned e = (lo >> 7) & 0xFFu;
        c += (e >= 100u && e <= 150u) ? 1 : 0;
    }
    cnt[threadIdx.x] = c;
    __syncthreads();
    for (int s = 128; s > 0; s >>= 1) {
        if (threadIdx.x < s) cnt[threadIdx.x] += cnt[threadIdx.x + s];
        __syncthreads();
    }
    const int bf = (cnt[0] > 512) ? 1 : 0;
    if (blockIdx.x == 0 && threadIdx.x == 0) *flag = bf;

    const int bid = blockIdx.x;
    if (bid >= P.ntrans) {
        const int s = bid - P.ntrans;
        const void* sp = P.psrc[s];
        float* dp = pf + P.poff[s];
        const int n = P.pn[s];
        for (int i = threadIdx.x; i < n; i += 256)
            dp[i] = bf ? bf2f(((const u16*)sp)[i]) : ((const float*)sp)[i];
        return;
    }
    __shared__ u16 tile[32][33];
    int m = 0;
#pragma unroll
    for (int i = 1; i < 8; i++) m = (bid >= P.toff[i]) ? i : m;
    const int local = bid - P.toff[m];
    const int R = P.tR[m], C = P.tC[m];
    const int tilesx = C >> 5;
    const int bx = local % tilesx, by = local / tilesx;
    const void* src = P.tsrc[m];
    u16* dst = P.tdst[m];
    const int tx = threadIdx.x & 31, ty = threadIdx.x >> 5;   // ty 0..7
#pragma unroll
    for (int i = 0; i < 32; i += 8) {
        size_t idx = (size_t)(by * 32 + ty + i) * C + bx * 32 + tx;
        tile[ty + i][tx] = bf ? ((const u16*)src)[idx] : f2bf(((const float*)src)[idx]);
    }
    __syncthreads();
#pragma unroll
    for (int i = 0; i < 32; i += 8)
        dst[(size_t)(bx * 32 + ty + i) * R + by * 32 + tx] = tile[tx][ty + i];
}

// ---------------- fused x-convert + LayerNorm (first LN) --------------------
__global__ __launch_bounds__(256) void ln_x_kernel(const void* __restrict__ X,
                                                   const float* __restrict__ G,
                                                   const float* __restrict__ Be,
                                                   u16* __restrict__ Xb,
                                                   u16* __restrict__ Y,
                                                   const int* __restrict__ flag) {
    const int row = blockIdx.x;
    const int tid = threadIdx.x;
    const int lane = tid & 63, wave = tid >> 6;
    u16 vbuf[4];
    if (*flag) {
        *(uint2*)vbuf = *(const uint2*)((const u16*)X + (size_t)row * 1024 + tid * 4);
    } else {
        float4 v = *(const float4*)((const float*)X + (size_t)row * 1024 + tid * 4);
        vbuf[0] = f2bf(v.x); vbuf[1] = f2bf(v.y); vbuf[2] = f2bf(v.z); vbuf[3] = f2bf(v.w);
    }
    *(uint2*)&Xb[(size_t)row * 1024 + tid * 4] = *(uint2*)vbuf;
    float f[4];
    float s = 0.f, sq = 0.f;
#pragma unroll
    for (int j = 0; j < 4; j++) { f[j] = bf2f(vbuf[j]); s += f[j]; sq += f[j] * f[j]; }
#pragma unroll
    for (int m = 1; m < 64; m <<= 1) { s += __shfl_xor(s, m, 64); sq += __shfl_xor(sq, m, 64); }
    __shared__ float rs_[4], rq_[4];
    if (lane == 0) { rs_[wave] = s; rq_[wave] = sq; }
    __syncthreads();
    float S = rs_[0] + rs_[1] + rs_[2] + rs_[3];
    float Q2 = rq_[0] + rq_[1] + rq_[2] + rq_[3];
    float mean = S * (1.f / 1024.f);
    float var = Q2 * (1.f / 1024.f) - mean * mean;
    float rstd = rsqrtf(var + 1e-5f);
    u16 o[4];
#pragma unroll
    for (int j = 0; j < 4; j++) {
        int c2 = tid * 4 + j;
        float y = (f[j] - mean) * rstd * G[c2] + Be[c2];
        o[j] = f2bf(y);
    }
    *(uint2*)&Y[(size_t)row * 1024 + tid * 4] = *(uint2*)o;
}

// ---------------- LayerNorm over C=1024 (bf16 in, f32 params, bf16 out) -----
__global__ __launch_bounds__(256) void ln_kernel(const u16* __restrict__ X,
                                                 const float* __restrict__ G,
                                                 const float* __restrict__ Be,
                                                 u16* __restrict__ Y) {
    const int row = blockIdx.x;
    const int tid = threadIdx.x;
    const int lane = tid & 63, wave = tid >> 6;
    const u16* xr = X + (size_t)row * 1024;
    u16 vbuf[4];
    *(uint2*)vbuf = *(const uint2*)&xr[tid * 4];
    float f[4];
    float s = 0.f, sq = 0.f;
#pragma unroll
    for (int j = 0; j < 4; j++) { f[j] = bf2f(vbuf[j]); s += f[j]; sq += f[j] * f[j]; }
#pragma unroll
    for (int m = 1; m < 64; m <<= 1) { s += __shfl_xor(s, m, 64); sq += __shfl_xor(sq, m, 64); }
    __shared__ float rs_[4], rq_[4];
    if (lane == 0) { rs_[wave] = s; rq_[wave] = sq; }
    __syncthreads();
    float S = rs_[0] + rs_[1] + rs_[2] + rs_[3];
    float Q2 = rq_[0] + rq_[1] + rq_[2] + rq_[3];
    float mean = S * (1.f / 1024.f);
    float var = Q2 * (1.f / 1024.f) - mean * mean;
    float rstd = rsqrtf(var + 1e-5f);
    u16 o[4];
#pragma unroll
    for (int j = 0; j < 4; j++) {
        int c2 = tid * 4 + j;
        float y = (f[j] - mean) * rstd * G[c2] + Be[c2];
        o[j] = f2bf(y);
    }
    *(uint2*)&Y[(size_t)row * 1024 + tid * 4] = *(uint2*)o;
}

// ---------------- GEMM 128x128 / 8 waves, K-region pipeline, 1 barrier ------
// Round-8 verified kernel. BK=64, 8 waves (32x64/wave), 64KB LDS -> 2 blk/CU
// where the grid supplies them. One barrier per phase. Calendar: t.ph0 stages
// (t+1,k1), waits vmcnt(4) [tail 0]; t.ph1 stages (t+2,k0), waits vmcnt(4)
// [tail 2]. Swizzle involution phys_chunk = logical ^ ((rsub>>1)&3) on BOTH
// global source and ds_read (rule #21).
template <int TAG>
__global__ __launch_bounds__(512, 4) void gemm128_kernel(const u16* __restrict__ A,
                                                         const u16* __restrict__ Bt,
                                                         const float* __restrict__ bias,
                                                         const u16* __restrict__ res1,
                                                         const u16* __restrict__ res2,
                                                         void* __restrict__ out,
                                                         void* __restrict__ out_k,
                                                         void* __restrict__ out_v,
                                                         int M, int N, int K, int relu, int mode,
                                                         int swz,
                                                         const int* __restrict__ flag) {
    (void)flag; (void)M;
    __shared__ __align__(16) u16 As[2][2][128 * 32];   // [buf][kh][row*32+chunk*8] = 8KB each
    __shared__ __align__(16) u16 Bs[2][2][128 * 32];
    const int tid = threadIdx.x;
    const int wave = tid >> 6, lane = tid & 63;
    const int l15 = lane & 15, quad = lane >> 4;
    const int wr = wave & 3, wc = wave >> 2;           // 4x2 wave grid: 32x64 per wave
    int bx = blockIdx.x, by = blockIdx.y;
    if (swz) {
        const int gx = gridDim.x;
        const int nwg = gx * gridDim.y;
        const int bid = by * gx + bx;
        const int sbid = (bid & 7) * (nwg >> 3) + (bid >> 3);  // XCD-chunked, bijective
        bx = sbid % gx;
        by = sbid / gx;
    }
    const int m0 = by * 128, n0 = bx * 128;
    const int nt = K >> 6;

    const int rsub = lane >> 2;                        // 0..15
    const int logc = (lane & 3) ^ ((rsub >> 1) & 3);

    auto stage_pair = [&](int t, int kh) {
        const int buf = t & 1;
        const int kk = (t << 6) + (kh << 5) + logc * 8;
        const int roff = wave * 16 + rsub;
        gl_lds16(A + (size_t)(m0 + roff) * K + kk, &As[buf][kh][wave * 512 + lane * 8]);
        gl_lds16(Bt + (size_t)(n0 + roff) * K + kk, &Bs[buf][kh][wave * 512 + lane * 8]);
    };

    f32x4 acc[2][4];
#pragma unroll
    for (int i = 0; i < 2; i++)
#pragma unroll
        for (int j = 0; j < 4; j++) acc[i][j] = (f32x4){0.f, 0.f, 0.f, 0.f};

    stage_pair(0, 0);
    stage_pair(0, 1);
    stage_pair(1, 0);
    asm volatile("s_waitcnt vmcnt(4)" ::: "memory");
    __builtin_amdgcn_s_barrier();

    const int rx = (l15 >> 1) & 3;                     // read-side involution
    for (int t = 0; t < nt; t++) {
        const int b = t & 1;
#pragma unroll
        for (int ph = 0; ph < 2; ph++) {
            const int kh = ph;
            short8 af[2], bfr[4];
#pragma unroll
            for (int i = 0; i < 2; i++)
                af[i] = *(const short8*)&As[b][kh][(wr * 32 + i * 16 + l15) * 32 +
                                                   ((quad ^ rx) << 3)];
#pragma unroll
            for (int j = 0; j < 4; j++)
                bfr[j] = *(const short8*)&Bs[b][kh][(wc * 64 + j * 16 + l15) * 32 +
                                                    ((quad ^ rx) << 3)];
            if (ph == 0) { if (t + 1 < nt) stage_pair(t + 1, 1); }
            else         { if (t + 2 < nt) stage_pair(t + 2, 0); }
            __builtin_amdgcn_s_setprio(1);
#pragma unroll
            for (int i = 0; i < 2; i++)
#pragma unroll
                for (int j = 0; j < 4; j++)
                    acc[i][j] = __builtin_amdgcn_mfma_f32_16x16x32_bf16(
                        af[i], bfr[j], acc[i][j], 0, 0, 0);
            __builtin_amdgcn_s_setprio(0);
            if (ph == 0) {
                if (t + 1 < nt) { asm volatile("s_waitcnt vmcnt(4)" ::: "memory"); }
                else            { asm volatile("s_waitcnt vmcnt(0)" ::: "memory"); }
            } else {
                if (t + 2 < nt)      { asm volatile("s_waitcnt vmcnt(4)" ::: "memory"); }
                else if (t + 1 < nt) { asm volatile("s_waitcnt vmcnt(2)" ::: "memory"); }
            }
            __builtin_amdgcn_s_barrier();
        }
    }

    // epilogue: C/D layout col=lane&15, row=quad*4+r (m89-verified)
    if (mode == 2) {
        const int region = n0 >> 10;
        if (region < 2) {
            u16* o = (u16*)(region == 0 ? out : out_k);
#pragma unroll
            for (int j = 0; j < 4; j++) {
                const int col = n0 + wc * 64 + j * 16 + l15;
                const float bv = bias[col];
                const int cl = col & 1023;
#pragma unroll
                for (int i = 0; i < 2; i++) {
                    const int row0 = m0 + wr * 32 + i * 16 + quad * 4;
#pragma unroll
                    for (int r = 0; r < 4; r++)
                        o[(size_t)(row0 + r) * 1024 + cl] = f2bf(acc[i][j][r] + bv);
                }
            }
        } else {
            u16* o = (u16*)out_v;
#pragma unroll
            for (int j = 0; j < 4; j++) {
                const int col = n0 + wc * 64 + j * 16 + l15;
                const float bv = bias[col];
                const int cl = col & 1023;
                const int h = cl >> 6, d = cl & 63;
#pragma unroll
                for (int i = 0; i < 2; i++) {
                    const int row_base = m0 + wr * 32 + i * 16 + quad * 4;
                    const int bb = row_base >> 11, tt = row_base & 2047;
                    u16 pk[4];
#pragma unroll
                    for (int r = 0; r < 4; r++) pk[r] = f2bf(acc[i][j][r] + bv);
                    *(uint2*)&o[(((size_t)bb * 16 + h) * 64 + d) * 2048 + tt] = *(uint2*)pk;
                }
            }
        }
        return;
    }
    // mode 0: bias [+relu] [+res] -> bf16
#pragma unroll
    for (int j = 0; j < 4; j++) {
        const int col = n0 + wc * 64 + j * 16 + l15;
        const float bv = bias ? bias[col] : 0.f;
#pragma unroll
        for (int i = 0; i < 2; i++) {
            const int row0 = m0 + wr * 32 + i * 16 + quad * 4;
#pragma unroll
            for (int r = 0; r < 4; r++) {
                float v = acc[i][j][r] + bv;
                if (relu) v = fmaxf(v, 0.f);
                const size_t idx = (size_t)(row0 + r) * N + col;
                if (res1) v += bf2f(res1[idx]);
                if (res2) v += bf2f(res2[idx]);
                ((u16*)out)[idx] = f2bf(v);
            }
        }
    }
}

// ---------------- GEMM 256x256 / 8 waves of 128x64, K-region pipeline -------
// FFN1 kernel (r18). K-MAJOR regions As/Bs[buf][kh][256*32] (16KB). Calendar
// at 4 loads/stage: prologue vmcnt(8); ph0-end vmcnt(8) [tail 0]; ph1-end
// vmcnt(8) [tail 4]. Both-sides involution ((row&15)>>1)&3 (rule #21).
template <int TAG>
__global__ __launch_bounds__(512, 2) void gemm256w_kernel(const u16* __restrict__ A,
                                                          const u16* __restrict__ Bt,
                                                          const float* __restrict__ bias,
                                                          void* __restrict__ out,
                                                          int N, int K, int relu) {
    __shared__ __align__(16) u16 As[2][2][256 * 32];   // [buf][kh] 16KB regions
    __shared__ __align__(16) u16 Bs[2][2][256 * 32];
    const int tid = threadIdx.x;
    const int wave = tid >> 6, lane = tid & 63;
    const int l15 = lane & 15, quad = lane >> 4;
    const int wr = wave >> 2, wc = wave & 3;           // 2x4 wave grid: 128x64 per wave
    const int m0 = blockIdx.y * 256, n0 = blockIdx.x * 256;
    const int nt = K >> 6;

    const int rsub = lane >> 2;                        // 0..15
    const int logc = (lane & 3) ^ ((rsub >> 1) & 3);   // involution, +16-row invariant

    auto stage_pair = [&](int t, int kh) {
        const int buf = t & 1;
        const int kk = (t << 6) + (kh << 5) + logc * 8;
        const int r0 = wave * 32 + rsub;
        u16* da = &As[buf][kh][wave * 1024 + lane * 8];
        u16* db = &Bs[buf][kh][wave * 1024 + lane * 8];
        gl_lds16(A + (size_t)(m0 + r0) * K + kk, da);
        gl_lds16(A + (size_t)(m0 + r0 + 16) * K + kk, da + 512);
        gl_lds16(Bt + (size_t)(n0 + r0) * K + kk, db);
        gl_lds16(Bt + (size_t)(n0 + r0 + 16) * K + kk, db + 512);
    };

    f32x4 acc[8][4];
#pragma unroll
    for (int i = 0; i < 8; i++)
#pragma unroll
        for (int j = 0; j < 4; j++) acc[i][j] = (f32x4){0.f, 0.f, 0.f, 0.f};

    stage_pair(0, 0);
    stage_pair(0, 1);
    stage_pair(1, 0);
    asm volatile("s_waitcnt vmcnt(8)" ::: "memory");
    __builtin_amdgcn_s_barrier();

    const int rx = (l15 >> 1) & 3;                     // read-side involution
    for (int t = 0; t < nt; t++) {
        const int b = t & 1;
#pragma unroll
        for (int ph = 0; ph < 2; ph++) {
            const int kh = ph;
            short8 af[8], bfr[4];
#pragma unroll
            for (int i = 0; i < 8; i++)
                af[i] = *(const short8*)&As[b][kh][(wr * 128 + i * 16 + l15) * 32 +
                                                   ((quad ^ rx) << 3)];
#pragma unroll
            for (int j = 0; j < 4; j++)
                bfr[j] = *(const short8*)&Bs[b][kh][(wc * 64 + j * 16 + l15) * 32 +
                                                    ((quad ^ rx) << 3)];
            if (ph == 0) { if (t + 1 < nt) stage_pair(t + 1, 1); }
            else         { if (t + 2 < nt) stage_pair(t + 2, 0); }
            __builtin_amdgcn_s_setprio(1);
#pragma unroll
            for (int i = 0; i < 8; i++)
#pragma unroll
                for (int j = 0; j < 4; j++)
                    acc[i][j] = __builtin_amdgcn_mfma_f32_16x16x32_bf16(
                        af[i], bfr[j], acc[i][j], 0, 0, 0);
            __builtin_amdgcn_s_setprio(0);
            if (ph == 0) {
                if (t + 1 < nt) { asm volatile("s_waitcnt vmcnt(8)" ::: "memory"); }
                else            { asm volatile("s_waitcnt vmcnt(0)" ::: "memory"); }
            } else {
                if (t + 2 < nt)      { asm volatile("s_waitcnt vmcnt(8)" ::: "memory"); }
                else if (t + 1 < nt) { asm volatile("s_waitcnt vmcnt(4)" ::: "memory"); }
            }
            __builtin_amdgcn_s_barrier();
        }
    }

    // epilogue: bias [+relu] -> bf16 (m89-verified C/D layout)
#pragma unroll
    for (int j = 0; j < 4; j++) {
        const int col = n0 + wc * 64 + j * 16 + l15;
        const float bv = bias ? bias[col] : 0.f;
#pragma unroll
        for (int i = 0; i < 8; i++) {
            const int row0 = m0 + wr * 128 + i * 16 + quad * 4;
#pragma unroll
            for (int r = 0; r < 4; r++) {
                float v = acc[i][j][r] + bv;
                if (relu) v = fmaxf(v, 0.f);
                ((u16*)out)[(size_t)(row0 + r) * N + col] = f2bf(v);
            }
        }
    }
}

// ---------------- GEMM 128x128 DEEP: BK=128, for 1-block/CU grids -----------
// For grid-256 shapes (Wo, FFN2). Calendar at 4 loads/stage: prologue
// vmcnt(8); ph0-end vmcnt(8) [tail 0]; ph1-end vmcnt(8) [tail 4].
// r19-21 lesson: split-K 2 variant trades an extra 64MB HBM round-trip for
// occupancy and nets -6us vs this kernel -- phase latency here is intrinsic.
template <int TAG>
__global__ __launch_bounds__(512, 2) void gemm128d_kernel(const u16* __restrict__ A,
                                                          const u16* __restrict__ Bt,
                                                          const float* __restrict__ bias,
                                                          const u16* __restrict__ res1,
                                                          void* __restrict__ out,
                                                          int N, int K, int relu, int swz) {
    __shared__ __align__(16) u16 As[2][2][128 * 64];   // [buf][kh] 16KB regions
    __shared__ __align__(16) u16 Bs[2][2][128 * 64];
    const int tid = threadIdx.x;
    const int wave = tid >> 6, lane = tid & 63;
    const int l15 = lane & 15, quad = lane >> 4;
    const int wr = wave & 3, wc = wave >> 2;           // 4x2 wave grid: 32x64 per wave
    int bx = blockIdx.x, by = blockIdx.y;
    if (swz) {
        const int gx = gridDim.x;
        const int nwg = gx * gridDim.y;
        const int bid = by * gx + bx;
        const int sbid = (bid & 7) * (nwg >> 3) + (bid >> 3);  // XCD-chunked, bijective
        bx = sbid % gx;
        by = sbid / gx;
    }
    const int m0 = by * 128, n0 = bx * 128;
    const int nt = K >> 7;                             // BK=128 tiles

    const int srow = lane >> 3;                        // 0..7
    const int logc = (lane & 7) ^ ((lane >> 4) & 3);   // involution, +8-row invariant

    auto stage_pair = [&](int t, int kh) {
        const int buf = t & 1;
        const int kk = (t << 7) + (kh << 6) + logc * 8;
        const int r0 = wave * 16 + srow;
        u16* da = &As[buf][kh][wave * 1024 + lane * 8];
        u16* db = &Bs[buf][kh][wave * 1024 + lane * 8];
        gl_lds16(A + (size_t)(m0 + r0) * K + kk, da);
        gl_lds16(A + (size_t)(m0 + r0 + 8) * K + kk, da + 512);
        gl_lds16(Bt + (size_t)(n0 + r0) * K + kk, db);
        gl_lds16(Bt + (size_t)(n0 + r0 + 8) * K + kk, db + 512);
    };

    f32x4 acc[2][4];
#pragma unroll
    for (int i = 0; i < 2; i++)
#pragma unroll
        for (int j = 0; j < 4; j++) acc[i][j] = (f32x4){0.f, 0.f, 0.f, 0.f};

    stage_pair(0, 0);
    stage_pair(0, 1);
    stage_pair(1, 0);
    asm volatile("s_waitcnt vmcnt(8)" ::: "memory");
    __builtin_amdgcn_s_barrier();

    const int rx = (l15 >> 1) & 3;                     // read-side involution
    for (int t = 0; t < nt; t++) {
        const int b = t & 1;
#pragma unroll
        for (int ph = 0; ph < 2; ph++) {
            const int kh = ph;
            short8 af[2][2], bfr[4][2];
#pragma unroll
            for (int ks = 0; ks < 2; ks++) {
                const int ck = ((ks << 2) | (quad ^ rx)) << 3;
#pragma unroll
                for (int i = 0; i < 2; i++)
                    af[i][ks] = *(const short8*)&As[b][kh][(wr * 32 + i * 16 + l15) * 64 + ck];
#pragma unroll
                for (int j = 0; j < 4; j++)
                    bfr[j][ks] = *(const short8*)&Bs[b][kh][(wc * 64 + j * 16 + l15) * 64 + ck];
            }
            if (ph == 0) { if (t + 1 < nt) stage_pair(t + 1, 1); }
            else         { if (t + 2 < nt) stage_pair(t + 2, 0); }
            __builtin_amdgcn_s_setprio(1);
#pragma unroll
            for (int ks = 0; ks < 2; ks++)
#pragma unroll
                for (int i = 0; i < 2; i++)
#pragma unroll
                    for (int j = 0; j < 4; j++)
                        acc[i][j] = __builtin_amdgcn_mfma_f32_16x16x32_bf16(
                            af[i][ks], bfr[j][ks], acc[i][j], 0, 0, 0);
            __builtin_amdgcn_s_setprio(0);
            if (ph == 0) {
                if (t + 1 < nt) { asm volatile("s_waitcnt vmcnt(8)" ::: "memory"); }
                else            { asm volatile("s_waitcnt vmcnt(0)" ::: "memory"); }
            } else {
                if (t + 2 < nt)      { asm volatile("s_waitcnt vmcnt(8)" ::: "memory"); }
                else if (t + 1 < nt) { asm volatile("s_waitcnt vmcnt(4)" ::: "memory"); }
            }
            __builtin_amdgcn_s_barrier();
        }
    }

    // epilogue: bias [+relu] [+res1] -> bf16 (m89-verified C/D layout)
#pragma unroll
    for (int j = 0; j < 4; j++) {
        const int col = n0 + wc * 64 + j * 16 + l15;
        const float bv = bias ? bias[col] : 0.f;
#pragma unroll
        for (int i = 0; i < 2; i++) {
            const int row0 = m0 + wr * 32 + i * 16 + quad * 4;
#pragma unroll
            for (int r = 0; r < 4; r++) {
                float v = acc[i][j][r] + bv;
                if (relu) v = fmaxf(v, 0.f);
                const size_t idx = (size_t)(row0 + r) * N + col;
                if (res1) v += bf2f(res1[idx]);
                ((u16*)out)[idx] = f2bf(v);
            }
        }
    }
}

// ---------------- fused adapter: out = x1 + hh + relu(hh@Wd+bd)@Wu + bu -----
__global__ __launch_bounds__(512) void adapter_kernel(const u16* __restrict__ hh,
                                                      const u16* __restrict__ x1,
                                                      const u16* __restrict__ WdT,
                                                      const u16* __restrict__ WuT,
                                                      const float* __restrict__ bd,
                                                      const float* __restrict__ bu,
                                                      void* __restrict__ out,
                                                      const int* __restrict__ flag) {
    const int tid = threadIdx.x;
    const int wave = tid >> 6, lane = tid & 63;
    const int l15 = lane & 15, quad = lane >> 4;
    const int r0 = blockIdx.x * 16;

    __shared__ float part[8][16 * 64];
    __shared__ __align__(16) u16 bot_s[16 * 72];       // 72-pad: conflict-free A-frag reads

    // phase 1: down-GEMM partial over this wave's K-slice
    f32x4 dacc[4];
#pragma unroll
    for (int j = 0; j < 4; j++) dacc[j] = (f32x4){0.f, 0.f, 0.f, 0.f};
    const int kw = wave * 128;
#pragma unroll
    for (int ks = 0; ks < 4; ks++) {
        const int k0 = kw + ks * 32 + quad * 8;
        short8 af = *(const short8*)&hh[(size_t)(r0 + l15) * 1024 + k0];
#pragma unroll
        for (int j = 0; j < 4; j++) {
            short8 bf = *(const short8*)&WdT[(size_t)(j * 16 + l15) * 1024 + k0];
            dacc[j] = __builtin_amdgcn_mfma_f32_16x16x32_bf16(af, bf, dacc[j], 0, 0, 0);
        }
    }
#pragma unroll
    for (int j = 0; j < 4; j++)
#pragma unroll
        for (int r = 0; r < 4; r++)
            part[wave][(quad * 4 + r) * 64 + j * 16 + l15] = dacc[j][r];
    __syncthreads();

    // reduce 8 partials, +bd, relu, bf16
    for (int e = tid; e < 1024; e += 512) {
        float s = part[0][e];
#pragma unroll
        for (int w = 1; w < 8; w++) s += part[w][e];
        s += bd[e & 63];
        s = fmaxf(s, 0.f);
        bot_s[(e >> 6) * 72 + (e & 63)] = f2bf(s);
    }
    __syncthreads();

    // phase 2: up-GEMM, wave owns cols [wave*128, +128), K=64
    short8 auf[2];
    auf[0] = *(const short8*)&bot_s[l15 * 72 + quad * 8];
    auf[1] = *(const short8*)&bot_s[l15 * 72 + 32 + quad * 8];
    f32x4 uacc[8];
#pragma unroll
    for (int j = 0; j < 8; j++) uacc[j] = (f32x4){0.f, 0.f, 0.f, 0.f};
#pragma unroll
    for (int j = 0; j < 8; j++) {
        const size_t nb = (size_t)(wave * 128 + j * 16 + l15) * 64;
        short8 b0 = *(const short8*)&WuT[nb + quad * 8];
        short8 b1 = *(const short8*)&WuT[nb + 32 + quad * 8];
        uacc[j] = __builtin_amdgcn_mfma_f32_16x16x32_bf16(auf[0], b0, uacc[j], 0, 0, 0);
        uacc[j] = __builtin_amdgcn_mfma_f32_16x16x32_bf16(auf[1], b1, uacc[j], 0, 0, 0);
    }
    const int f32out = (*flag == 0);
#pragma unroll
    for (int j = 0; j < 8; j++) {
        const int col = wave * 128 + j * 16 + l15;
        const float bv = bu[col];
#pragma unroll
        for (int r = 0; r < 4; r++) {
            const int row = r0 + quad * 4 + r;
            const size_t idx = (size_t)row * 1024 + col;
            float v = uacc[j][r] + bv;
            v += bf2f(hh[idx]);
            v += bf2f(x1[idx]);
            if (f32out) ((float*)out)[idx] = v;
            else ((u16*)out)[idx] = f2bf(v);
        }
    }
}

// ---------------- flash attention v11: paired q-blocks, shared K/V staging --
// r19 WIN (52 -> off top-5). v8b's exact per-wave math; waves 0-3 own qbA,
// waves 4-7 own qbB, shared K/V tile feeds 128 q-rows; zero per-wave VGPR
// change -> VGPR-capped 24 waves/CU (vs LDS-capped 20).
__global__ __launch_bounds__(512) void flash_pair_kernel(const u16* __restrict__ Q,
                                                         const u16* __restrict__ Kg,
                                                         const u16* __restrict__ VtG,
                                                         u16* __restrict__ O,
                                                         u16* __restrict__ pO,
                                                         float* __restrict__ pL) {
    const int tid = threadIdx.x;
    const int wave = tid >> 6, lane = tid & 63;
    const int half = wave >> 2, w4 = wave & 3;
    int i = blockIdx.x, c, p;
    if (i < 16)      { c = 0; p = i; }
    else if (i < 28) { c = 1; p = i - 16; }
    else if (i < 36) { c = 2; p = i - 28; }
    else             { c = 3; p = i - 36; }
    const int qb = 31 - 2 * p - half;          // A: 31-2p (waves 0-3), B: 30-2p
    const int bh = blockIdx.y;
    const int t0 = qb * 64;
    const int steps = qb + 1;
    const int ktbeg = c * 8;
    int ktend = ktbeg + 8; if (steps < ktend) ktend = steps;        // this half
    const int qbA = 31 - 2 * p;
    int ktend_blk = ktbeg + 8; if (qbA + 1 < ktend_blk) ktend_blk = qbA + 1;
    const size_t base = ((size_t)(bh >> 4) * 2048) * 1024 + (size_t)(bh & 15) * 64;
    const size_t basev = (size_t)bh * 64 * 2048;

    __shared__ __align__(16) u16 Ks[2][64 * 64];
    __shared__ __align__(16) u16 Vt[2][64 * 64];
#if !__has_builtin(__builtin_amdgcn_mfma_f32_16x16x16bf16_1k)
    __shared__ __align__(16) u16 Ps[8][16 * 72];
#endif

    const int l15 = lane & 15, quad = lane >> 4;
    const int rmin = t0 + w4 * 16;             // this wave's 16 q-rows

    // Q fragments (B-operand): lane holds Q[qrow=l15][d = st*32 + quad*8 ..+7]
    short8 qf[2];
    {
        const u16* qp = Q + base + (size_t)(rmin + l15) * 1024 + quad * 8;
        qf[0] = *(const short8*)qp;
        qf[1] = *(const short8*)(qp + 32);
    }

    const int slr = lane >> 3;                 // 0..7
    const int sc8 = (lane & 7) ^ slr;          // swizzled source col-chunk
    const int rb = wave * 8;                   // 8 waves x 8 rows = 64-row tile

    auto stage = [&](int kt, int bufi) {
        gl_lds16(Kg + base + (size_t)(kt * 64 + rb + slr) * 1024 + sc8 * 8,
                 &Ks[bufi][rb * 64 + lane * 8]);
        gl_lds16(VtG + basev + (size_t)(rb + slr) * 2048 + kt * 64 + sc8 * 8,
                 &Vt[bufi][rb * 64 + lane * 8]);
    };

    float l_part = 0.f;
    f32x4 oacc[4];
#pragma unroll
    for (int jt = 0; jt < 4; jt++) oacc[jt] = (f32x4){0.f, 0.f, 0.f, 0.f};

    const float Cs = 0.125f * 1.44269504f;     // scale * log2(e)

    stage(ktbeg, 0);
    __syncthreads();

    for (int kt = ktbeg; kt < ktend_blk; kt++) {
        const int cur = kt & 1;
        if (kt + 1 < ktend_blk) stage(kt + 1, cur ^ 1);   // prefetch overlaps compute

        if (kt < ktend) {
            // K fragments (A-operand): lane holds K[key=j*16+l15][d chunk st*4+quad]
            short8 kf[2][4];
#pragma unroll
            for (int st = 0; st < 2; st++)
#pragma unroll
                for (int j = 0; j < 4; j++)
                    kf[st][j] = *(const short8*)&Ks[cur][(j * 16 + l15) * 64 +
                                                         (((st * 4 + quad) ^ (l15 & 7)) * 8)];
#if __has_builtin(__builtin_amdgcn_mfma_f32_16x16x16bf16_1k)
            // V b64 fragments for 16x16x16 PV
            short4v vf[4][4];
#pragma unroll
            for (int j = 0; j < 4; j++) {
                int k8 = j * 2 + (quad >> 1);      // data key-chunk
#pragma unroll
                for (int jt = 0; jt < 4; jt++) {
                    int d = jt * 16 + l15;
                    vf[j][jt] = *(const short4v*)&Vt[cur][d * 64 + ((k8 ^ (d & 7)) * 8) +
                                                          (quad & 1) * 4];
                }
            }
#else
            short8 vf[2][4];
#pragma unroll
            for (int st = 0; st < 2; st++)
#pragma unroll
                for (int jt = 0; jt < 4; jt++) {
                    int d = jt * 16 + l15;
                    vf[st][jt] = *(const short8*)&Vt[cur][d * 64 + (((st * 4 + quad) ^ (d & 7)) * 8)];
                }
#endif

            // S^T = K Q^T : lane gets qrow=l15, keys j*16+quad*4+r
            f32x4 s[4];
#pragma unroll
            for (int j = 0; j < 4; j++) s[j] = (f32x4){0.f, 0.f, 0.f, 0.f};
#pragma unroll
            for (int st = 0; st < 2; st++)
#pragma unroll
                for (int j = 0; j < 4; j++)
                    s[j] = __builtin_amdgcn_mfma_f32_16x16x32_bf16(kf[st][j], qf[st], s[j], 0, 0, 0);

            // softmax: mask fires only on this half's diagonal step (kt==qb)
            float lpv[4] = {0.f, 0.f, 0.f, 0.f};
            short4v pj[4];
            if (kt != qb) {
#pragma unroll
                for (int j = 0; j < 4; j++) {
                    union { short4v v; u16 u[4]; } pk;
#pragma unroll
                    for (int r = 0; r < 4; r++) {
                        float pv = __builtin_amdgcn_exp2f(s[j][r] * Cs);
                        lpv[r] += pv;
                        pk.u[r] = f2bf_fast(pv);
                    }
                    pj[j] = pk.v;
                }
            } else {
                const int qrow = rmin + l15;
#pragma unroll
                for (int j = 0; j < 4; j++) {
                    union { short4v v; u16 u[4]; } pk;
#pragma unroll
                    for (int r = 0; r < 4; r++) {
                        float pv = __builtin_amdgcn_exp2f(s[j][r] * Cs);
                        int key = kt * 64 + j * 16 + quad * 4 + r;
                        if (key > qrow) pv = 0.f;
                        lpv[r] += pv;
                        pk.u[r] = f2bf_fast(pv);
                    }
                    pj[j] = pk.v;
                }
            }
            l_part += (lpv[0] + lpv[1]) + (lpv[2] + lpv[3]);

#if __has_builtin(__builtin_amdgcn_mfma_f32_16x16x16bf16_1k)
            // O += P V, P straight from registers (A-frag match)
#pragma unroll
            for (int jt = 0; jt < 4; jt++)
#pragma unroll
                for (int j = 0; j < 4; j++)
                    oacc[jt] = __builtin_amdgcn_mfma_f32_16x16x16bf16_1k(pj[j], vf[j][jt],
                                                                         oacc[jt], 0, 0, 0);
#else
            u16* Pw = Ps[wave];
#pragma unroll
            for (int j = 0; j < 4; j++)
                *(short4v*)&Pw[l15 * 72 + j * 16 + quad * 4] = pj[j];
#pragma unroll
            for (int st = 0; st < 2; st++) {
                short8 pf2 = *(const short8*)&Pw[l15 * 72 + st * 32 + quad * 8];
#pragma unroll
                for (int jt = 0; jt < 4; jt++)
                    oacc[jt] = __builtin_amdgcn_mfma_f32_16x16x32_bf16(pf2, vf[st][jt],
                                                                      oacc[jt], 0, 0, 0);
            }
#endif
        }
        __syncthreads();
    }

    // l reduction: l lives per qrow=l15; reduce across quads
    float lf = l_part;
    lf += __shfl_xor(lf, 16, 64);
    lf += __shfl_xor(lf, 32, 64);

    if (steps > 8) {
        // multi-chunk q-block: write un-normalized bf16 partials (v8b layout)
        const size_t ib = ((size_t)bh * 24 + (qb - 8)) * 4 + c;
        u16* po = pO + ib * 4096;
#pragma unroll
        for (int jt = 0; jt < 4; jt++)
#pragma unroll
            for (int r = 0; r < 4; r++)
                po[(w4 * 16 + quad * 4 + r) * 64 + jt * 16 + l15] = f2bf(oacc[jt][r]);
        if (quad == 0) pL[ib * 64 + w4 * 16 + l15] = lf;
        return;
    }

    // single-chunk (qb<=7, c==0): normalize and store bf16
    {
        float inv[4];
#pragma unroll
        for (int r = 0; r < 4; r++) inv[r] = 1.f / __shfl(lf, quad * 4 + r, 64);
#pragma unroll
        for (int jt = 0; jt < 4; jt++) {
            int d = jt * 16 + l15;
#pragma unroll
            for (int r = 0; r < 4; r++) {
                int t = rmin + quad * 4 + r;
                O[base + (size_t)t * 1024 + d] = f2bf(oacc[jt][r] * inv[r]);
            }
        }
    }
}

// ---------------- flash attention v8b (non-split fallback, 256 threads) -----
__global__ __launch_bounds__(256) void flash_kernel(const u16* __restrict__ Q,
                                                    const u16* __restrict__ Kg,
                                                    const u16* __restrict__ VtG,
                                                    u16* __restrict__ O) {
    const int tid = threadIdx.x;
    const int wave = tid >> 6, lane = tid & 63;
    const int qb = 31 - blockIdx.x;
    const int bh = blockIdx.y;
    const int t0 = qb * 64;
    const int steps = qb + 1;
    const size_t base = ((size_t)(bh >> 4) * 2048) * 1024 + (size_t)(bh & 15) * 64;
    const size_t basev = (size_t)bh * 64 * 2048;

    __shared__ __align__(16) u16 Ks[2][64 * 64];
    __shared__ __align__(16) u16 Vt[2][64 * 64];
#if !__has_builtin(__builtin_amdgcn_mfma_f32_16x16x16bf16_1k)
    __shared__ __align__(16) u16 Ps[4][16 * 72];
#endif

    const int l15 = lane & 15, quad = lane >> 4;
    const int rmin = t0 + wave * 16;

    short8 qf[2];
    {
        const u16* qp = Q + base + (size_t)(rmin + l15) * 1024 + quad * 8;
        qf[0] = *(const short8*)qp;
        qf[1] = *(const short8*)(qp + 32);
    }

    const int slr = lane >> 3;
    const int sc8 = (lane & 7) ^ slr;
    const int rb = wave * 16;

    auto stage = [&](int kt, int bufi) {
        gl_lds16(Kg + base + (size_t)(kt * 64 + rb + slr) * 1024 + sc8 * 8,
                 &Ks[bufi][rb * 64 + lane * 8]);
        gl_lds16(Kg + base + (size_t)(kt * 64 + rb + 8 + slr) * 1024 + sc8 * 8,
                 &Ks[bufi][(rb + 8) * 64 + lane * 8]);
        gl_lds16(VtG + basev + (size_t)(rb + slr) * 2048 + kt * 64 + sc8 * 8,
                 &Vt[bufi][rb * 64 + lane * 8]);
        gl_lds16(VtG + basev + (size_t)(rb + 8 + slr) * 2048 + kt * 64 + sc8 * 8,
                 &Vt[bufi][(rb + 8) * 64 + lane * 8]);
    };

    float l_part = 0.f;
    f32x4 oacc[4];
#pragma unroll
    for (int jt = 0; jt < 4; jt++) oacc[jt] = (f32x4){0.f, 0.f, 0.f, 0.f};

    const float Cs = 0.125f * 1.44269504f;

    stage(0, 0);
    __syncthreads();

    for (int kt = 0; kt < steps; kt++) {
        const int cur = kt & 1;
        if (kt + 1 < steps) stage(kt + 1, cur ^ 1);

        short8 kf[2][4];
#pragma unroll
        for (int st = 0; st < 2; st++)
#pragma unroll
            for (int j = 0; j < 4; j++)
                kf[st][j] = *(const short8*)&Ks[cur][(j * 16 + l15) * 64 +
                                                     (((st * 4 + quad) ^ (l15 & 7)) * 8)];
#if __has_builtin(__builtin_amdgcn_mfma_f32_16x16x16bf16_1k)
        short4v vf[4][4];
#pragma unroll
        for (int j = 0; j < 4; j++) {
            int k8 = j * 2 + (quad >> 1);
#pragma unroll
            for (int jt = 0; jt < 4; jt++) {
                int d = jt * 16 + l15;
                vf[j][jt] = *(const short4v*)&Vt[cur][d * 64 + ((k8 ^ (d & 7)) * 8) +
                                                      (quad & 1) * 4];
            }
        }
#else
        short8 vf[2][4];
#pragma unroll
        for (int st = 0; st < 2; st++)
#pragma unroll
            for (int jt = 0; jt < 4; jt++) {
                int d = jt * 16 + l15;
                vf[st][jt] = *(const short8*)&Vt[cur][d * 64 + (((st * 4 + quad) ^ (d & 7)) * 8)];
            }
#endif

        f32x4 s[4];
#pragma unroll
        for (int j = 0; j < 4; j++) s[j] = (f32x4){0.f, 0.f, 0.f, 0.f};
#pragma unroll
        for (int st = 0; st < 2; st++)
#pragma unroll
            for (int j = 0; j < 4; j++)
                s[j] = __builtin_amdgcn_mfma_f32_16x16x32_bf16(kf[st][j], qf[st], s[j], 0, 0, 0);

        float lpv[4] = {0.f, 0.f, 0.f, 0.f};
        short4v pj[4];
        if (kt != qb) {
#pragma unroll
            for (int j = 0; j < 4; j++) {
                union { short4v v; u16 u[4]; } pk;
#pragma unroll
                for (int r = 0; r < 4; r++) {
                    float pv = __builtin_amdgcn_exp2f(s[j][r] * Cs);
                    lpv[r] += pv;
                    pk.u[r] = f2bf_fast(pv);
                }
                pj[j] = pk.v;
            }
        } else {
            const int qrow = rmin + l15;
#pragma unroll
            for (int j = 0; j < 4; j++) {
                union { short4v v; u16 u[4]; } pk;
#pragma unroll
                for (int r = 0; r < 4; r++) {
                    float pv = __builtin_amdgcn_exp2f(s[j][r] * Cs);
                    int key = kt * 64 + j * 16 + quad * 4 + r;
                    if (key > qrow) pv = 0.f;
                    lpv[r] += pv;
                    pk.u[r] = f2bf_fast(pv);
                }
                pj[j] = pk.v;
            }
        }
        l_part += (lpv[0] + lpv[1]) + (lpv[2] + lpv[3]);

#if __has_builtin(__builtin_amdgcn_mfma_f32_16x16x16bf16_1k)
#pragma unroll
        for (int jt = 0; jt < 4; jt++)
#pragma unroll
            for (int j = 0; j < 4; j++)
                oacc[jt] = __builtin_amdgcn_mfma_f32_16x16x16bf16_1k(pj[j], vf[j][jt],
                                                                     oacc[jt], 0, 0, 0);
#else
        u16* Pw = Ps[wave];
#pragma unroll
        for (int j = 0; j < 4; j++)
            *(short4v*)&Pw[l15 * 72 + j * 16 + quad * 4] = pj[j];
#pragma unroll
        for (int st = 0; st < 2; st++) {
            short8 pf2 = *(const short8*)&Pw[l15 * 72 + st * 32 + quad * 8];
#pragma unroll
            for (int jt = 0; jt < 4; jt++)
                oacc[jt] = __builtin_amdgcn_mfma_f32_16x16x32_bf16(pf2, vf[st][jt],
                                                                  oacc[jt], 0, 0, 0);
        }
#endif
        __syncthreads();
    }

    float lf = l_part;
    lf += __shfl_xor(lf, 16, 64);
    lf += __shfl_xor(lf, 32, 64);
    float inv[4];
#pragma unroll
    for (int r = 0; r < 4; r++) inv[r] = 1.f / __shfl(lf, quad * 4 + r, 64);
#pragma unroll
    for (int jt = 0; jt < 4; jt++) {
        int d = jt * 16 + l15;
#pragma unroll
        for (int r = 0; r < 4; r++) {
            int t = rmin + quad * 4 + r;
            O[base + (size_t)t * 1024 + d] = f2bf(oacc[jt][r] * inv[r]);
        }
    }
}

// ---------------- flash combine: O = (sum_c O_c) / (sum_c l_c) --------------
__global__ __launch_bounds__(256) void flash_combine_kernel(const u16* __restrict__ pO,
                                                            const float* __restrict__ pL,
                                                            u16* __restrict__ O) {
    const int qj = blockIdx.x;                 // 0..23 -> qb = qj + 8
    const int bh = blockIdx.y;
    const int qb = qj + 8;
    const int nch = (qb >> 3) + 1;             // 2, 3 or 4 chunks
    const int tid = threadIdx.x;
    const int row = tid >> 2;                  // 0..63
    const int d0 = (tid & 3) * 16;
    const size_t ib = ((size_t)bh * 24 + qj) * 4;

    float acc[16];
#pragma unroll
    for (int k = 0; k < 16; k++) acc[k] = 0.f;
    float lsum = 0.f;
    for (int c = 0; c < nch; c++) {
        const u16* po = pO + (ib + c) * 4096 + row * 64 + d0;
        u16 pb[16];
        *(uint4*)pb = *(const uint4*)po;
        *(uint4*)(pb + 8) = *(const uint4*)(po + 8);
#pragma unroll
        for (int k = 0; k < 16; k++) acc[k] += bf2f(pb[k]);
        lsum += pL[(ib + c) * 64 + row];
    }
    const float inv = 1.f / lsum;
    u16 o[16];
#pragma unroll
    for (int k = 0; k < 16; k++) o[k] = f2bf(acc[k] * inv);
    const size_t base = ((size_t)(bh >> 4) * 2048) * 1024 + (size_t)(bh & 15) * 64;
    const int t = qb * 64 + row;
    u16* op = &O[base + (size_t)t * 1024 + d0];
    *(uint4*)op = ((uint4*)o)[0];
    *(uint4*)(op + 8) = ((uint4*)o)[1];
}

extern "C" void kernel_launch(void* const* d_in, const int* in_sizes, int n_in,
                              void* d_out, int out_size, void* d_ws, size_t ws_size,
                              hipStream_t stream) {
    (void)in_sizes; (void)n_in; (void)out_size;
    const void* x   = d_in[0];
    // d_in[1] = attn_mask (int32, pure causal) -- implemented directly
    const void* Wq  = d_in[2];  const void* bq  = d_in[3];
    const void* Wk  = d_in[4];  const void* bk  = d_in[5];
    const void* Wv  = d_in[6];  const void* bv  = d_in[7];
    const void* Wo  = d_in[8];  const void* bo  = d_in[9];
    const void* g1  = d_in[10]; const void* be1 = d_in[11];
    const void* g2  = d_in[12]; const void* be2 = d_in[13];
    const void* W1  = d_in[14]; const void* bf1 = d_in[15];
    const void* W2  = d_in[16]; const void* bf2 = d_in[17];
    const void* Wd  = d_in[18]; const void* bd  = d_in[19];
    const void* Wu  = d_in[20]; const void* bu  = d_in[21];

    uint8_t* w8 = (uint8_t*)d_ws;
    int* flag = (int*)w8;                    // 64 B header
    float* pf = (float*)(w8 + 64);           // f32 param pool
    u16* wsb = (u16*)(w8 + 64 + 65536);      // bf16 arena

    const size_t M1 = 1024ull * 1024ull;
    u16* WqT = wsb;                          // Wq/Wk/Wv transposed, contiguous 3072xK
    u16* WkT = wsb + 1 * M1;
    u16* WvT = wsb + 2 * M1;
    u16* WoT = wsb + 3 * M1;
    u16* W1T = wsb + 4 * M1;                 // 4M
    u16* W2T = wsb + 8 * M1;                 // 4M
    u16* WdT = wsb + 12 * M1;                // 64K
    u16* WuT = wsb + 12 * M1 + 65536;        // 64K
    u16* S0  = wsb + 12 * M1 + 131072;
    u16* Areg = S0;                          // xb
    u16* Breg = S0 + 4 * M1;                 // xn -> attn
    u16* ff1  = S0;                          // 16M spans Areg+Breg+8M fresh
    u16* Creg = S0 + 16 * M1;                // q -> xn2
    u16* Dreg = S0 + 20 * M1;                // k -> x1
    u16* Ereg = S0 + 24 * M1;                // VtG -> hh
    u16* xb = Areg;
    u16* xn = Breg; u16* attn = Breg;
    u16* q = Creg;  u16* xn2 = Creg;
    u16* kk_ = Dreg; u16* x1 = Dreg;
    u16* VtG = Ereg; u16* hh = Ereg;

    // flash partial buffer after the bf16 arena (24MB bf16 O + 1MB f32 l)
    const size_t arena_bytes = (size_t)(64 + 65536) + (40 * M1 + 131072) * 2;
    float* partf = (float*)(w8 + ((arena_bytes + 255) & ~(size_t)255));
    const size_t need = ((arena_bytes + 255) & ~(size_t)255) + 4ull * 4 * M1 * 4;
    const bool sk = ws_size >= need;
    float* flL = partf + 14 * M1;            // flash l partials at +56MB

    float* bqkv_f = pf + 0;    // bq,bk,bv contiguous (3072)
    float* bo_f  = pf + 3072;
    float* bf1_f = pf + 4096;  float* bf2_f = pf + 8192;
    float* bd_f  = pf + 9216;  float* bu_f  = pf + 9280;
    float* g1_f  = pf + 10304; float* be1_f = pf + 11328;
    float* g2_f  = pf + 12352; float* be2_f = pf + 13376;

    // merged prologue: detect + param convert + weight transpose (1 launch)
    Prologue P;
    const void* tsrc[8] = {Wq, Wk, Wv, Wo, W1, W2, Wd, Wu};
    u16* tdst[8] = {WqT, WkT, WvT, WoT, W1T, W2T, WdT, WuT};
    int tR[8] = {1024, 1024, 1024, 1024, 1024, 4096, 1024, 64};
    int tC[8] = {1024, 1024, 1024, 1024, 4096, 1024, 64, 1024};
    int acc_off = 0;
    for (int i = 0; i < 8; i++) {
        P.tsrc[i] = tsrc[i]; P.tdst[i] = tdst[i];
        P.tR[i] = tR[i]; P.tC[i] = tC[i];
        P.toff[i] = acc_off;
        acc_off += (tR[i] >> 5) * (tC[i] >> 5);
    }
    P.ntrans = acc_off;
    const void* psrc[12] = {bq, bk, bv, bo, bf1, bf2, bd, bu, g1, be1, g2, be2};
    int poff[12] = {0, 1024, 2048, 3072, 4096, 8192, 9216, 9280, 10304, 11328, 12352, 13376};
    int pn[12]   = {1024, 1024, 1024, 1024, 4096, 1024, 64, 1024, 1024, 1024, 1024, 1024};
    for (int i = 0; i < 12; i++) { P.psrc[i] = psrc[i]; P.poff[i] = poff[i]; P.pn[i] = pn[i]; }
    prologue_kernel<<<acc_off + 12, 256, 0, stream>>>(P, (const unsigned*)x, flag, pf);

    // fused x-convert + LN1: writes xb (bf16 x) and xn in one pass
    ln_x_kernel<<<4096, 256, 0, stream>>>(x, g1_f, be1_f, xb, xn, flag);
    // TAG 0: fused QKV (N=3072, V transposed per-head into VtG), 768 blocks
    gemm128_kernel<0><<<dim3(24, 32), 512, 0, stream>>>(xn, WqT, bqkv_f, nullptr, nullptr,
                                                        q, kk_, VtG, 4096, 3072, 1024, 0, 2, 0, flag);
    if (sk) {
        flash_pair_kernel<<<dim3(40, 32), 512, 0, stream>>>(q, kk_, VtG, attn, (u16*)partf, flL);
        flash_combine_kernel<<<dim3(24, 32), 256, 0, stream>>>((const u16*)partf, flL, attn);
    } else {
        flash_kernel<<<dim3(32, 32), 256, 0, stream>>>(q, kk_, VtG, attn);
    }
    // TAG 1: Wo projection + bias + residual, BK=128 deep kernel + XCD swizzle
    gemm128d_kernel<1><<<dim3(8, 32), 512, 0, stream>>>(attn, WoT, bo_f, xb,
                                                        x1, 1024, 1024, 0, 1);
    ln_kernel<<<4096, 256, 0, stream>>>(x1, g2_f, be2_f, xn2);
    // TAG 2: FFN1 (relu), 256x256 tile / 128x64 waves
    gemm256w_kernel<2><<<dim3(16, 16), 512, 0, stream>>>(xn2, W1T, bf1_f,
                                                         ff1, 4096, 1024, 1);
    // TAG 3: FFN2, BK=128 deep kernel (64 phases vs 128) + XCD swizzle
    // (r19 measured-best; split-K 2 variant r20/r21 regressed: +64MB HBM
    // round-trip for partials outweighs the occupancy win)
    gemm128d_kernel<3><<<dim3(8, 32), 512, 0, stream>>>(ff1, W2T, bf2_f, nullptr,
                                                        hh, 1024, 4096, 0, 1);
    // fused adapter: replaces TAG4 + reduce + TAG5 (3 launches -> 1)
    adapter_kernel<<<256, 512, 0, stream>>>(hh, x1, WdT, WuT, bd_f, bu_f, d_out, flag);
}

// Round 23
// 382.231 us; speedup vs baseline: 1.0780x; 1.0380x over previous
//
#include <hip/hip_runtime.h>
#include <cstdint>
#include <cstddef>

typedef unsigned short u16;
typedef __attribute__((ext_vector_type(4))) short short4v;
typedef __attribute__((ext_vector_type(8))) short short8;
typedef __attribute__((ext_vector_type(4))) float f32x4;

__device__ __forceinline__ float bf2f(u16 h) { return __uint_as_float(((unsigned)h) << 16); }
__device__ __forceinline__ u16 f2bf(float f) {
    unsigned u = __float_as_uint(f);
    unsigned r = (u + 0x7fffu + ((u >> 16) & 1u)) >> 16;
    return (u16)r;
}
// round-half-up: <=0.5 ULP, 2 VALU ops (flash inner loop)
__device__ __forceinline__ u16 f2bf_fast(float f) {
    return (u16)((__float_as_uint(f) + 0x8000u) >> 16);
}

__device__ __forceinline__ void gl_lds16(const void* g, void* l) {
    __builtin_amdgcn_global_load_lds((const __attribute__((address_space(1))) void*)g,
                                     (__attribute__((address_space(3))) void*)l, 16, 0, 0);
}

// ---------------- merged prologue: detect + param-cvt + weight transpose ----
// r22 found this kernel at 49.4us / 1.04 TB/s -- scalar 2B loads+stores (G13
// violation, hidden below the top-5 cutoff every prior round). Rewritten as
// 64x64-tile transpose with uint4 (8xu16, 16B) loads AND stores: 128B wave
// segments both directions; LDS [64][73] pad -> 8-lane column reads hit 8
// distinct banks (stride 292 dwords == 4 mod 32). fp32 path reads 2x float4,
// rounds with the same f2bf -> numerics byte-identical to the old kernel.
struct Prologue {
    const void* tsrc[8];
    u16* tdst[8];
    int tR[8], tC[8], toff[8];
    const void* psrc[12];
    int poff[12], pn[12];
    int ntrans;
};
__global__ __launch_bounds__(256) void prologue_kernel(Prologue P,
                                                       const unsigned* __restrict__ x,
                                                       int* __restrict__ flag,
                                                       float* __restrict__ pf) {
    // self-detect dtype (1024 samples of x's low u16: bf16 exponent-field test)
    __shared__ int cnt[256];
    int c = 0;
    for (int i = threadIdx.x; i < 1024; i += 256) {
        unsigned lo = x[i] & 0xFFFFu;
        unsigned e = (lo >> 7) & 0xFFu;
        c += (e >= 100u && e <= 150u) ? 1 : 0;
    }
    cnt[threadIdx.x] = c;
    __syncthreads();
    for (int s = 128; s > 0; s >>= 1) {
        if (threadIdx.x < s) cnt[threadIdx.x] += cnt[threadIdx.x + s];
        __syncthreads();
    }
    const int bf = (cnt[0] > 512) ? 1 : 0;
    if (blockIdx.x == 0 && threadIdx.x == 0) *flag = bf;

    const int bid = blockIdx.x;
    if (bid >= P.ntrans) {
        // param convert (12 blocks)
        const int s = bid - P.ntrans;
        const void* sp = P.psrc[s];
        float* dp = pf + P.poff[s];
        const int n = P.pn[s];
        for (int i = threadIdx.x; i < n; i += 256)
            dp[i] = bf ? bf2f(((const u16*)sp)[i]) : ((const float*)sp)[i];
        return;
    }
    // weight transpose+cast: 64x64 tile, vectorized 16B in / 16B out
    __shared__ u16 tile[64][73];
    int m = 0;
#pragma unroll
    for (int i = 1; i < 8; i++) m = (bid >= P.toff[i]) ? i : m;
    const int local = bid - P.toff[m];
    const int R = P.tR[m], C = P.tC[m];
    const int tilesx = C >> 6;
    const int bx = local % tilesx, by = local / tilesx;
    const void* src = P.tsrc[m];
    u16* dst = P.tdst[m];
    const int tid = threadIdx.x;
    const int c0 = (tid & 7) * 8;              // 0..56, 8-u16 chunk
#pragma unroll
    for (int pass = 0; pass < 2; pass++) {
        const int r = pass * 32 + (tid >> 3);  // 0..63
        const size_t idx = (size_t)(by * 64 + r) * C + bx * 64 + c0;
        if (bf) {
            *(uint4*)&tile[r][c0] = *(const uint4*)&((const u16*)src)[idx];
        } else {
            float4 v0 = *(const float4*)&((const float*)src)[idx];
            float4 v1 = *(const float4*)&((const float*)src)[idx + 4];
            u16 t8[8];
            t8[0] = f2bf(v0.x); t8[1] = f2bf(v0.y); t8[2] = f2bf(v0.z); t8[3] = f2bf(v0.w);
            t8[4] = f2bf(v1.x); t8[5] = f2bf(v1.y); t8[6] = f2bf(v1.z); t8[7] = f2bf(v1.w);
            *(uint4*)&tile[r][c0] = *(uint4*)t8;
        }
    }
    __syncthreads();
#pragma unroll
    for (int pass = 0; pass < 2; pass++) {
        const int cc = pass * 32 + (tid >> 3); // dst row = src col, 0..63
        u16 o8[8];
#pragma unroll
        for (int i = 0; i < 8; i++) o8[i] = tile[c0 + i][cc];
        *(uint4*)&dst[(size_t)(bx * 64 + cc) * R + by * 64 + c0] = *(uint4*)o8;
    }
}

// ---------------- fused x-convert + LayerNorm (first LN) --------------------
__global__ __launch_bounds__(256) void ln_x_kernel(const void* __restrict__ X,
                                                   const float* __restrict__ G,
                                                   const float* __restrict__ Be,
                                                   u16* __restrict__ Xb,
                                                   u16* __restrict__ Y,
                                                   const int* __restrict__ flag) {
    const int row = blockIdx.x;
    const int tid = threadIdx.x;
    const int lane = tid & 63, wave = tid >> 6;
    u16 vbuf[4];
    if (*flag) {
        *(uint2*)vbuf = *(const uint2*)((const u16*)X + (size_t)row * 1024 + tid * 4);
    } else {
        float4 v = *(const float4*)((const float*)X + (size_t)row * 1024 + tid * 4);
        vbuf[0] = f2bf(v.x); vbuf[1] = f2bf(v.y); vbuf[2] = f2bf(v.z); vbuf[3] = f2bf(v.w);
    }
    *(uint2*)&Xb[(size_t)row * 1024 + tid * 4] = *(uint2*)vbuf;
    float f[4];
    float s = 0.f, sq = 0.f;
#pragma unroll
    for (int j = 0; j < 4; j++) { f[j] = bf2f(vbuf[j]); s += f[j]; sq += f[j] * f[j]; }
#pragma unroll
    for (int m = 1; m < 64; m <<= 1) { s += __shfl_xor(s, m, 64); sq += __shfl_xor(sq, m, 64); }
    __shared__ float rs_[4], rq_[4];
    if (lane == 0) { rs_[wave] = s; rq_[wave] = sq; }
    __syncthreads();
    float S = rs_[0] + rs_[1] + rs_[2] + rs_[3];
    float Q2 = rq_[0] + rq_[1] + rq_[2] + rq_[3];
    float mean = S * (1.f / 1024.f);
    float var = Q2 * (1.f / 1024.f) - mean * mean;
    float rstd = rsqrtf(var + 1e-5f);
    u16 o[4];
#pragma unroll
    for (int j = 0; j < 4; j++) {
        int c2 = tid * 4 + j;
        float y = (f[j] - mean) * rstd * G[c2] + Be[c2];
        o[j] = f2bf(y);
    }
    *(uint2*)&Y[(size_t)row * 1024 + tid * 4] = *(uint2*)o;
}

// ---------------- LayerNorm over C=1024 (bf16 in, f32 params, bf16 out) -----
__global__ __launch_bounds__(256) void ln_kernel(const u16* __restrict__ X,
                                                 const float* __restrict__ G,
                                                 const float* __restrict__ Be,
                                                 u16* __restrict__ Y) {
    const int row = blockIdx.x;
    const int tid = threadIdx.x;
    const int lane = tid & 63, wave = tid >> 6;
    const u16* xr = X + (size_t)row * 1024;
    u16 vbuf[4];
    *(uint2*)vbuf = *(const uint2*)&xr[tid * 4];
    float f[4];
    float s = 0.f, sq = 0.f;
#pragma unroll
    for (int j = 0; j < 4; j++) { f[j] = bf2f(vbuf[j]); s += f[j]; sq += f[j] * f[j]; }
#pragma unroll
    for (int m = 1; m < 64; m <<= 1) { s += __shfl_xor(s, m, 64); sq += __shfl_xor(sq, m, 64); }
    __shared__ float rs_[4], rq_[4];
    if (lane == 0) { rs_[wave] = s; rq_[wave] = sq; }
    __syncthreads();
    float S = rs_[0] + rs_[1] + rs_[2] + rs_[3];
    float Q2 = rq_[0] + rq_[1] + rq_[2] + rq_[3];
    float mean = S * (1.f / 1024.f);
    float var = Q2 * (1.f / 1024.f) - mean * mean;
    float rstd = rsqrtf(var + 1e-5f);
    u16 o[4];
#pragma unroll
    for (int j = 0; j < 4; j++) {
        int c2 = tid * 4 + j;
        float y = (f[j] - mean) * rstd * G[c2] + Be[c2];
        o[j] = f2bf(y);
    }
    *(uint2*)&Y[(size_t)row * 1024 + tid * 4] = *(uint2*)o;
}

// ---------------- GEMM 128x128 / 8 waves, K-region pipeline, 1 barrier ------
// Round-8 verified kernel. BK=64, 8 waves (32x64/wave), 64KB LDS -> 2 blk/CU
// where the grid supplies them. One barrier per phase. Calendar: t.ph0 stages
// (t+1,k1), waits vmcnt(4) [tail 0]; t.ph1 stages (t+2,k0), waits vmcnt(4)
// [tail 2]. Swizzle involution phys_chunk = logical ^ ((rsub>>1)&3) on BOTH
// global source and ds_read (rule #21).
template <int TAG>
__global__ __launch_bounds__(512, 4) void gemm128_kernel(const u16* __restrict__ A,
                                                         const u16* __restrict__ Bt,
                                                         const float* __restrict__ bias,
                                                         const u16* __restrict__ res1,
                                                         const u16* __restrict__ res2,
                                                         void* __restrict__ out,
                                                         void* __restrict__ out_k,
                                                         void* __restrict__ out_v,
                                                         int M, int N, int K, int relu, int mode,
                                                         int swz,
                                                         const int* __restrict__ flag) {
    (void)flag; (void)M;
    __shared__ __align__(16) u16 As[2][2][128 * 32];   // [buf][kh][row*32+chunk*8] = 8KB each
    __shared__ __align__(16) u16 Bs[2][2][128 * 32];
    const int tid = threadIdx.x;
    const int wave = tid >> 6, lane = tid & 63;
    const int l15 = lane & 15, quad = lane >> 4;
    const int wr = wave & 3, wc = wave >> 2;           // 4x2 wave grid: 32x64 per wave
    int bx = blockIdx.x, by = blockIdx.y;
    if (swz) {
        const int gx = gridDim.x;
        const int nwg = gx * gridDim.y;
        const int bid = by * gx + bx;
        const int sbid = (bid & 7) * (nwg >> 3) + (bid >> 3);  // XCD-chunked, bijective
        bx = sbid % gx;
        by = sbid / gx;
    }
    const int m0 = by * 128, n0 = bx * 128;
    const int nt = K >> 6;

    const int rsub = lane >> 2;                        // 0..15
    const int logc = (lane & 3) ^ ((rsub >> 1) & 3);

    auto stage_pair = [&](int t, int kh) {
        const int buf = t & 1;
        const int kk = (t << 6) + (kh << 5) + logc * 8;
        const int roff = wave * 16 + rsub;
        gl_lds16(A + (size_t)(m0 + roff) * K + kk, &As[buf][kh][wave * 512 + lane * 8]);
        gl_lds16(Bt + (size_t)(n0 + roff) * K + kk, &Bs[buf][kh][wave * 512 + lane * 8]);
    };

    f32x4 acc[2][4];
#pragma unroll
    for (int i = 0; i < 2; i++)
#pragma unroll
        for (int j = 0; j < 4; j++) acc[i][j] = (f32x4){0.f, 0.f, 0.f, 0.f};

    stage_pair(0, 0);
    stage_pair(0, 1);
    stage_pair(1, 0);
    asm volatile("s_waitcnt vmcnt(4)" ::: "memory");
    __builtin_amdgcn_s_barrier();

    const int rx = (l15 >> 1) & 3;                     // read-side involution
    for (int t = 0; t < nt; t++) {
        const int b = t & 1;
#pragma unroll
        for (int ph = 0; ph < 2; ph++) {
            const int kh = ph;
            short8 af[2], bfr[4];
#pragma unroll
            for (int i = 0; i < 2; i++)
                af[i] = *(const short8*)&As[b][kh][(wr * 32 + i * 16 + l15) * 32 +
                                                   ((quad ^ rx) << 3)];
#pragma unroll
            for (int j = 0; j < 4; j++)
                bfr[j] = *(const short8*)&Bs[b][kh][(wc * 64 + j * 16 + l15) * 32 +
                                                    ((quad ^ rx) << 3)];
            if (ph == 0) { if (t + 1 < nt) stage_pair(t + 1, 1); }
            else         { if (t + 2 < nt) stage_pair(t + 2, 0); }
            __builtin_amdgcn_s_setprio(1);
#pragma unroll
            for (int i = 0; i < 2; i++)
#pragma unroll
                for (int j = 0; j < 4; j++)
                    acc[i][j] = __builtin_amdgcn_mfma_f32_16x16x32_bf16(
                        af[i], bfr[j], acc[i][j], 0, 0, 0);
            __builtin_amdgcn_s_setprio(0);
            if (ph == 0) {
                if (t + 1 < nt) { asm volatile("s_waitcnt vmcnt(4)" ::: "memory"); }
                else            { asm volatile("s_waitcnt vmcnt(0)" ::: "memory"); }
            } else {
                if (t + 2 < nt)      { asm volatile("s_waitcnt vmcnt(4)" ::: "memory"); }
                else if (t + 1 < nt) { asm volatile("s_waitcnt vmcnt(2)" ::: "memory"); }
            }
            __builtin_amdgcn_s_barrier();
        }
    }

    // epilogue: C/D layout col=lane&15, row=quad*4+r (m89-verified)
    if (mode == 2) {
        const int region = n0 >> 10;
        if (region < 2) {
            u16* o = (u16*)(region == 0 ? out : out_k);
#pragma unroll
            for (int j = 0; j < 4; j++) {
                const int col = n0 + wc * 64 + j * 16 + l15;
                const float bv = bias[col];
                const int cl = col & 1023;
#pragma unroll
                for (int i = 0; i < 2; i++) {
                    const int row0 = m0 + wr * 32 + i * 16 + quad * 4;
#pragma unroll
                    for (int r = 0; r < 4; r++)
                        o[(size_t)(row0 + r) * 1024 + cl] = f2bf(acc[i][j][r] + bv);
                }
            }
        } else {
            u16* o = (u16*)out_v;
#pragma unroll
            for (int j = 0; j < 4; j++) {
                const int col = n0 + wc * 64 + j * 16 + l15;
                const float bv = bias[col];
                const int cl = col & 1023;
                const int h = cl >> 6, d = cl & 63;
#pragma unroll
                for (int i = 0; i < 2; i++) {
                    const int row_base = m0 + wr * 32 + i * 16 + quad * 4;
                    const int bb = row_base >> 11, tt = row_base & 2047;
                    u16 pk[4];
#pragma unroll
                    for (int r = 0; r < 4; r++) pk[r] = f2bf(acc[i][j][r] + bv);
                    *(uint2*)&o[(((size_t)bb * 16 + h) * 64 + d) * 2048 + tt] = *(uint2*)pk;
                }
            }
        }
        return;
    }
    // mode 0: bias [+relu] [+res] -> bf16
#pragma unroll
    for (int j = 0; j < 4; j++) {
        const int col = n0 + wc * 64 + j * 16 + l15;
        const float bv = bias ? bias[col] : 0.f;
#pragma unroll
        for (int i = 0; i < 2; i++) {
            const int row0 = m0 + wr * 32 + i * 16 + quad * 4;
#pragma unroll
            for (int r = 0; r < 4; r++) {
                float v = acc[i][j][r] + bv;
                if (relu) v = fmaxf(v, 0.f);
                const size_t idx = (size_t)(row0 + r) * N + col;
                if (res1) v += bf2f(res1[idx]);
                if (res2) v += bf2f(res2[idx]);
                ((u16*)out)[idx] = f2bf(v);
            }
        }
    }
}

// ---------------- GEMM 256x256 / 8 waves of 128x64, K-region pipeline -------
// FFN1 kernel (r18). K-MAJOR regions As/Bs[buf][kh][256*32] (16KB). Calendar
// at 4 loads/stage: prologue vmcnt(8); ph0-end vmcnt(8) [tail 0]; ph1-end
// vmcnt(8) [tail 4]. Both-sides involution ((row&15)>>1)&3 (rule #21).
template <int TAG>
__global__ __launch_bounds__(512, 2) void gemm256w_kernel(const u16* __restrict__ A,
                                                          const u16* __restrict__ Bt,
                                                          const float* __restrict__ bias,
                                                          void* __restrict__ out,
                                                          int N, int K, int relu) {
    __shared__ __align__(16) u16 As[2][2][256 * 32];   // [buf][kh] 16KB regions
    __shared__ __align__(16) u16 Bs[2][2][256 * 32];
    const int tid = threadIdx.x;
    const int wave = tid >> 6, lane = tid & 63;
    const int l15 = lane & 15, quad = lane >> 4;
    const int wr = wave >> 2, wc = wave & 3;           // 2x4 wave grid: 128x64 per wave
    const int m0 = blockIdx.y * 256, n0 = blockIdx.x * 256;
    const int nt = K >> 6;

    const int rsub = lane >> 2;                        // 0..15
    const int logc = (lane & 3) ^ ((rsub >> 1) & 3);   // involution, +16-row invariant

    auto stage_pair = [&](int t, int kh) {
        const int buf = t & 1;
        const int kk = (t << 6) + (kh << 5) + logc * 8;
        const int r0 = wave * 32 + rsub;
        u16* da = &As[buf][kh][wave * 1024 + lane * 8];
        u16* db = &Bs[buf][kh][wave * 1024 + lane * 8];
        gl_lds16(A + (size_t)(m0 + r0) * K + kk, da);
        gl_lds16(A + (size_t)(m0 + r0 + 16) * K + kk, da + 512);
        gl_lds16(Bt + (size_t)(n0 + r0) * K + kk, db);
        gl_lds16(Bt + (size_t)(n0 + r0 + 16) * K + kk, db + 512);
    };

    f32x4 acc[8][4];
#pragma unroll
    for (int i = 0; i < 8; i++)
#pragma unroll
        for (int j = 0; j < 4; j++) acc[i][j] = (f32x4){0.f, 0.f, 0.f, 0.f};

    stage_pair(0, 0);
    stage_pair(0, 1);
    stage_pair(1, 0);
    asm volatile("s_waitcnt vmcnt(8)" ::: "memory");
    __builtin_amdgcn_s_barrier();

    const int rx = (l15 >> 1) & 3;                     // read-side involution
    for (int t = 0; t < nt; t++) {
        const int b = t & 1;
#pragma unroll
        for (int ph = 0; ph < 2; ph++) {
            const int kh = ph;
            short8 af[8], bfr[4];
#pragma unroll
            for (int i = 0; i < 8; i++)
                af[i] = *(const short8*)&As[b][kh][(wr * 128 + i * 16 + l15) * 32 +
                                                   ((quad ^ rx) << 3)];
#pragma unroll
            for (int j = 0; j < 4; j++)
                bfr[j] = *(const short8*)&Bs[b][kh][(wc * 64 + j * 16 + l15) * 32 +
                                                    ((quad ^ rx) << 3)];
            if (ph == 0) { if (t + 1 < nt) stage_pair(t + 1, 1); }
            else         { if (t + 2 < nt) stage_pair(t + 2, 0); }
            __builtin_amdgcn_s_setprio(1);
#pragma unroll
            for (int i = 0; i < 8; i++)
#pragma unroll
                for (int j = 0; j < 4; j++)
                    acc[i][j] = __builtin_amdgcn_mfma_f32_16x16x32_bf16(
                        af[i], bfr[j], acc[i][j], 0, 0, 0);
            __builtin_amdgcn_s_setprio(0);
            if (ph == 0) {
                if (t + 1 < nt) { asm volatile("s_waitcnt vmcnt(8)" ::: "memory"); }
                else            { asm volatile("s_waitcnt vmcnt(0)" ::: "memory"); }
            } else {
                if (t + 2 < nt)      { asm volatile("s_waitcnt vmcnt(8)" ::: "memory"); }
                else if (t + 1 < nt) { asm volatile("s_waitcnt vmcnt(4)" ::: "memory"); }
            }
            __builtin_amdgcn_s_barrier();
        }
    }

    // epilogue: bias [+relu] -> bf16 (m89-verified C/D layout)
#pragma unroll
    for (int j = 0; j < 4; j++) {
        const int col = n0 + wc * 64 + j * 16 + l15;
        const float bv = bias ? bias[col] : 0.f;
#pragma unroll
        for (int i = 0; i < 8; i++) {
            const int row0 = m0 + wr * 128 + i * 16 + quad * 4;
#pragma unroll
            for (int r = 0; r < 4; r++) {
                float v = acc[i][j][r] + bv;
                if (relu) v = fmaxf(v, 0.f);
                ((u16*)out)[(size_t)(row0 + r) * N + col] = f2bf(v);
            }
        }
    }
}

// ---------------- GEMM 128x128 DEEP: BK=128, for 1-block/CU grids -----------
// For grid-256 shapes (Wo, FFN2). Calendar at 4 loads/stage: prologue
// vmcnt(8); ph0-end vmcnt(8) [tail 0]; ph1-end vmcnt(8) [tail 4].
// r19-21 lesson: split-K 2 variant trades an extra 64MB HBM round-trip for
// occupancy and nets -6us vs this kernel -- phase latency here is intrinsic.
template <int TAG>
__global__ __launch_bounds__(512, 2) void gemm128d_kernel(const u16* __restrict__ A,
                                                          const u16* __restrict__ Bt,
                                                          const float* __restrict__ bias,
                                                          const u16* __restrict__ res1,
                                                          void* __restrict__ out,
                                                          int N, int K, int relu, int swz) {
    __shared__ __align__(16) u16 As[2][2][128 * 64];   // [buf][kh] 16KB regions
    __shared__ __align__(16) u16 Bs[2][2][128 * 64];
    const int tid = threadIdx.x;
    const int wave = tid >> 6, lane = tid & 63;
    const int l15 = lane & 15, quad = lane >> 4;
    const int wr = wave & 3, wc = wave >> 2;           // 4x2 wave grid: 32x64 per wave
    int bx = blockIdx.x, by = blockIdx.y;
    if (swz) {
        const int gx = gridDim.x;
        const int nwg = gx * gridDim.y;
        const int bid = by * gx + bx;
        const int sbid = (bid & 7) * (nwg >> 3) + (bid >> 3);  // XCD-chunked, bijective
        bx = sbid % gx;
        by = sbid / gx;
    }
    const int m0 = by * 128, n0 = bx * 128;
    const int nt = K >> 7;                             // BK=128 tiles

    const int srow = lane >> 3;                        // 0..7
    const int logc = (lane & 7) ^ ((lane >> 4) & 3);   // involution, +8-row invariant

    auto stage_pair = [&](int t, int kh) {
        const int buf = t & 1;
        const int kk = (t << 7) + (kh << 6) + logc * 8;
        const int r0 = wave * 16 + srow;
        u16* da = &As[buf][kh][wave * 1024 + lane * 8];
        u16* db = &Bs[buf][kh][wave * 1024 + lane * 8];
        gl_lds16(A + (size_t)(m0 + r0) * K + kk, da);
        gl_lds16(A + (size_t)(m0 + r0 + 8) * K + kk, da + 512);
        gl_lds16(Bt + (size_t)(n0 + r0) * K + kk, db);
        gl_lds16(Bt + (size_t)(n0 + r0 + 8) * K + kk, db + 512);
    };

    f32x4 acc[2][4];
#pragma unroll
    for (int i = 0; i < 2; i++)
#pragma unroll
        for (int j = 0; j < 4; j++) acc[i][j] = (f32x4){0.f, 0.f, 0.f, 0.f};

    stage_pair(0, 0);
    stage_pair(0, 1);
    stage_pair(1, 0);
    asm volatile("s_waitcnt vmcnt(8)" ::: "memory");
    __builtin_amdgcn_s_barrier();

    const int rx = (l15 >> 1) & 3;                     // read-side involution
    for (int t = 0; t < nt; t++) {
        const int b = t & 1;
#pragma unroll
        for (int ph = 0; ph < 2; ph++) {
            const int kh = ph;
            short8 af[2][2], bfr[4][2];
#pragma unroll
            for (int ks = 0; ks < 2; ks++) {
                const int ck = ((ks << 2) | (quad ^ rx)) << 3;
#pragma unroll
                for (int i = 0; i < 2; i++)
                    af[i][ks] = *(const short8*)&As[b][kh][(wr * 32 + i * 16 + l15) * 64 + ck];
#pragma unroll
                for (int j = 0; j < 4; j++)
                    bfr[j][ks] = *(const short8*)&Bs[b][kh][(wc * 64 + j * 16 + l15) * 64 + ck];
            }
            if (ph == 0) { if (t + 1 < nt) stage_pair(t + 1, 1); }
            else         { if (t + 2 < nt) stage_pair(t + 2, 0); }
            __builtin_amdgcn_s_setprio(1);
#pragma unroll
            for (int ks = 0; ks < 2; ks++)
#pragma unroll
                for (int i = 0; i < 2; i++)
#pragma unroll
                    for (int j = 0; j < 4; j++)
                        acc[i][j] = __builtin_amdgcn_mfma_f32_16x16x32_bf16(
                            af[i][ks], bfr[j][ks], acc[i][j], 0, 0, 0);
            __builtin_amdgcn_s_setprio(0);
            if (ph == 0) {
                if (t + 1 < nt) { asm volatile("s_waitcnt vmcnt(8)" ::: "memory"); }
                else            { asm volatile("s_waitcnt vmcnt(0)" ::: "memory"); }
            } else {
                if (t + 2 < nt)      { asm volatile("s_waitcnt vmcnt(8)" ::: "memory"); }
                else if (t + 1 < nt) { asm volatile("s_waitcnt vmcnt(4)" ::: "memory"); }
            }
            __builtin_amdgcn_s_barrier();
        }
    }

    // epilogue: bias [+relu] [+res1] -> bf16 (m89-verified C/D layout)
#pragma unroll
    for (int j = 0; j < 4; j++) {
        const int col = n0 + wc * 64 + j * 16 + l15;
        const float bv = bias ? bias[col] : 0.f;
#pragma unroll
        for (int i = 0; i < 2; i++) {
            const int row0 = m0 + wr * 32 + i * 16 + quad * 4;
#pragma unroll
            for (int r = 0; r < 4; r++) {
                float v = acc[i][j][r] + bv;
                if (relu) v = fmaxf(v, 0.f);
                const size_t idx = (size_t)(row0 + r) * N + col;
                if (res1) v += bf2f(res1[idx]);
                ((u16*)out)[idx] = f2bf(v);
            }
        }
    }
}

// ---------------- fused adapter: out = x1 + hh + relu(hh@Wd+bd)@Wu + bu -----
__global__ __launch_bounds__(512) void adapter_kernel(const u16* __restrict__ hh,
                                                      const u16* __restrict__ x1,
                                                      const u16* __restrict__ WdT,
                                                      const u16* __restrict__ WuT,
                                                      const float* __restrict__ bd,
                                                      const float* __restrict__ bu,
                                                      void* __restrict__ out,
                                                      const int* __restrict__ flag) {
    const int tid = threadIdx.x;
    const int wave = tid >> 6, lane = tid & 63;
    const int l15 = lane & 15, quad = lane >> 4;
    const int r0 = blockIdx.x * 16;

    __shared__ float part[8][16 * 64];
    __shared__ __align__(16) u16 bot_s[16 * 72];       // 72-pad: conflict-free A-frag reads

    // phase 1: down-GEMM partial over this wave's K-slice
    f32x4 dacc[4];
#pragma unroll
    for (int j = 0; j < 4; j++) dacc[j] = (f32x4){0.f, 0.f, 0.f, 0.f};
    const int kw = wave * 128;
#pragma unroll
    for (int ks = 0; ks < 4; ks++) {
        const int k0 = kw + ks * 32 + quad * 8;
        short8 af = *(const short8*)&hh[(size_t)(r0 + l15) * 1024 + k0];
#pragma unroll
        for (int j = 0; j < 4; j++) {
            short8 bf = *(const short8*)&WdT[(size_t)(j * 16 + l15) * 1024 + k0];
            dacc[j] = __builtin_amdgcn_mfma_f32_16x16x32_bf16(af, bf, dacc[j], 0, 0, 0);
        }
    }
#pragma unroll
    for (int j = 0; j < 4; j++)
#pragma unroll
        for (int r = 0; r < 4; r++)
            part[wave][(quad * 4 + r) * 64 + j * 16 + l15] = dacc[j][r];
    __syncthreads();

    // reduce 8 partials, +bd, relu, bf16
    for (int e = tid; e < 1024; e += 512) {
        float s = part[0][e];
#pragma unroll
        for (int w = 1; w < 8; w++) s += part[w][e];
        s += bd[e & 63];
        s = fmaxf(s, 0.f);
        bot_s[(e >> 6) * 72 + (e & 63)] = f2bf(s);
    }
    __syncthreads();

    // phase 2: up-GEMM, wave owns cols [wave*128, +128), K=64
    short8 auf[2];
    auf[0] = *(const short8*)&bot_s[l15 * 72 + quad * 8];
    auf[1] = *(const short8*)&bot_s[l15 * 72 + 32 + quad * 8];
    f32x4 uacc[8];
#pragma unroll
    for (int j = 0; j < 8; j++) uacc[j] = (f32x4){0.f, 0.f, 0.f, 0.f};
#pragma unroll
    for (int j = 0; j < 8; j++) {
        const size_t nb = (size_t)(wave * 128 + j * 16 + l15) * 64;
        short8 b0 = *(const short8*)&WuT[nb + quad * 8];
        short8 b1 = *(const short8*)&WuT[nb + 32 + quad * 8];
        uacc[j] = __builtin_amdgcn_mfma_f32_16x16x32_bf16(auf[0], b0, uacc[j], 0, 0, 0);
        uacc[j] = __builtin_amdgcn_mfma_f32_16x16x32_bf16(auf[1], b1, uacc[j], 0, 0, 0);
    }
    const int f32out = (*flag == 0);
#pragma unroll
    for (int j = 0; j < 8; j++) {
        const int col = wave * 128 + j * 16 + l15;
        const float bv = bu[col];
#pragma unroll
        for (int r = 0; r < 4; r++) {
            const int row = r0 + quad * 4 + r;
            const size_t idx = (size_t)row * 1024 + col;
            float v = uacc[j][r] + bv;
            v += bf2f(hh[idx]);
            v += bf2f(x1[idx]);
            if (f32out) ((float*)out)[idx] = v;
            else ((u16*)out)[idx] = f2bf(v);
        }
    }
}

// ---------------- flash attention v11: paired q-blocks, shared K/V staging --
// r19 WIN (52 -> off top-5). v8b's exact per-wave math; waves 0-3 own qbA,
// waves 4-7 own qbB, shared K/V tile feeds 128 q-rows; zero per-wave VGPR
// change -> VGPR-capped 24 waves/CU (vs LDS-capped 20).
__global__ __launch_bounds__(512) void flash_pair_kernel(const u16* __restrict__ Q,
                                                         const u16* __restrict__ Kg,
                                                         const u16* __restrict__ VtG,
                                                         u16* __restrict__ O,
                                                         u16* __restrict__ pO,
                                                         float* __restrict__ pL) {
    const int tid = threadIdx.x;
    const int wave = tid >> 6, lane = tid & 63;
    const int half = wave >> 2, w4 = wave & 3;
    int i = blockIdx.x, c, p;
    if (i < 16)      { c = 0; p = i; }
    else if (i < 28) { c = 1; p = i - 16; }
    else if (i < 36) { c = 2; p = i - 28; }
    else             { c = 3; p = i - 36; }
    const int qb = 31 - 2 * p - half;          // A: 31-2p (waves 0-3), B: 30-2p
    const int bh = blockIdx.y;
    const int t0 = qb * 64;
    const int steps = qb + 1;
    const int ktbeg = c * 8;
    int ktend = ktbeg + 8; if (steps < ktend) ktend = steps;        // this half
    const int qbA = 31 - 2 * p;
    int ktend_blk = ktbeg + 8; if (qbA + 1 < ktend_blk) ktend_blk = qbA + 1;
    const size_t base = ((size_t)(bh >> 4) * 2048) * 1024 + (size_t)(bh & 15) * 64;
    const size_t basev = (size_t)bh * 64 * 2048;

    __shared__ __align__(16) u16 Ks[2][64 * 64];
    __shared__ __align__(16) u16 Vt[2][64 * 64];
#if !__has_builtin(__builtin_amdgcn_mfma_f32_16x16x16bf16_1k)
    __shared__ __align__(16) u16 Ps[8][16 * 72];
#endif

    const int l15 = lane & 15, quad = lane >> 4;
    const int rmin = t0 + w4 * 16;             // this wave's 16 q-rows

    // Q fragments (B-operand): lane holds Q[qrow=l15][d = st*32 + quad*8 ..+7]
    short8 qf[2];
    {
        const u16* qp = Q + base + (size_t)(rmin + l15) * 1024 + quad * 8;
        qf[0] = *(const short8*)qp;
        qf[1] = *(const short8*)(qp + 32);
    }

    const int slr = lane >> 3;                 // 0..7
    const int sc8 = (lane & 7) ^ slr;          // swizzled source col-chunk
    const int rb = wave * 8;                   // 8 waves x 8 rows = 64-row tile

    auto stage = [&](int kt, int bufi) {
        gl_lds16(Kg + base + (size_t)(kt * 64 + rb + slr) * 1024 + sc8 * 8,
                 &Ks[bufi][rb * 64 + lane * 8]);
        gl_lds16(VtG + basev + (size_t)(rb + slr) * 2048 + kt * 64 + sc8 * 8,
                 &Vt[bufi][rb * 64 + lane * 8]);
    };

    float l_part = 0.f;
    f32x4 oacc[4];
#pragma unroll
    for (int jt = 0; jt < 4; jt++) oacc[jt] = (f32x4){0.f, 0.f, 0.f, 0.f};

    const float Cs = 0.125f * 1.44269504f;     // scale * log2(e)

    stage(ktbeg, 0);
    __syncthreads();

    for (int kt = ktbeg; kt < ktend_blk; kt++) {
        const int cur = kt & 1;
        if (kt + 1 < ktend_blk) stage(kt + 1, cur ^ 1);   // prefetch overlaps compute

        if (kt < ktend) {
            // K fragments (A-operand): lane holds K[key=j*16+l15][d chunk st*4+quad]
            short8 kf[2][4];
#pragma unroll
            for (int st = 0; st < 2; st++)
#pragma unroll
                for (int j = 0; j < 4; j++)
                    kf[st][j] = *(const short8*)&Ks[cur][(j * 16 + l15) * 64 +
                                                         (((st * 4 + quad) ^ (l15 & 7)) * 8)];
#if __has_builtin(__builtin_amdgcn_mfma_f32_16x16x16bf16_1k)
            // V b64 fragments for 16x16x16 PV
            short4v vf[4][4];
#pragma unroll
            for (int j = 0; j < 4; j++) {
                int k8 = j * 2 + (quad >> 1);      // data key-chunk
#pragma unroll
                for (int jt = 0; jt < 4; jt++) {
                    int d = jt * 16 + l15;
                    vf[j][jt] = *(const short4v*)&Vt[cur][d * 64 + ((k8 ^ (d & 7)) * 8) +
                                                          (quad & 1) * 4];
                }
            }
#else
            short8 vf[2][4];
#pragma unroll
            for (int st = 0; st < 2; st++)
#pragma unroll
                for (int jt = 0; jt < 4; jt++) {
                    int d = jt * 16 + l15;
                    vf[st][jt] = *(const short8*)&Vt[cur][d * 64 + (((st * 4 + quad) ^ (d & 7)) * 8)];
                }
#endif

            // S^T = K Q^T : lane gets qrow=l15, keys j*16+quad*4+r
            f32x4 s[4];
#pragma unroll
            for (int j = 0; j < 4; j++) s[j] = (f32x4){0.f, 0.f, 0.f, 0.f};
#pragma unroll
            for (int st = 0; st < 2; st++)
#pragma unroll
                for (int j = 0; j < 4; j++)
                    s[j] = __builtin_amdgcn_mfma_f32_16x16x32_bf16(kf[st][j], qf[st], s[j], 0, 0, 0);

            // softmax: mask fires only on this half's diagonal step (kt==qb)
            float lpv[4] = {0.f, 0.f, 0.f, 0.f};
            short4v pj[4];
            if (kt != qb) {
#pragma unroll
                for (int j = 0; j < 4; j++) {
                    union { short4v v; u16 u[4]; } pk;
#pragma unroll
                    for (int r = 0; r < 4; r++) {
                        float pv = __builtin_amdgcn_exp2f(s[j][r] * Cs);
                        lpv[r] += pv;
                        pk.u[r] = f2bf_fast(pv);
                    }
                    pj[j] = pk.v;
                }
            } else {
                const int qrow = rmin + l15;
#pragma unroll
                for (int j = 0; j < 4; j++) {
                    union { short4v v; u16 u[4]; } pk;
#pragma unroll
                    for (int r = 0; r < 4; r++) {
                        float pv = __builtin_amdgcn_exp2f(s[j][r] * Cs);
                        int key = kt * 64 + j * 16 + quad * 4 + r;
                        if (key > qrow) pv = 0.f;
                        lpv[r] += pv;
                        pk.u[r] = f2bf_fast(pv);
                    }
                    pj[j] = pk.v;
                }
            }
            l_part += (lpv[0] + lpv[1]) + (lpv[2] + lpv[3]);

#if __has_builtin(__builtin_amdgcn_mfma_f32_16x16x16bf16_1k)
            // O += P V, P straight from registers (A-frag match)
#pragma unroll
            for (int jt = 0; jt < 4; jt++)
#pragma unroll
                for (int j = 0; j < 4; j++)
                    oacc[jt] = __builtin_amdgcn_mfma_f32_16x16x16bf16_1k(pj[j], vf[j][jt],
                                                                         oacc[jt], 0, 0, 0);
#else
            u16* Pw = Ps[wave];
#pragma unroll
            for (int j = 0; j < 4; j++)
                *(short4v*)&Pw[l15 * 72 + j * 16 + quad * 4] = pj[j];
#pragma unroll
            for (int st = 0; st < 2; st++) {
                short8 pf2 = *(const short8*)&Pw[l15 * 72 + st * 32 + quad * 8];
#pragma unroll
                for (int jt = 0; jt < 4; jt++)
                    oacc[jt] = __builtin_amdgcn_mfma_f32_16x16x32_bf16(pf2, vf[st][jt],
                                                                      oacc[jt], 0, 0, 0);
            }
#endif
        }
        __syncthreads();
    }

    // l reduction: l lives per qrow=l15; reduce across quads
    float lf = l_part;
    lf += __shfl_xor(lf, 16, 64);
    lf += __shfl_xor(lf, 32, 64);

    if (steps > 8) {
        // multi-chunk q-block: write un-normalized bf16 partials (v8b layout)
        const size_t ib = ((size_t)bh * 24 + (qb - 8)) * 4 + c;
        u16* po = pO + ib * 4096;
#pragma unroll
        for (int jt = 0; jt < 4; jt++)
#pragma unroll
            for (int r = 0; r < 4; r++)
                po[(w4 * 16 + quad * 4 + r) * 64 + jt * 16 + l15] = f2bf(oacc[jt][r]);
        if (quad == 0) pL[ib * 64 + w4 * 16 + l15] = lf;
        return;
    }

    // single-chunk (qb<=7, c==0): normalize and store bf16
    {
        float inv[4];
#pragma unroll
        for (int r = 0; r < 4; r++) inv[r] = 1.f / __shfl(lf, quad * 4 + r, 64);
#pragma unroll
        for (int jt = 0; jt < 4; jt++) {
            int d = jt * 16 + l15;
#pragma unroll
            for (int r = 0; r < 4; r++) {
                int t = rmin + quad * 4 + r;
                O[base + (size_t)t * 1024 + d] = f2bf(oacc[jt][r] * inv[r]);
            }
        }
    }
}

// ---------------- flash attention v8b (non-split fallback, 256 threads) -----
__global__ __launch_bounds__(256) void flash_kernel(const u16* __restrict__ Q,
                                                    const u16* __restrict__ Kg,
                                                    const u16* __restrict__ VtG,
                                                    u16* __restrict__ O) {
    const int tid = threadIdx.x;
    const int wave = tid >> 6, lane = tid & 63;
    const int qb = 31 - blockIdx.x;
    const int bh = blockIdx.y;
    const int t0 = qb * 64;
    const int steps = qb + 1;
    const size_t base = ((size_t)(bh >> 4) * 2048) * 1024 + (size_t)(bh & 15) * 64;
    const size_t basev = (size_t)bh * 64 * 2048;

    __shared__ __align__(16) u16 Ks[2][64 * 64];
    __shared__ __align__(16) u16 Vt[2][64 * 64];
#if !__has_builtin(__builtin_amdgcn_mfma_f32_16x16x16bf16_1k)
    __shared__ __align__(16) u16 Ps[4][16 * 72];
#endif

    const int l15 = lane & 15, quad = lane >> 4;
    const int rmin = t0 + wave * 16;

    short8 qf[2];
    {
        const u16* qp = Q + base + (size_t)(rmin + l15) * 1024 + quad * 8;
        qf[0] = *(const short8*)qp;
        qf[1] = *(const short8*)(qp + 32);
    }

    const int slr = lane >> 3;
    const int sc8 = (lane & 7) ^ slr;
    const int rb = wave * 16;

    auto stage = [&](int kt, int bufi) {
        gl_lds16(Kg + base + (size_t)(kt * 64 + rb + slr) * 1024 + sc8 * 8,
                 &Ks[bufi][rb * 64 + lane * 8]);
        gl_lds16(Kg + base + (size_t)(kt * 64 + rb + 8 + slr) * 1024 + sc8 * 8,
                 &Ks[bufi][(rb + 8) * 64 + lane * 8]);
        gl_lds16(VtG + basev + (size_t)(rb + slr) * 2048 + kt * 64 + sc8 * 8,
                 &Vt[bufi][rb * 64 + lane * 8]);
        gl_lds16(VtG + basev + (size_t)(rb + 8 + slr) * 2048 + kt * 64 + sc8 * 8,
                 &Vt[bufi][(rb + 8) * 64 + lane * 8]);
    };

    float l_part = 0.f;
    f32x4 oacc[4];
#pragma unroll
    for (int jt = 0; jt < 4; jt++) oacc[jt] = (f32x4){0.f, 0.f, 0.f, 0.f};

    const float Cs = 0.125f * 1.44269504f;

    stage(0, 0);
    __syncthreads();

    for (int kt = 0; kt < steps; kt++) {
        const int cur = kt & 1;
        if (kt + 1 < steps) stage(kt + 1, cur ^ 1);

        short8 kf[2][4];
#pragma unroll
        for (int st = 0; st < 2; st++)
#pragma unroll
            for (int j = 0; j < 4; j++)
                kf[st][j] = *(const short8*)&Ks[cur][(j * 16 + l15) * 64 +
                                                     (((st * 4 + quad) ^ (l15 & 7)) * 8)];
#if __has_builtin(__builtin_amdgcn_mfma_f32_16x16x16bf16_1k)
        short4v vf[4][4];
#pragma unroll
        for (int j = 0; j < 4; j++) {
            int k8 = j * 2 + (quad >> 1);
#pragma unroll
            for (int jt = 0; jt < 4; jt++) {
                int d = jt * 16 + l15;
                vf[j][jt] = *(const short4v*)&Vt[cur][d * 64 + ((k8 ^ (d & 7)) * 8) +
                                                      (quad & 1) * 4];
            }
        }
#else
        short8 vf[2][4];
#pragma unroll
        for (int st = 0; st < 2; st++)
#pragma unroll
            for (int jt = 0; jt < 4; jt++) {
                int d = jt * 16 + l15;
                vf[st][jt] = *(const short8*)&Vt[cur][d * 64 + (((st * 4 + quad) ^ (d & 7)) * 8)];
            }
#endif

        f32x4 s[4];
#pragma unroll
        for (int j = 0; j < 4; j++) s[j] = (f32x4){0.f, 0.f, 0.f, 0.f};
#pragma unroll
        for (int st = 0; st < 2; st++)
#pragma unroll
            for (int j = 0; j < 4; j++)
                s[j] = __builtin_amdgcn_mfma_f32_16x16x32_bf16(kf[st][j], qf[st], s[j], 0, 0, 0);

        float lpv[4] = {0.f, 0.f, 0.f, 0.f};
        short4v pj[4];
        if (kt != qb) {
#pragma unroll
            for (int j = 0; j < 4; j++) {
                union { short4v v; u16 u[4]; } pk;
#pragma unroll
                for (int r = 0; r < 4; r++) {
                    float pv = __builtin_amdgcn_exp2f(s[j][r] * Cs);
                    lpv[r] += pv;
                    pk.u[r] = f2bf_fast(pv);
                }
                pj[j] = pk.v;
            }
        } else {
            const int qrow = rmin + l15;
#pragma unroll
            for (int j = 0; j < 4; j++) {
                union { short4v v; u16 u[4]; } pk;
#pragma unroll
                for (int r = 0; r < 4; r++) {
                    float pv = __builtin_amdgcn_exp2f(s[j][r] * Cs);
                    int key = kt * 64 + j * 16 + quad * 4 + r;
                    if (key > qrow) pv = 0.f;
                    lpv[r] += pv;
                    pk.u[r] = f2bf_fast(pv);
                }
                pj[j] = pk.v;
            }
        }
        l_part += (lpv[0] + lpv[1]) + (lpv[2] + lpv[3]);

#if __has_builtin(__builtin_amdgcn_mfma_f32_16x16x16bf16_1k)
#pragma unroll
        for (int jt = 0; jt < 4; jt++)
#pragma unroll
            for (int j = 0; j < 4; j++)
                oacc[jt] = __builtin_amdgcn_mfma_f32_16x16x16bf16_1k(pj[j], vf[j][jt],
                                                                     oacc[jt], 0, 0, 0);
#else
        u16* Pw = Ps[wave];
#pragma unroll
        for (int j = 0; j < 4; j++)
            *(short4v*)&Pw[l15 * 72 + j * 16 + quad * 4] = pj[j];
#pragma unroll
        for (int st = 0; st < 2; st++) {
            short8 pf2 = *(const short8*)&Pw[l15 * 72 + st * 32 + quad * 8];
#pragma unroll
            for (int jt = 0; jt < 4; jt++)
                oacc[jt] = __builtin_amdgcn_mfma_f32_16x16x32_bf16(pf2, vf[st][jt],
                                                                  oacc[jt], 0, 0, 0);
        }
#endif
        __syncthreads();
    }

    float lf = l_part;
    lf += __shfl_xor(lf, 16, 64);
    lf += __shfl_xor(lf, 32, 64);
    float inv[4];
#pragma unroll
    for (int r = 0; r < 4; r++) inv[r] = 1.f / __shfl(lf, quad * 4 + r, 64);
#pragma unroll
    for (int jt = 0; jt < 4; jt++) {
        int d = jt * 16 + l15;
#pragma unroll
        for (int r = 0; r < 4; r++) {
            int t = rmin + quad * 4 + r;
            O[base + (size_t)t * 1024 + d] = f2bf(oacc[jt][r] * inv[r]);
        }
    }
}

// ---------------- flash combine: O = (sum_c O_c) / (sum_c l_c) --------------
__global__ __launch_bounds__(256) void flash_combine_kernel(const u16* __restrict__ pO,
                                                            const float* __restrict__ pL,
                                                            u16* __restrict__ O) {
    const int qj = blockIdx.x;                 // 0..23 -> qb = qj + 8
    const int bh = blockIdx.y;
    const int qb = qj + 8;
    const int nch = (qb >> 3) + 1;             // 2, 3 or 4 chunks
    const int tid = threadIdx.x;
    const int row = tid >> 2;                  // 0..63
    const int d0 = (tid & 3) * 16;
    const size_t ib = ((size_t)bh * 24 + qj) * 4;

    float acc[16];
#pragma unroll
    for (int k = 0; k < 16; k++) acc[k] = 0.f;
    float lsum = 0.f;
    for (int c = 0; c < nch; c++) {
        const u16* po = pO + (ib + c) * 4096 + row * 64 + d0;
        u16 pb[16];
        *(uint4*)pb = *(const uint4*)po;
        *(uint4*)(pb + 8) = *(const uint4*)(po + 8);
#pragma unroll
        for (int k = 0; k < 16; k++) acc[k] += bf2f(pb[k]);
        lsum += pL[(ib + c) * 64 + row];
    }
    const float inv = 1.f / lsum;
    u16 o[16];
#pragma unroll
    for (int k = 0; k < 16; k++) o[k] = f2bf(acc[k] * inv);
    const size_t base = ((size_t)(bh >> 4) * 2048) * 1024 + (size_t)(bh & 15) * 64;
    const int t = qb * 64 + row;
    u16* op = &O[base + (size_t)t * 1024 + d0];
    *(uint4*)op = ((uint4*)o)[0];
    *(uint4*)(op + 8) = ((uint4*)o)[1];
}

extern "C" void kernel_launch(void* const* d_in, const int* in_sizes, int n_in,
                              void* d_out, int out_size, void* d_ws, size_t ws_size,
                              hipStream_t stream) {
    (void)in_sizes; (void)n_in; (void)out_size;
    const void* x   = d_in[0];
    // d_in[1] = attn_mask (int32, pure causal) -- implemented directly
    const void* Wq  = d_in[2];  const void* bq  = d_in[3];
    const void* Wk  = d_in[4];  const void* bk  = d_in[5];
    const void* Wv  = d_in[6];  const void* bv  = d_in[7];
    const void* Wo  = d_in[8];  const void* bo  = d_in[9];
    const void* g1  = d_in[10]; const void* be1 = d_in[11];
    const void* g2  = d_in[12]; const void* be2 = d_in[13];
    const void* W1  = d_in[14]; const void* bf1 = d_in[15];
    const void* W2  = d_in[16]; const void* bf2 = d_in[17];
    const void* Wd  = d_in[18]; const void* bd  = d_in[19];
    const void* Wu  = d_in[20]; const void* bu  = d_in[21];

    uint8_t* w8 = (uint8_t*)d_ws;
    int* flag = (int*)w8;                    // 64 B header
    float* pf = (float*)(w8 + 64);           // f32 param pool
    u16* wsb = (u16*)(w8 + 64 + 65536);      // bf16 arena

    const size_t M1 = 1024ull * 1024ull;
    u16* WqT = wsb;                          // Wq/Wk/Wv transposed, contiguous 3072xK
    u16* WkT = wsb + 1 * M1;
    u16* WvT = wsb + 2 * M1;
    u16* WoT = wsb + 3 * M1;
    u16* W1T = wsb + 4 * M1;                 // 4M
    u16* W2T = wsb + 8 * M1;                 // 4M
    u16* WdT = wsb + 12 * M1;                // 64K
    u16* WuT = wsb + 12 * M1 + 65536;        // 64K
    u16* S0  = wsb + 12 * M1 + 131072;
    u16* Areg = S0;                          // xb
    u16* Breg = S0 + 4 * M1;                 // xn -> attn
    u16* ff1  = S0;                          // 16M spans Areg+Breg+8M fresh
    u16* Creg = S0 + 16 * M1;                // q -> xn2
    u16* Dreg = S0 + 20 * M1;                // k -> x1
    u16* Ereg = S0 + 24 * M1;                // VtG -> hh
    u16* xb = Areg;
    u16* xn = Breg; u16* attn = Breg;
    u16* q = Creg;  u16* xn2 = Creg;
    u16* kk_ = Dreg; u16* x1 = Dreg;
    u16* VtG = Ereg; u16* hh = Ereg;

    // flash partial buffer after the bf16 arena (24MB bf16 O + 1MB f32 l)
    const size_t arena_bytes = (size_t)(64 + 65536) + (40 * M1 + 131072) * 2;
    float* partf = (float*)(w8 + ((arena_bytes + 255) & ~(size_t)255));
    const size_t need = ((arena_bytes + 255) & ~(size_t)255) + 4ull * 4 * M1 * 4;
    const bool sk = ws_size >= need;
    float* flL = partf + 14 * M1;            // flash l partials at +56MB

    float* bqkv_f = pf + 0;    // bq,bk,bv contiguous (3072)
    float* bo_f  = pf + 3072;
    float* bf1_f = pf + 4096;  float* bf2_f = pf + 8192;
    float* bd_f  = pf + 9216;  float* bu_f  = pf + 9280;
    float* g1_f  = pf + 10304; float* be1_f = pf + 11328;
    float* g2_f  = pf + 12352; float* be2_f = pf + 13376;

    // merged prologue: detect + param convert + weight transpose (1 launch)
    // 64x64 vectorized tiles (r22: scalar 32x32 version measured 49.4us at
    // 1.04 TB/s -- G13 violation hidden below the top-5 cutoff all session)
    Prologue P;
    const void* tsrc[8] = {Wq, Wk, Wv, Wo, W1, W2, Wd, Wu};
    u16* tdst[8] = {WqT, WkT, WvT, WoT, W1T, W2T, WdT, WuT};
    int tR[8] = {1024, 1024, 1024, 1024, 1024, 4096, 1024, 64};
    int tC[8] = {1024, 1024, 1024, 1024, 4096, 1024, 64, 1024};
    int acc_off = 0;
    for (int i = 0; i < 8; i++) {
        P.tsrc[i] = tsrc[i]; P.tdst[i] = tdst[i];
        P.tR[i] = tR[i]; P.tC[i] = tC[i];
        P.toff[i] = acc_off;
        acc_off += (tR[i] >> 6) * (tC[i] >> 6);
    }
    P.ntrans = acc_off;
    const void* psrc[12] = {bq, bk, bv, bo, bf1, bf2, bd, bu, g1, be1, g2, be2};
    int poff[12] = {0, 1024, 2048, 3072, 4096, 8192, 9216, 9280, 10304, 11328, 12352, 13376};
    int pn[12]   = {1024, 1024, 1024, 1024, 4096, 1024, 64, 1024, 1024, 1024, 1024, 1024};
    for (int i = 0; i < 12; i++) { P.psrc[i] = psrc[i]; P.poff[i] = poff[i]; P.pn[i] = pn[i]; }
    prologue_kernel<<<acc_off + 12, 256, 0, stream>>>(P, (const unsigned*)x, flag, pf);

    // fused x-convert + LN1: writes xb (bf16 x) and xn in one pass
    ln_x_kernel<<<4096, 256, 0, stream>>>(x, g1_f, be1_f, xb, xn, flag);
    // TAG 0: fused QKV (N=3072, V transposed per-head into VtG), 768 blocks
    gemm128_kernel<0><<<dim3(24, 32), 512, 0, stream>>>(xn, WqT, bqkv_f, nullptr, nullptr,
                                                        q, kk_, VtG, 4096, 3072, 1024, 0, 2, 0, flag);
    if (sk) {
        flash_pair_kernel<<<dim3(40, 32), 512, 0, stream>>>(q, kk_, VtG, attn, (u16*)partf, flL);
        flash_combine_kernel<<<dim3(24, 32), 256, 0, stream>>>((const u16*)partf, flL, attn);
    } else {
        flash_kernel<<<dim3(32, 32), 256, 0, stream>>>(q, kk_, VtG, attn);
    }
    // TAG 1: Wo projection + bias + residual, BK=128 deep kernel + XCD swizzle
    gemm128d_kernel<1><<<dim3(8, 32), 512, 0, stream>>>(attn, WoT, bo_f, xb,
                                                        x1, 1024, 1024, 0, 1);
    ln_kernel<<<4096, 256, 0, stream>>>(x1, g2_f, be2_f, xn2);
    // TAG 2: FFN1 (relu), 256x256 tile / 128x64 waves
    gemm256w_kernel<2><<<dim3(16, 16), 512, 0, stream>>>(xn2, W1T, bf1_f,
                                                         ff1, 4096, 1024, 1);
    // TAG 3: FFN2, BK=128 deep kernel (64 phases vs 128) + XCD swizzle
    // (r19 measured-best; split-K 2 variant r20/r21 regressed: +64MB HBM
    // round-trip for partials outweighs the occupancy win)
    gemm128d_kernel<3><<<dim3(8, 32), 512, 0, stream>>>(ff1, W2T, bf2_f, nullptr,
                                                        hh, 1024, 4096, 0, 1);
    // fused adapter: replaces TAG4 + reduce + TAG5 (3 launches -> 1)
    adapter_kernel<<<256, 512, 0, stream>>>(hh, x1, WdT, WuT, bd_f, bu_f, d_out, flag);
}